// Round 15
// baseline (1002.153 us; speedup 1.0000x reference)
//
#include <hip/hip_runtime.h>
#include <math.h>

constexpr int Lseq = 4096, Dm = 1024, H = 4, DK = 512, DV = 1024;
constexpr int DQH = 128, DVH = 256, CH = 64, ROWS = 4 * 4096;

typedef unsigned short u16;
struct alignas(16) us8 { u16 u[8]; };
typedef __attribute__((ext_vector_type(8))) short bf16x8;   // 8 bf16 (4 VGPRs)
typedef __attribute__((ext_vector_type(4))) float f32x4;

__device__ __forceinline__ float sig_(float x) { return 1.f / (1.f + expf(-x)); }
__device__ __forceinline__ float b2f(u16 u) {
  union { float f; unsigned v; } x; x.v = (unsigned)u << 16; return x.f;
}
__device__ __forceinline__ u16 f2b(float f) {   // round-to-nearest-even
  union { float f; unsigned v; } x; x.f = f;
  unsigned r = x.v + 0x7fffu + ((x.v >> 16) & 1u);
  return (u16)(r >> 16);
}
// async global->LDS, 16B per lane; lds dest = wave-uniform base + lane*16
__device__ __forceinline__ void gld16(const u16* g, u16* l) {
  __builtin_amdgcn_global_load_lds(
      (const __attribute__((address_space(1))) void*)g,
      (__attribute__((address_space(3))) void*)l, 16, 0, 0);
}
// LDS-only barrier (prep): global ops stay in flight
__device__ __forceinline__ void lds_barrier() {
  asm volatile("s_waitcnt lgkmcnt(0)" ::: "memory");
  __builtin_amdgcn_s_barrier();
  asm volatile("" ::: "memory");
}

__global__ void ws_sentinel_kernel(float* out, float v) { out[0] = v; }

// ---- 0. f32 -> bf16 convert + TRANSPOSE: in[K][N] -> out[N][K] ----
__global__ __launch_bounds__(256) void cvt_t_kernel(
    const float* __restrict__ in, u16* __restrict__ out, int N, int K) {
  __shared__ u16 T[32][66];
  const int k0 = blockIdx.y * 32, n0 = blockIdx.x * 64;
  const int t = threadIdx.x;
#pragma unroll
  for (int i = 0; i < 8; ++i) {
    int idx = t + i * 256;
    int kk = idx >> 6, nn = idx & 63;
    T[kk][nn] = f2b(in[(size_t)(k0 + kk) * N + n0 + nn]);
  }
  __syncthreads();
#pragma unroll
  for (int i = 0; i < 8; ++i) {
    int idx = t + i * 256;
    int kk = idx & 31, nn = idx >> 5;
    out[(size_t)(n0 + nn) * K + k0 + kk] = T[kk][nn];
  }
}

// ---- 1. conv + silu -> bf16 ----
__global__ __launch_bounds__(256) void conv_silu_kernel(
    const float* __restrict__ x, const float* __restrict__ w, u16* __restrict__ h) {
  int idx = blockIdx.x * 256 + threadIdx.x;
  int d = idx & (Dm - 1), l = (idx >> 10) & (Lseq - 1), b = idx >> 22;
  const float* xb = x + ((size_t)b << 22);
  float acc = 0.f;
#pragma unroll
  for (int i = 0; i < 4; ++i) {
    int li = l - 3 + i;
    if (li >= 0) acc = fmaf(w[d * 4 + i], xb[((size_t)li << 10) | d], acc);
  }
  h[idx] = f2b(acc * sig_(acc));
}

// ---- 2. MFMA GEMM, m97 structure. MODE: 0=bf16 out, 1=f32 out, 2=bf16+l2norm
template <int MODE>
__global__ __launch_bounds__(256) void gemm_mfma_kernel(
    const u16* __restrict__ A, const u16* __restrict__ BT, void* __restrict__ Cv,
    int M, int N, int K) {
  __shared__ u16 As[128 * 32];
  __shared__ u16 Bs[128 * 32];
  const int tid = threadIdx.x;
  const int wid = tid >> 6, lane = tid & 63;
  const int wr = wid >> 1, wc = wid & 1;
  const int fr = lane & 15, fk = lane >> 4;
  const int nbx = N >> 7;
  const int bid = blockIdx.x, nwg = gridDim.x;
  const int swz = (bid & 7) * (nwg >> 3) + (bid >> 3);   // T1: nwg % 8 == 0
  const int row0 = (swz / nbx) * 128, col0 = (swz % nbx) * 128;

  const int sA[2] = {(0 * 4 + wid) * 64 + lane, (1 * 4 + wid) * 64 + lane};

  f32x4 acc[4][4];
#pragma unroll
  for (int i = 0; i < 4; ++i)
#pragma unroll
    for (int j = 0; j < 4; ++j) acc[i][j] = {0.f, 0.f, 0.f, 0.f};

  for (int k0 = 0; k0 < K; k0 += 32) {
#pragma unroll
    for (int i = 0; i < 2; ++i) {
      const int seg = sA[i];
      const int r = seg >> 2, k8 = (seg & 3) << 3;
      gld16(&A[(size_t)(row0 + r) * K + k0 + k8], &As[(i * 4 + wid) * 512]);
      gld16(&BT[(size_t)(col0 + r) * K + k0 + k8], &Bs[(i * 4 + wid) * 512]);
    }
    __syncthreads();
    bf16x8 af[4], bf[4];
#pragma unroll
    for (int mi = 0; mi < 4; ++mi)
      af[mi] = *(const bf16x8*)&As[(wr * 64 + mi * 16 + fr) * 32 + fk * 8];
#pragma unroll
    for (int ni = 0; ni < 4; ++ni)
      bf[ni] = *(const bf16x8*)&Bs[(wc * 64 + ni * 16 + fr) * 32 + fk * 8];
#pragma unroll
    for (int mi = 0; mi < 4; ++mi)
#pragma unroll
      for (int ni = 0; ni < 4; ++ni)
        acc[mi][ni] = __builtin_amdgcn_mfma_f32_16x16x32_bf16(
            af[mi], bf[ni], acc[mi][ni], 0, 0, 0);
    __syncthreads();
  }

  if (MODE == 2) {   // fused per-row l2norm (128-col tile == one head)
    __shared__ float ssh[2][128];
#pragma unroll
    for (int mi = 0; mi < 4; ++mi)
#pragma unroll
      for (int r = 0; r < 4; ++r) {
        float p = 0.f;
#pragma unroll
        for (int ni = 0; ni < 4; ++ni) p += acc[mi][ni][r] * acc[mi][ni][r];
        p += __shfl_xor(p, 1); p += __shfl_xor(p, 2);
        p += __shfl_xor(p, 4); p += __shfl_xor(p, 8);
        if (fr == 0) ssh[wc][wr * 64 + mi * 16 + fk * 4 + r] = p;
      }
    __syncthreads();
#pragma unroll
    for (int mi = 0; mi < 4; ++mi)
#pragma unroll
      for (int r = 0; r < 4; ++r) {
        int ridx = wr * 64 + mi * 16 + fk * 4 + r;
        float sc = 1.f / fmaxf(sqrtf(ssh[0][ridx] + ssh[1][ridx]), 1e-12f);
#pragma unroll
        for (int ni = 0; ni < 4; ++ni) acc[mi][ni][r] *= sc;
      }
  }

#pragma unroll
  for (int mi = 0; mi < 4; ++mi)
#pragma unroll
    for (int ni = 0; ni < 4; ++ni) {
      int col = col0 + wc * 64 + ni * 16 + fr;
#pragma unroll
      for (int r = 0; r < 4; ++r) {
        int row = row0 + wr * 64 + mi * 16 + fk * 4 + r;
        if (MODE == 1) ((float*)Cv)[(size_t)row * N + col] = acc[mi][ni][r];
        else           ((u16*)Cv)[(size_t)row * N + col] = f2b(acc[mi][ni][r]);
      }
    }
}

// ---- 3. beta ----
__global__ __launch_bounds__(256) void beta_kernel(
    const u16* __restrict__ h, const float* __restrict__ Wb, float* __restrict__ beta) {
  int row = blockIdx.x * 4 + (threadIdx.x >> 6), lane = threadIdx.x & 63;
  const u16* hrow = h + (size_t)row * Dm;
  float a0 = 0, a1 = 0, a2 = 0, a3 = 0;
  for (int k0 = 0; k0 < Dm; k0 += 64) {
    float hv = b2f(hrow[k0 + lane]);
    float4 wv = *(const float4*)&Wb[(size_t)(k0 + lane) * 4];
    a0 = fmaf(hv, wv.x, a0); a1 = fmaf(hv, wv.y, a1);
    a2 = fmaf(hv, wv.z, a2); a3 = fmaf(hv, wv.w, a3);
  }
#pragma unroll
  for (int off = 32; off; off >>= 1) {
    a0 += __shfl_down(a0, off); a1 += __shfl_down(a1, off);
    a2 += __shfl_down(a2, off); a3 += __shfl_down(a3, off);
  }
  if (lane == 0) {
    int b = row >> 12, l = row & (Lseq - 1);
    beta[((size_t)(b * H + 0)) * Lseq + l] = sig_(a0);
    beta[((size_t)(b * H + 1)) * Lseq + l] = sig_(a1);
    beta[((size_t)(b * H + 2)) * Lseq + l] = sig_(a2);
    beta[((size_t)(b * H + 3)) * Lseq + l] = sig_(a3);
  }
}

// ---- 5a. delta prep (+ chunk-blocked K transpose for the scan) ----
__global__ __launch_bounds__(256) void delta_prep_kernel(
    const u16* __restrict__ q, const u16* __restrict__ k,
    u16* v, const float* __restrict__ beta,
    u16* __restrict__ Wout, u16* __restrict__ QKout, u16* __restrict__ Ktr) {
  __shared__ alignas(16) float Am[64][68];
  __shared__ alignas(16) float R[64][68];
  __shared__ float Bc[64];
  const int tid = threadIdx.x;
  const int wid = tid >> 6, lane = tid & 63;
  const int fr = lane & 15, fq = lane >> 4;
  const int bh = blockIdx.x >> 6, ch = blockIdx.x & 63;
  const int b = bh >> 2, hh = bh & 3;
  const int c0 = ch * CH;
  const u16* qbase = q + (size_t)b * Lseq * DK + hh * DQH;
  const u16* kbase = k + (size_t)b * Lseq * DK + hh * DQH;
  u16*       vbase = v + (size_t)b * Lseq * DV + hh * DVH;
  const float* bbase = beta + (size_t)bh * Lseq;
  u16* Wrow  = Wout  + ((size_t)bh * Lseq + c0) * DQH;
  u16* QKrow = QKout + ((size_t)bh * Lseq + c0) * CH;
  u16* ktrow = Ktr + (size_t)(bh * 64 + ch) * (128 * 64);   // [d(128)][r(64)]

  if (tid < 64) Bc[tid] = bbase[c0 + tid];

  // K transpose -> global (coalesced per j: 64 lanes consecutive r)
#pragma unroll
  for (int i = 0; i < 4; ++i) {
    int id = tid + i * 256;
    int r = id & 63, d8 = (id >> 6) << 3;
    us8 kv = *(const us8*)&kbase[(size_t)(c0 + r) * DK + d8];
#pragma unroll
    for (int j = 0; j < 8; ++j) ktrow[(size_t)(d8 + j) * 64 + r] = kv.u[j];
  }
  lds_barrier();

  {   // G = K K^T, QKt = Q K^T via MFMA
    const int m0 = wid * 16;
    f32x4 accG[4], accQ[4];
#pragma unroll
    for (int ni = 0; ni < 4; ++ni) {
      accG[ni] = {0.f, 0.f, 0.f, 0.f};
      accQ[ni] = {0.f, 0.f, 0.f, 0.f};
    }
#pragma unroll
    for (int kt = 0; kt < 4; ++kt) {
      bf16x8 afk = *(const bf16x8*)&kbase[(size_t)(c0 + m0 + fr) * DK + kt * 32 + fq * 8];
      bf16x8 afq = *(const bf16x8*)&qbase[(size_t)(c0 + m0 + fr) * DK + kt * 32 + fq * 8];
#pragma unroll
      for (int ni = 0; ni < 4; ++ni) {
        bf16x8 bfk = *(const bf16x8*)&kbase[(size_t)(c0 + ni * 16 + fr) * DK + kt * 32 + fq * 8];
        accG[ni] = __builtin_amdgcn_mfma_f32_16x16x32_bf16(afk, bfk, accG[ni], 0, 0, 0);
        accQ[ni] = __builtin_amdgcn_mfma_f32_16x16x32_bf16(afq, bfk, accQ[ni], 0, 0, 0);
      }
    }
#pragma unroll
    for (int ni = 0; ni < 4; ++ni)
#pragma unroll
      for (int i = 0; i < 4; ++i) {
        int row = m0 + fq * 4 + i, col = ni * 16 + fr;
        float br = Bc[row];
        Am[row][col] = (col < row) ? br * accG[ni][i] : 0.f;
        QKrow[(size_t)row * CH + col] = f2b((col <= row) ? accQ[ni][i] : 0.f);
      }
  }
  lds_barrier();

  for (int p = 0; p < 6; ++p) {
    if (p < 2) {
      const int dbase = p * 64;
      for (int idx = tid; idx < 64 * 64; idx += 256) {
        int r = idx >> 6, d = idx & 63;
        R[r][d] = Bc[r] * b2f(kbase[(size_t)(c0 + r) * DK + dbase + d]);
      }
    } else {
      const int cbase = (p - 2) * 64;
      for (int idx = tid; idx < 64 * 64; idx += 256) {
        int r = idx >> 6, j = idx & 63;
        R[r][j] = Bc[r] * b2f(vbase[(size_t)(c0 + r) * DV + cbase + j]);
      }
    }
    lds_barrier();
    for (int rb = 0; rb < 4; ++rb) {   // blocked forward substitution
      if (rb > 0) {
        const int c = tid & 63, g = tid >> 6;
        const int R0 = rb * 16, row = R0 + g * 4;
        float s0 = 0, s1 = 0, s2 = 0, s3 = 0;
        for (int m = 0; m < R0; ++m) {
          float uv = R[m][c];
          s0 = fmaf(Am[row + 0][m], uv, s0);
          s1 = fmaf(Am[row + 1][m], uv, s1);
          s2 = fmaf(Am[row + 2][m], uv, s2);
          s3 = fmaf(Am[row + 3][m], uv, s3);
        }
        R[row + 0][c] -= s0; R[row + 1][c] -= s1;
        R[row + 2][c] -= s2; R[row + 3][c] -= s3;
      }
      lds_barrier();
      if (tid < 64) {
        const int c = tid;
        for (int i = 1; i < 16; ++i) {
          const int row = rb * 16 + i;
          float s = R[row][c];
          for (int m = 0; m < i; ++m)
            s = fmaf(-Am[row][rb * 16 + m], R[rb * 16 + m][c], s);
          R[row][c] = s;
        }
      }
      lds_barrier();
    }
    if (p < 2) {
      const int dbase = p * 64;
      for (int idx = tid; idx < 64 * 64; idx += 256) {
        int r = idx >> 6, d = idx & 63;
        Wrow[(size_t)r * DQH + dbase + d] = f2b(-R[r][d]);   // NEGATED
      }
    } else {
      const int cbase = (p - 2) * 64;
      for (int idx = tid; idx < 64 * 64; idx += 256) {
        int r = idx >> 6, j = idx & 63;
        vbase[(size_t)(c0 + r) * DV + cbase + j] = f2b(R[r][j]);
      }
    }
    lds_barrier();
  }
}

// ---- 5b. delta scan — BARRIER-FREE wave-private column slices ----
// grid 64 = 4 colgroups x 16 bh (bh = bid&15 -> XCD bh%8); 256 thr = 4
// independent wave-units, each owning 16 v-cols: S in VGPR C-frags + private
// LDS hi/lo for B-operand; U round-trips through private LDS. No barriers.
__global__ __launch_bounds__(256) void delta_scan_kernel(
    const u16* __restrict__ q, const u16* __restrict__ Ktr,
    const u16* __restrict__ Wb, const u16* __restrict__ QKb, u16* uo) {
  __shared__ alignas(16) u16 Shi[4][16][136];
  __shared__ alignas(16) u16 Slo[4][16][136];
  __shared__ alignas(16) u16 Ubt[4][16][72];
  const int tid = threadIdx.x;
  const int wid = tid >> 6, lane = tid & 63;
  const int fr = lane & 15, fq = lane >> 4;
  const int bh = blockIdx.x & 15, cg = blockIdx.x >> 4;
  const int b = bh >> 2, hh = bh & 3;
  const int col0 = (cg * 4 + wid) * 16;
  const u16* qbase = q + (size_t)b * Lseq * DK + hh * DQH;
  const u16* Wbase = Wb + (size_t)bh * Lseq * DQH;
  const u16* QKbase = QKb + (size_t)bh * Lseq * CH;
  const u16* Kbase = Ktr + (size_t)bh * 64 * (128 * 64);
  u16* uobase = uo + (size_t)b * Lseq * DV + hh * DVH + col0;

  u16 (*Sh)[136] = Shi[wid];
  u16 (*Sl)[136] = Slo[wid];
  u16 (*Uw)[72]  = Ubt[wid];

  for (int i = lane; i < 16 * 136; i += 64) {
    (&Sh[0][0])[i] = 0; (&Sl[0][0])[i] = 0;
  }
  f32x4 Sfr[8];
#pragma unroll
  for (int t = 0; t < 8; ++t) Sfr[t] = {0.f, 0.f, 0.f, 0.f};

  for (int ch = 0; ch < 64; ++ch) {
    const int c0 = ch * CH;
    // S B-frags (shared across m-tiles); read once per chunk
    bf16x8 sh[4], sl[4];
#pragma unroll
    for (int kt = 0; kt < 4; ++kt) {
      sh[kt] = *(const bf16x8*)&Sh[fr][kt * 32 + fq * 8];
      sl[kt] = *(const bf16x8*)&Sl[fr][kt * 32 + fq * 8];
    }
    // phase1: U = U0 + Wneg·(S_hi + S_lo)
#pragma unroll
    for (int mt = 0; mt < 4; ++mt) {
      const u16* up = uobase + (size_t)(c0 + mt * 16 + fq * 4) * DV + fr;
      f32x4 a, aB = {0.f, 0.f, 0.f, 0.f};
      a[0] = b2f(up[0]);
      a[1] = b2f(up[(size_t)DV]);
      a[2] = b2f(up[(size_t)2 * DV]);
      a[3] = b2f(up[(size_t)3 * DV]);
      const u16* wp = Wbase + (size_t)(c0 + mt * 16 + fr) * DQH + fq * 8;
#pragma unroll
      for (int kt = 0; kt < 4; ++kt) {
        bf16x8 wf = *(const bf16x8*)&wp[kt * 32];
        a  = __builtin_amdgcn_mfma_f32_16x16x32_bf16(wf, sh[kt], a, 0, 0, 0);
        aB = __builtin_amdgcn_mfma_f32_16x16x32_bf16(wf, sl[kt], aB, 0, 0, 0);
      }
      ushort4 ub = {f2b(a[0] + aB[0]), f2b(a[1] + aB[1]),
                    f2b(a[2] + aB[2]), f2b(a[3] + aB[3])};
      *(ushort4*)&Uw[fr][mt * 16 + fq * 4] = ub;
    }
    // U B-frags (wave-local turnaround; compiler inserts lgkmcnt)
    bf16x8 uf0 = *(const bf16x8*)&Uw[fr][fq * 8];
    bf16x8 uf1 = *(const bf16x8*)&Uw[fr][32 + fq * 8];
    // phase3 (critical path): S += K^T·U via chunk-blocked Ktr
    const u16* kp = Kbase + (size_t)ch * (128 * 64);
#pragma unroll
    for (int dt = 0; dt < 8; ++dt) {
      const u16* ka = kp + (size_t)(dt * 16 + fr) * 64 + fq * 8;
      Sfr[dt] = __builtin_amdgcn_mfma_f32_16x16x32_bf16(
          *(const bf16x8*)&ka[0], uf0, Sfr[dt], 0, 0, 0);
      Sfr[dt] = __builtin_amdgcn_mfma_f32_16x16x32_bf16(
          *(const bf16x8*)&ka[32], uf1, Sfr[dt], 0, 0, 0);
    }
    // phase2 (off critical path): O = Q·S_hi + QK·U -> overwrite U0 slot
#pragma unroll
    for (int mt = 0; mt < 4; ++mt) {
      f32x4 a = {0.f, 0.f, 0.f, 0.f}, aB = {0.f, 0.f, 0.f, 0.f};
      const u16* qp = qbase + (size_t)(c0 + mt * 16 + fr) * DK + fq * 8;
#pragma unroll
      for (int kt = 0; kt < 4; ++kt)
        a = __builtin_amdgcn_mfma_f32_16x16x32_bf16(
            *(const bf16x8*)&qp[kt * 32], sh[kt], a, 0, 0, 0);
      const u16* qkp = QKbase + (size_t)(c0 + mt * 16 + fr) * CH + fq * 8;
      aB = __builtin_amdgcn_mfma_f32_16x16x32_bf16(
          *(const bf16x8*)&qkp[0], uf0, aB, 0, 0, 0);
      aB = __builtin_amdgcn_mfma_f32_16x16x32_bf16(
          *(const bf16x8*)&qkp[32], uf1, aB, 0, 0, 0);
      u16* op = uobase + (size_t)(c0 + mt * 16 + fq * 4) * DV + fr;
      op[0] = f2b(a[0] + aB[0]);
      op[(size_t)DV] = f2b(a[1] + aB[1]);
      op[(size_t)2 * DV] = f2b(a[2] + aB[2]);
      op[(size_t)3 * DV] = f2b(a[3] + aB[3]);
    }
    // publish split-S for next chunk (wave-local)
#pragma unroll
    for (int dt = 0; dt < 8; ++dt) {
      ushort4 shv, slv;
#pragma unroll
      for (int i = 0; i < 4; ++i) {
        float s = Sfr[dt][i];
        u16 hp = f2b(s);
        ((u16*)&shv)[i] = hp;
        ((u16*)&slv)[i] = f2b(s - b2f(hp));
      }
      *(ushort4*)&Sh[fr][dt * 16 + fq * 4] = shv;
      *(ushort4*)&Sl[fr][dt * 16 + fq * 4] = slv;
    }
  }
}

// ---- 6. gate ----
__global__ __launch_bounds__(256) void gate_kernel(
    const u16* og, const u16* __restrict__ g,
    const float* __restrict__ nw, u16* out) {
  int idx = blockIdx.x * 4 + (threadIdx.x >> 6), lane = threadIdx.x & 63;
  size_t base = (size_t)(idx >> 2) * DV + (size_t)(idx & 3) * DVH + (size_t)lane * 4;
  ushort4 o4 = *(const ushort4*)&og[base];
  float ox = b2f(o4.x), oy = b2f(o4.y), oz = b2f(o4.z), ow = b2f(o4.w);
  float ss = ox * ox + oy * oy + oz * oz + ow * ow;
#pragma unroll
  for (int off = 32; off; off >>= 1) ss += __shfl_xor(ss, off);
  float r = 1.f / sqrtf(ss * (1.f / DVH) + 1e-5f);
  ushort4 g4 = *(const ushort4*)&g[base];
  float gx = b2f(g4.x), gy = b2f(g4.y), gz = b2f(g4.z), gw = b2f(g4.w);
  float4 wv = *(const float4*)&nw[lane * 4];
  ushort4 res;
  res.x = f2b(ox * r * wv.x * (gx * sig_(gx)));
  res.y = f2b(oy * r * wv.y * (gy * sig_(gy)));
  res.z = f2b(oz * r * wv.z * (gz * sig_(gz)));
  res.w = f2b(ow * r * wv.w * (gw * sig_(gw)));
  *(ushort4*)&out[base] = res;
}

// ---- host ----
extern "C" void kernel_launch(void* const* d_in, const int* in_sizes, int n_in,
                              void* d_out, int out_size, void* d_ws, size_t ws_size,
                              hipStream_t stream) {
  (void)in_sizes; (void)n_in; (void)out_size;
  const float* x  = (const float*)d_in[0];
  const float* cw = (const float*)d_in[1];
  const float* Wq = (const float*)d_in[2];
  const float* Wk = (const float*)d_in[3];
  const float* Wv = (const float*)d_in[4];
  const float* Wb = (const float*)d_in[5];
  const float* Wg = (const float*)d_in[6];
  const float* nw = (const float*)d_in[7];
  const float* Wo = (const float*)d_in[8];
  float* out = (float*)d_out;   // f32 output

  u16* hb = (u16*)d_ws;                       // ROWS*Dm  bf16
  u16* qb = hb + (size_t)ROWS * Dm;           // ROWS*DK
  u16* kb = qb + (size_t)ROWS * DK;           // ROWS*DK
  u16* vb = kb + (size_t)ROWS * DK;           // ROWS*DV  (v -> U0 -> O; gate in-place)
  float* bbuf = (float*)(vb + (size_t)ROWS * DV);   // ROWS*H f32
  u16* Wbuf  = (u16*)(bbuf + (size_t)ROWS * H);     // 16*Lseq*DQH bf16 (negated)
  u16* QKbuf = Wbuf + (size_t)16 * Lseq * DQH;      // 16*Lseq*CH  bf16
  u16* wq16 = QKbuf + (size_t)16 * Lseq * CH;       // bf16 weights, TRANSPOSED [N][K]
  u16* wk16 = wq16 + (size_t)Dm * DK;
  u16* wv16 = wk16 + (size_t)Dm * DK;
  u16* wg16 = wv16 + (size_t)Dm * DV;
  u16* wo16 = wg16 + (size_t)Dm * DV;
  u16* ktr  = wo16 + (size_t)DV * Dm;               // 16*Lseq*DQH bf16 (K^T, chunk-blocked)
  u16* gb = qb;                               // g reuses q+k region after scan

  const size_t need = (size_t)ROWS * (Dm + DK + DK + DV) * 2 + (size_t)ROWS * H * 4
                    + (size_t)16 * Lseq * (DQH + CH) * 2
                    + ((size_t)Dm * (DK * 2 + DV * 3)) * 2
                    + (size_t)16 * Lseq * DQH * 2;
  if (ws_size < need) {
    ws_sentinel_kernel<<<1, 1, 0, stream>>>(out, (float)ws_size);
    return;
  }

  // weight convert + transpose: in [K][N] f32 -> out [N][K] bf16
  cvt_t_kernel<<<dim3(DK / 64, Dm / 32), 256, 0, stream>>>(Wq, wq16, DK, Dm);
  cvt_t_kernel<<<dim3(DK / 64, Dm / 32), 256, 0, stream>>>(Wk, wk16, DK, Dm);
  cvt_t_kernel<<<dim3(DV / 64, Dm / 32), 256, 0, stream>>>(Wv, wv16, DV, Dm);
  cvt_t_kernel<<<dim3(DV / 64, Dm / 32), 256, 0, stream>>>(Wg, wg16, DV, Dm);
  cvt_t_kernel<<<dim3(Dm / 64, DV / 32), 256, 0, stream>>>(Wo, wo16, Dm, DV);

  conv_silu_kernel<<<ROWS * Dm / 256, 256, 0, stream>>>(x, cw, hb);

  // q/k with fused l2norm (128-col tile == one head)
  gemm_mfma_kernel<2><<<(DK / 128) * (ROWS / 128), 256, 0, stream>>>(hb, wq16, qb, ROWS, DK, Dm);
  gemm_mfma_kernel<2><<<(DK / 128) * (ROWS / 128), 256, 0, stream>>>(hb, wk16, kb, ROWS, DK, Dm);
  gemm_mfma_kernel<0><<<(DV / 128) * (ROWS / 128), 256, 0, stream>>>(hb, wv16, vb, ROWS, DV, Dm);
  beta_kernel<<<ROWS / 4, 256, 0, stream>>>(hb, Wb, bbuf);

  delta_prep_kernel<<<1024, 256, 0, stream>>>(qb, kb, vb, bbuf, Wbuf, QKbuf, ktr);
  delta_scan_kernel<<<64, 256, 0, stream>>>(qb, ktr, Wbuf, QKbuf, vb);

  gemm_mfma_kernel<0><<<(DV / 128) * (ROWS / 128), 256, 0, stream>>>(hb, wg16, gb, ROWS, DV, Dm);
  gate_kernel<<<ROWS * H / 4, 256, 0, stream>>>(vb, gb, nw, vb);

  gemm_mfma_kernel<1><<<(Dm / 128) * (ROWS / 128), 256, 0, stream>>>(vb, wo16, out, ROWS, Dm, DV);
}

// Round 16
// 553.351 us; speedup vs baseline: 1.8111x; 1.8111x over previous
//
#include <hip/hip_runtime.h>
#include <math.h>

constexpr int Lseq = 4096, Dm = 1024, H = 4, DK = 512, DV = 1024;
constexpr int DQH = 128, DVH = 256, CH = 64, ROWS = 4 * 4096;

typedef unsigned short u16;
struct alignas(16) us8 { u16 u[8]; };
typedef __attribute__((ext_vector_type(8))) short bf16x8;   // 8 bf16 (4 VGPRs)
typedef __attribute__((ext_vector_type(4))) float f32x4;

__device__ __forceinline__ float sig_(float x) { return 1.f / (1.f + expf(-x)); }
__device__ __forceinline__ float b2f(u16 u) {
  union { float f; unsigned v; } x; x.v = (unsigned)u << 16; return x.f;
}
__device__ __forceinline__ u16 f2b(float f) {   // round-to-nearest-even
  union { float f; unsigned v; } x; x.f = f;
  unsigned r = x.v + 0x7fffu + ((x.v >> 16) & 1u);
  return (u16)(r >> 16);
}
// async global->LDS, 16B per lane; lds dest = wave-uniform base + lane*16
__device__ __forceinline__ void gld16(const u16* g, u16* l) {
  __builtin_amdgcn_global_load_lds(
      (const __attribute__((address_space(1))) void*)g,
      (__attribute__((address_space(3))) void*)l, 16, 0, 0);
}

__global__ void ws_sentinel_kernel(float* out, float v) { out[0] = v; }

// ---- 0. f32 -> bf16 convert + TRANSPOSE: in[K][N] -> out[N][K] ----
__global__ __launch_bounds__(256) void cvt_t_kernel(
    const float* __restrict__ in, u16* __restrict__ out, int N, int K) {
  __shared__ u16 T[32][66];
  const int k0 = blockIdx.y * 32, n0 = blockIdx.x * 64;
  const int t = threadIdx.x;
#pragma unroll
  for (int i = 0; i < 8; ++i) {
    int idx = t + i * 256;
    int kk = idx >> 6, nn = idx & 63;
    T[kk][nn] = f2b(in[(size_t)(k0 + kk) * N + n0 + nn]);
  }
  __syncthreads();
#pragma unroll
  for (int i = 0; i < 8; ++i) {
    int idx = t + i * 256;
    int kk = idx & 31, nn = idx >> 5;
    out[(size_t)(n0 + nn) * K + k0 + kk] = T[kk][nn];
  }
}

// ---- 1. conv + silu -> bf16 ----
__global__ __launch_bounds__(256) void conv_silu_kernel(
    const float* __restrict__ x, const float* __restrict__ w, u16* __restrict__ h) {
  int idx = blockIdx.x * 256 + threadIdx.x;
  int d = idx & (Dm - 1), l = (idx >> 10) & (Lseq - 1), b = idx >> 22;
  const float* xb = x + ((size_t)b << 22);
  float acc = 0.f;
#pragma unroll
  for (int i = 0; i < 4; ++i) {
    int li = l - 3 + i;
    if (li >= 0) acc = fmaf(w[d * 4 + i], xb[((size_t)li << 10) | d], acc);
  }
  h[idx] = f2b(acc * sig_(acc));
}

// ---- 2. MFMA GEMM, BK=64 + T2 XOR-swizzle (linear LDS dest, pre-swizzled
// global source, swizzled frag reads -> 2-way banks = free).
// MODE: 0=bf16 out, 1=f32 out, 2=bf16+l2norm (DK GEMMs: 128-col tile == head)
template <int MODE>
__global__ __launch_bounds__(256) void gemm_mfma_kernel(
    const u16* __restrict__ A, const u16* __restrict__ BT, void* __restrict__ Cv,
    int M, int N, int K) {
  __shared__ u16 As[128 * 64];
  __shared__ u16 Bs[128 * 64];
  const int tid = threadIdx.x;
  const int wid = tid >> 6, lane = tid & 63;
  const int wr = wid >> 1, wc = wid & 1;
  const int fr = lane & 15, fk = lane >> 4;
  const int nbx = N >> 7;
  const int bid = blockIdx.x, nwg = gridDim.x;
  const int swz = (bid & 7) * (nwg >> 3) + (bid >> 3);   // T1: nwg % 8 == 0
  const int row0 = (swz / nbx) * 128, col0 = (swz % nbx) * 128;

  // staging: 16 segments (4/wave/operand). seg s covers rows s*8..s*8+7;
  // lane l: r = s*8 + l/8, logical chunk kc = l&7, SOURCE chunk = kc^(r&7).
  int sr[4], sk[4];
#pragma unroll
  for (int i = 0; i < 4; ++i) {
    int s = i * 4 + wid;
    int r = s * 8 + (lane >> 3);
    sr[i] = r;
    sk[i] = ((lane & 7) ^ (r & 7)) << 3;
  }

  f32x4 acc[4][4];
#pragma unroll
  for (int i = 0; i < 4; ++i)
#pragma unroll
    for (int j = 0; j < 4; ++j) acc[i][j] = {0.f, 0.f, 0.f, 0.f};

  for (int k0 = 0; k0 < K; k0 += 64) {
#pragma unroll
    for (int i = 0; i < 4; ++i) {
      const int s = i * 4 + wid;
      gld16(&A[(size_t)(row0 + sr[i]) * K + k0 + sk[i]], &As[s * 512]);
      gld16(&BT[(size_t)(col0 + sr[i]) * K + k0 + sk[i]], &Bs[s * 512]);
    }
    __syncthreads();
#pragma unroll
    for (int kt = 0; kt < 2; ++kt) {
      bf16x8 af[4], bf[4];
#pragma unroll
      for (int mi = 0; mi < 4; ++mi) {
        int row = wr * 64 + mi * 16 + fr;
        af[mi] = *(const bf16x8*)&As[row * 64 + (((kt * 4 + fk) ^ (fr & 7)) << 3)];
      }
#pragma unroll
      for (int ni = 0; ni < 4; ++ni) {
        int row = wc * 64 + ni * 16 + fr;
        bf[ni] = *(const bf16x8*)&Bs[row * 64 + (((kt * 4 + fk) ^ (fr & 7)) << 3)];
      }
#pragma unroll
      for (int mi = 0; mi < 4; ++mi)
#pragma unroll
        for (int ni = 0; ni < 4; ++ni)
          acc[mi][ni] = __builtin_amdgcn_mfma_f32_16x16x32_bf16(
              af[mi], bf[ni], acc[mi][ni], 0, 0, 0);
    }
    __syncthreads();
  }

  if (MODE == 2) {   // fused per-row l2norm (128-col tile == one head)
    __shared__ float ssh[2][128];
#pragma unroll
    for (int mi = 0; mi < 4; ++mi)
#pragma unroll
      for (int r = 0; r < 4; ++r) {
        float p = 0.f;
#pragma unroll
        for (int ni = 0; ni < 4; ++ni) p += acc[mi][ni][r] * acc[mi][ni][r];
        p += __shfl_xor(p, 1); p += __shfl_xor(p, 2);
        p += __shfl_xor(p, 4); p += __shfl_xor(p, 8);
        if (fr == 0) ssh[wc][wr * 64 + mi * 16 + fk * 4 + r] = p;
      }
    __syncthreads();
#pragma unroll
    for (int mi = 0; mi < 4; ++mi)
#pragma unroll
      for (int r = 0; r < 4; ++r) {
        int ridx = wr * 64 + mi * 16 + fk * 4 + r;
        float sc = 1.f / fmaxf(sqrtf(ssh[0][ridx] + ssh[1][ridx]), 1e-12f);
#pragma unroll
        for (int ni = 0; ni < 4; ++ni) acc[mi][ni][r] *= sc;
      }
  }

  // epilogue: D col = lane&15, row = (lane>>4)*4 + r  [m89/m91-verified]
#pragma unroll
  for (int mi = 0; mi < 4; ++mi)
#pragma unroll
    for (int ni = 0; ni < 4; ++ni) {
      int col = col0 + wc * 64 + ni * 16 + fr;
#pragma unroll
      for (int r = 0; r < 4; ++r) {
        int row = row0 + wr * 64 + mi * 16 + fk * 4 + r;
        if (MODE == 1) ((float*)Cv)[(size_t)row * N + col] = acc[mi][ni][r];
        else           ((u16*)Cv)[(size_t)row * N + col] = f2b(acc[mi][ni][r]);
      }
    }
}

// ---- 3. beta ----
__global__ __launch_bounds__(256) void beta_kernel(
    const u16* __restrict__ h, const float* __restrict__ Wb, float* __restrict__ beta) {
  int row = blockIdx.x * 4 + (threadIdx.x >> 6), lane = threadIdx.x & 63;
  const u16* hrow = h + (size_t)row * Dm;
  float a0 = 0, a1 = 0, a2 = 0, a3 = 0;
  for (int k0 = 0; k0 < Dm; k0 += 64) {
    float hv = b2f(hrow[k0 + lane]);
    float4 wv = *(const float4*)&Wb[(size_t)(k0 + lane) * 4];
    a0 = fmaf(hv, wv.x, a0); a1 = fmaf(hv, wv.y, a1);
    a2 = fmaf(hv, wv.z, a2); a3 = fmaf(hv, wv.w, a3);
  }
#pragma unroll
  for (int off = 32; off; off >>= 1) {
    a0 += __shfl_down(a0, off); a1 += __shfl_down(a1, off);
    a2 += __shfl_down(a2, off); a3 += __shfl_down(a3, off);
  }
  if (lane == 0) {
    int b = row >> 12, l = row & (Lseq - 1);
    beta[((size_t)(b * H + 0)) * Lseq + l] = sig_(a0);
    beta[((size_t)(b * H + 1)) * Lseq + l] = sig_(a1);
    beta[((size_t)(b * H + 2)) * Lseq + l] = sig_(a2);
    beta[((size_t)(b * H + 3)) * Lseq + l] = sig_(a3);
  }
}

// ---- 5a. delta prep (round-12 proven config) ----
__global__ __launch_bounds__(256) void delta_prep_kernel(
    const u16* __restrict__ q, const u16* __restrict__ k,
    u16* v, const float* __restrict__ beta,
    u16* __restrict__ Wout, u16* __restrict__ QKout) {
  __shared__ alignas(16) float Am[64][68];
  __shared__ alignas(16) float R[64][68];
  __shared__ float Bc[64];
  const int tid = threadIdx.x;
  const int wid = tid >> 6, lane = tid & 63;
  const int fr = lane & 15, fq = lane >> 4;
  const int bh = blockIdx.x >> 6, ch = blockIdx.x & 63;
  const int b = bh >> 2, hh = bh & 3;
  const int c0 = ch * CH;
  const u16* qbase = q + (size_t)b * Lseq * DK + hh * DQH;
  const u16* kbase = k + (size_t)b * Lseq * DK + hh * DQH;
  u16*       vbase = v + (size_t)b * Lseq * DV + hh * DVH;
  const float* bbase = beta + (size_t)bh * Lseq;
  u16* Wrow  = Wout  + ((size_t)bh * Lseq + c0) * DQH;
  u16* QKrow = QKout + ((size_t)bh * Lseq + c0) * CH;

  if (tid < 64) Bc[tid] = bbase[c0 + tid];
  __syncthreads();

  {   // G = K K^T, QKt = Q K^T via MFMA
    const int m0 = wid * 16;
    f32x4 accG[4], accQ[4];
#pragma unroll
    for (int ni = 0; ni < 4; ++ni) {
      accG[ni] = {0.f, 0.f, 0.f, 0.f};
      accQ[ni] = {0.f, 0.f, 0.f, 0.f};
    }
#pragma unroll
    for (int kt = 0; kt < 4; ++kt) {
      bf16x8 afk = *(const bf16x8*)&kbase[(size_t)(c0 + m0 + fr) * DK + kt * 32 + fq * 8];
      bf16x8 afq = *(const bf16x8*)&qbase[(size_t)(c0 + m0 + fr) * DK + kt * 32 + fq * 8];
#pragma unroll
      for (int ni = 0; ni < 4; ++ni) {
        bf16x8 bfk = *(const bf16x8*)&kbase[(size_t)(c0 + ni * 16 + fr) * DK + kt * 32 + fq * 8];
        accG[ni] = __builtin_amdgcn_mfma_f32_16x16x32_bf16(afk, bfk, accG[ni], 0, 0, 0);
        accQ[ni] = __builtin_amdgcn_mfma_f32_16x16x32_bf16(afq, bfk, accQ[ni], 0, 0, 0);
      }
    }
#pragma unroll
    for (int ni = 0; ni < 4; ++ni)
#pragma unroll
      for (int i = 0; i < 4; ++i) {
        int row = m0 + fq * 4 + i, col = ni * 16 + fr;
        float br = Bc[row];
        Am[row][col] = (col < row) ? br * accG[ni][i] : 0.f;
        QKrow[(size_t)row * CH + col] = f2b((col <= row) ? accQ[ni][i] : 0.f);
      }
  }
  __syncthreads();

  for (int p = 0; p < 6; ++p) {
    if (p < 2) {
      const int dbase = p * 64;
      for (int idx = tid; idx < 64 * 64; idx += 256) {
        int r = idx >> 6, d = idx & 63;
        R[r][d] = Bc[r] * b2f(kbase[(size_t)(c0 + r) * DK + dbase + d]);
      }
    } else {
      const int cbase = (p - 2) * 64;
      for (int idx = tid; idx < 64 * 64; idx += 256) {
        int r = idx >> 6, j = idx & 63;
        R[r][j] = Bc[r] * b2f(vbase[(size_t)(c0 + r) * DV + cbase + j]);
      }
    }
    __syncthreads();
    for (int rb = 0; rb < 4; ++rb) {   // blocked forward substitution
      if (rb > 0) {
        const int c = tid & 63, g = tid >> 6;
        const int R0 = rb * 16, row = R0 + g * 4;
        float s0 = 0, s1 = 0, s2 = 0, s3 = 0;
        for (int m = 0; m < R0; ++m) {
          float uv = R[m][c];
          s0 = fmaf(Am[row + 0][m], uv, s0);
          s1 = fmaf(Am[row + 1][m], uv, s1);
          s2 = fmaf(Am[row + 2][m], uv, s2);
          s3 = fmaf(Am[row + 3][m], uv, s3);
        }
        R[row + 0][c] -= s0; R[row + 1][c] -= s1;
        R[row + 2][c] -= s2; R[row + 3][c] -= s3;
      }
      __syncthreads();
      if (tid < 64) {
        const int c = tid;
        for (int i = 1; i < 16; ++i) {
          const int row = rb * 16 + i;
          float s = R[row][c];
          for (int m = 0; m < i; ++m)
            s = fmaf(-Am[row][rb * 16 + m], R[rb * 16 + m][c], s);
          R[row][c] = s;
        }
      }
      __syncthreads();
    }
    if (p < 2) {
      const int dbase = p * 64;
      for (int idx = tid; idx < 64 * 64; idx += 256) {
        int r = idx >> 6, d = idx & 63;
        Wrow[(size_t)r * DQH + dbase + d] = f2b(-R[r][d]);   // NEGATED
      }
    } else {
      const int cbase = (p - 2) * 64;
      for (int idx = tid; idx < 64 * 64; idx += 256) {
        int r = idx >> 6, j = idx & 63;
        vbase[(size_t)(c0 + r) * DV + cbase + j] = f2b(R[r][j]);
      }
    }
    __syncthreads();
  }
}

// ---- 5b. delta scan (round-12 proven: MFMA + prefetch + XCD map + hi-only O) ----
__global__ __launch_bounds__(512) void delta_scan_kernel(
    const u16* __restrict__ q, const u16* __restrict__ k,
    const u16* __restrict__ Wb, const u16* __restrict__ QKb, u16* uo) {
  __shared__ alignas(16) u16 Kt[128][72];
  __shared__ alignas(16) u16 Sbt_hi[16][136];
  __shared__ alignas(16) u16 Sbt_lo[16][136];
  __shared__ alignas(16) u16 Ubt[16][72];
  const int tid = threadIdx.x;
  const int wid = tid >> 6, lane = tid & 63;
  const int fr = lane & 15, fq = lane >> 4;
  const int m0w = 16 * (wid & 3);
  const int bh = blockIdx.x & 15, vblk = blockIdx.x >> 4;   // XCD-local bh
  const int b = bh >> 2, hh = bh & 3;
  const u16* qbase = q + (size_t)b * Lseq * DK + hh * DQH;
  const u16* kbase = k + (size_t)b * Lseq * DK + hh * DQH;
  const u16* Wbase = Wb + (size_t)bh * Lseq * DQH;
  const u16* QKbase = QKb + (size_t)bh * Lseq * CH;
  u16* uobase = uo + (size_t)b * Lseq * DV + hh * DVH + vblk * 16;

  for (int i = tid; i < 16 * 136; i += 512) {
    (&Sbt_hi[0][0])[i] = 0; (&Sbt_lo[0][0])[i] = 0;
  }
  f32x4 Sfrag = {0.f, 0.f, 0.f, 0.f};

  const int kr0 = tid & 63, kd0 = (tid >> 6) << 3;
  const int kr1 = (tid + 512) & 63, kd1 = ((tid + 512) >> 6) << 3;

  us8 kpre0 = *(const us8*)&kbase[(size_t)kr0 * DK + kd0];
  us8 kpre1 = *(const us8*)&kbase[(size_t)kr1 * DK + kd1];
  bf16x8 fpre[4];
  bf16x8 qkpre0 = {}, qkpre1 = {};
  ushort4 u0pre = {};
  if (wid < 4) {
    const u16* wp = Wbase + (size_t)(m0w + fr) * DQH + fq * 8;
#pragma unroll
    for (int kt = 0; kt < 4; ++kt) fpre[kt] = *(const bf16x8*)&wp[kt * 32];
    const u16* up = uobase + (size_t)(m0w + fq * 4) * DV + fr;
    u0pre.x = up[0]; u0pre.y = up[(size_t)DV];
    u0pre.z = up[(size_t)2 * DV]; u0pre.w = up[(size_t)3 * DV];
  } else {
    const u16* qp = qbase + (size_t)(m0w + fr) * DK + fq * 8;
#pragma unroll
    for (int kt = 0; kt < 4; ++kt) fpre[kt] = *(const bf16x8*)&qp[kt * 32];
    const u16* qkp = QKbase + (size_t)(m0w + fr) * CH + fq * 8;
    qkpre0 = *(const bf16x8*)&qkp[0];
    qkpre1 = *(const bf16x8*)&qkp[32];
  }
  __syncthreads();

  for (int c0 = 0; c0 < Lseq; c0 += CH) {
#pragma unroll
    for (int j = 0; j < 8; ++j) Kt[kd0 + j][kr0] = kpre0.u[j];
#pragma unroll
    for (int j = 0; j < 8; ++j) Kt[kd1 + j][kr1] = kpre1.u[j];

    bf16x8 fcur[4];
#pragma unroll
    for (int kt = 0; kt < 4; ++kt) fcur[kt] = fpre[kt];
    bf16x8 qkc0 = qkpre0, qkc1 = qkpre1;
    ushort4 u0c = u0pre;

    if (c0 + CH < Lseq) {
      const int cn = c0 + CH;
      kpre0 = *(const us8*)&kbase[(size_t)(cn + kr0) * DK + kd0];
      kpre1 = *(const us8*)&kbase[(size_t)(cn + kr1) * DK + kd1];
      if (wid < 4) {
        const u16* wp = Wbase + (size_t)(cn + m0w + fr) * DQH + fq * 8;
#pragma unroll
        for (int kt = 0; kt < 4; ++kt) fpre[kt] = *(const bf16x8*)&wp[kt * 32];
        const u16* up = uobase + (size_t)(cn + m0w + fq * 4) * DV + fr;
        u0pre.x = up[0]; u0pre.y = up[(size_t)DV];
        u0pre.z = up[(size_t)2 * DV]; u0pre.w = up[(size_t)3 * DV];
      } else {
        const u16* qp = qbase + (size_t)(cn + m0w + fr) * DK + fq * 8;
#pragma unroll
        for (int kt = 0; kt < 4; ++kt) fpre[kt] = *(const bf16x8*)&qp[kt * 32];
        const u16* qkp = QKbase + (size_t)(cn + m0w + fr) * CH + fq * 8;
        qkpre0 = *(const bf16x8*)&qkp[0];
        qkpre1 = *(const bf16x8*)&qkp[32];
      }
    }

    f32x4 acc;
    if (wid < 4) {
      // phase1: U = U0 + Wneg·(S_hi + S_lo) — full split precision (feeds S)
      acc[0] = b2f(u0c.x); acc[1] = b2f(u0c.y);
      acc[2] = b2f(u0c.z); acc[3] = b2f(u0c.w);
#pragma unroll
      for (int kt = 0; kt < 4; ++kt) {
        bf16x8 sh = *(const bf16x8*)&Sbt_hi[fr][kt * 32 + fq * 8];
        bf16x8 sl = *(const bf16x8*)&Sbt_lo[fr][kt * 32 + fq * 8];
        acc = __builtin_amdgcn_mfma_f32_16x16x32_bf16(fcur[kt], sh, acc, 0, 0, 0);
        acc = __builtin_amdgcn_mfma_f32_16x16x32_bf16(fcur[kt], sl, acc, 0, 0, 0);
      }
      ushort4 ub = {f2b(acc[0]), f2b(acc[1]), f2b(acc[2]), f2b(acc[3])};
      *(ushort4*)&Ubt[fr][m0w + fq * 4] = ub;
    } else {
      // phase2a: O = Q·S_hi (output-only path: no feedback, hi suffices)
      acc = (f32x4){0.f, 0.f, 0.f, 0.f};
#pragma unroll
      for (int kt = 0; kt < 4; ++kt) {
        bf16x8 sh = *(const bf16x8*)&Sbt_hi[fr][kt * 32 + fq * 8];
        acc = __builtin_amdgcn_mfma_f32_16x16x32_bf16(fcur[kt], sh, acc, 0, 0, 0);
      }
    }
    __syncthreads();

    if (wid >= 4) {
      bf16x8 uf0 = *(const bf16x8*)&Ubt[fr][fq * 8];
      bf16x8 uf1 = *(const bf16x8*)&Ubt[fr][32 + fq * 8];
      acc = __builtin_amdgcn_mfma_f32_16x16x32_bf16(qkc0, uf0, acc, 0, 0, 0);
      acc = __builtin_amdgcn_mfma_f32_16x16x32_bf16(qkc1, uf1, acc, 0, 0, 0);
      u16* op = uobase + (size_t)(c0 + m0w + fq * 4) * DV + fr;
      op[0] = f2b(acc[0]);
      op[(size_t)DV] = f2b(acc[1]);
      op[(size_t)2 * DV] = f2b(acc[2]);
      op[(size_t)3 * DV] = f2b(acc[3]);
    }
#pragma unroll
    for (int kt = 0; kt < 2; ++kt) {
      bf16x8 kf = *(const bf16x8*)&Kt[16 * wid + fr][kt * 32 + fq * 8];
      bf16x8 uf = *(const bf16x8*)&Ubt[fr][kt * 32 + fq * 8];
      Sfrag = __builtin_amdgcn_mfma_f32_16x16x32_bf16(kf, uf, Sfrag, 0, 0, 0);
    }
    ushort4 shv, slv;
#pragma unroll
    for (int i = 0; i < 4; ++i) {
      float s = Sfrag[i];
      u16 hpart = f2b(s);
      ((u16*)&shv)[i] = hpart;
      ((u16*)&slv)[i] = f2b(s - b2f(hpart));
    }
    *(ushort4*)&Sbt_hi[fr][16 * wid + fq * 4] = shv;
    *(ushort4*)&Sbt_lo[fr][16 * wid + fq * 4] = slv;
    __syncthreads();
  }
}

// ---- 6. gate ----
__global__ __launch_bounds__(256) void gate_kernel(
    const u16* og, const u16* __restrict__ g,
    const float* __restrict__ nw, u16* out) {
  int idx = blockIdx.x * 4 + (threadIdx.x >> 6), lane = threadIdx.x & 63;
  size_t base = (size_t)(idx >> 2) * DV + (size_t)(idx & 3) * DVH + (size_t)lane * 4;
  ushort4 o4 = *(const ushort4*)&og[base];
  float ox = b2f(o4.x), oy = b2f(o4.y), oz = b2f(o4.z), ow = b2f(o4.w);
  float ss = ox * ox + oy * oy + oz * oz + ow * ow;
#pragma unroll
  for (int off = 32; off; off >>= 1) ss += __shfl_xor(ss, off);
  float r = 1.f / sqrtf(ss * (1.f / DVH) + 1e-5f);
  ushort4 g4 = *(const ushort4*)&g[base];
  float gx = b2f(g4.x), gy = b2f(g4.y), gz = b2f(g4.z), gw = b2f(g4.w);
  float4 wv = *(const float4*)&nw[lane * 4];
  ushort4 res;
  res.x = f2b(ox * r * wv.x * (gx * sig_(gx)));
  res.y = f2b(oy * r * wv.y * (gy * sig_(gy)));
  res.z = f2b(oz * r * wv.z * (gz * sig_(gz)));
  res.w = f2b(ow * r * wv.w * (gw * sig_(gw)));
  *(ushort4*)&out[base] = res;
}

// ---- host ----
extern "C" void kernel_launch(void* const* d_in, const int* in_sizes, int n_in,
                              void* d_out, int out_size, void* d_ws, size_t ws_size,
                              hipStream_t stream) {
  (void)in_sizes; (void)n_in; (void)out_size;
  const float* x  = (const float*)d_in[0];
  const float* cw = (const float*)d_in[1];
  const float* Wq = (const float*)d_in[2];
  const float* Wk = (const float*)d_in[3];
  const float* Wv = (const float*)d_in[4];
  const float* Wb = (const float*)d_in[5];
  const float* Wg = (const float*)d_in[6];
  const float* nw = (const float*)d_in[7];
  const float* Wo = (const float*)d_in[8];
  float* out = (float*)d_out;   // f32 output

  u16* hb = (u16*)d_ws;                       // ROWS*Dm  bf16
  u16* qb = hb + (size_t)ROWS * Dm;           // ROWS*DK
  u16* kb = qb + (size_t)ROWS * DK;           // ROWS*DK
  u16* vb = kb + (size_t)ROWS * DK;           // ROWS*DV  (v -> U0 -> O; gate in-place)
  float* bbuf = (float*)(vb + (size_t)ROWS * DV);   // ROWS*H f32
  u16* Wbuf  = (u16*)(bbuf + (size_t)ROWS * H);     // 16*Lseq*DQH bf16 (negated)
  u16* QKbuf = Wbuf + (size_t)16 * Lseq * DQH;      // 16*Lseq*CH  bf16
  u16* wq16 = QKbuf + (size_t)16 * Lseq * CH;       // bf16 weights, TRANSPOSED [N][K]
  u16* wk16 = wq16 + (size_t)Dm * DK;
  u16* wv16 = wk16 + (size_t)Dm * DK;
  u16* wg16 = wv16 + (size_t)Dm * DV;
  u16* wo16 = wg16 + (size_t)Dm * DV;
  u16* gb = qb;                               // g reuses q+k region after scan

  const size_t need = (size_t)ROWS * (Dm + DK + DK + DV) * 2 + (size_t)ROWS * H * 4
                    + (size_t)16 * Lseq * (DQH + CH) * 2
                    + ((size_t)Dm * (DK * 2 + DV * 3)) * 2;
  if (ws_size < need) {
    ws_sentinel_kernel<<<1, 1, 0, stream>>>(out, (float)ws_size);
    return;
  }

  // weight convert + transpose: in [K][N] f32 -> out [N][K] bf16
  cvt_t_kernel<<<dim3(DK / 64, Dm / 32), 256, 0, stream>>>(Wq, wq16, DK, Dm);
  cvt_t_kernel<<<dim3(DK / 64, Dm / 32), 256, 0, stream>>>(Wk, wk16, DK, Dm);
  cvt_t_kernel<<<dim3(DV / 64, Dm / 32), 256, 0, stream>>>(Wv, wv16, DV, Dm);
  cvt_t_kernel<<<dim3(DV / 64, Dm / 32), 256, 0, stream>>>(Wg, wg16, DV, Dm);
  cvt_t_kernel<<<dim3(Dm / 64, DV / 32), 256, 0, stream>>>(Wo, wo16, Dm, DV);

  conv_silu_kernel<<<ROWS * Dm / 256, 256, 0, stream>>>(x, cw, hb);

  // q/k with fused l2norm (128-col tile == one head)
  gemm_mfma_kernel<2><<<(DK / 128) * (ROWS / 128), 256, 0, stream>>>(hb, wq16, qb, ROWS, DK, Dm);
  gemm_mfma_kernel<2><<<(DK / 128) * (ROWS / 128), 256, 0, stream>>>(hb, wk16, kb, ROWS, DK, Dm);
  gemm_mfma_kernel<0><<<(DV / 128) * (ROWS / 128), 256, 0, stream>>>(hb, wv16, vb, ROWS, DV, Dm);
  beta_kernel<<<ROWS / 4, 256, 0, stream>>>(hb, Wb, bbuf);

  delta_prep_kernel<<<1024, 256, 0, stream>>>(qb, kb, vb, bbuf, Wbuf, QKbuf);
  delta_scan_kernel<<<256, 512, 0, stream>>>(qb, kb, Wbuf, QKbuf, vb);

  gemm_mfma_kernel<0><<<(DV / 128) * (ROWS / 128), 256, 0, stream>>>(hb, wg16, gb, ROWS, DV, Dm);
  gate_kernel<<<ROWS * H / 4, 256, 0, stream>>>(vb, gb, nw, vb);

  gemm_mfma_kernel<1><<<(Dm / 128) * (ROWS / 128), 256, 0, stream>>>(vb, wo16, out, ROWS, Dm, DV);
}

// Round 17
// 537.914 us; speedup vs baseline: 1.8630x; 1.0287x over previous
//
#include <hip/hip_runtime.h>
#include <math.h>

constexpr int Lseq = 4096, Dm = 1024, H = 4, DK = 512, DV = 1024;
constexpr int DQH = 128, DVH = 256, CH = 64, ROWS = 4 * 4096;

typedef unsigned short u16;
struct alignas(16) us8 { u16 u[8]; };
typedef __attribute__((ext_vector_type(8))) short bf16x8;   // 8 bf16 (4 VGPRs)
typedef __attribute__((ext_vector_type(4))) float f32x4;

__device__ __forceinline__ float sig_(float x) { return 1.f / (1.f + expf(-x)); }
__device__ __forceinline__ float b2f(u16 u) {
  union { float f; unsigned v; } x; x.v = (unsigned)u << 16; return x.f;
}
__device__ __forceinline__ u16 f2b(float f) {   // round-to-nearest-even
  union { float f; unsigned v; } x; x.f = f;
  unsigned r = x.v + 0x7fffu + ((x.v >> 16) & 1u);
  return (u16)(r >> 16);
}
// async global->LDS, 16B per lane; lds dest = wave-uniform base + lane*16
__device__ __forceinline__ void gld16(const u16* g, u16* l) {
  __builtin_amdgcn_global_load_lds(
      (const __attribute__((address_space(1))) void*)g,
      (__attribute__((address_space(3))) void*)l, 16, 0, 0);
}

__global__ void ws_sentinel_kernel(float* out, float v) { out[0] = v; }

// ---- 0. f32 -> bf16 convert + TRANSPOSE: in[K][N] -> out[N][K] ----
__global__ __launch_bounds__(256) void cvt_t_kernel(
    const float* __restrict__ in, u16* __restrict__ out, int N, int K) {
  __shared__ u16 T[32][66];
  const int k0 = blockIdx.y * 32, n0 = blockIdx.x * 64;
  const int t = threadIdx.x;
#pragma unroll
  for (int i = 0; i < 8; ++i) {
    int idx = t + i * 256;
    int kk = idx >> 6, nn = idx & 63;
    T[kk][nn] = f2b(in[(size_t)(k0 + kk) * N + n0 + nn]);
  }
  __syncthreads();
#pragma unroll
  for (int i = 0; i < 8; ++i) {
    int idx = t + i * 256;
    int kk = idx & 31, nn = idx >> 5;
    out[(size_t)(n0 + nn) * K + k0 + kk] = T[kk][nn];
  }
}

// ---- 1. conv + silu -> bf16, VECTORIZED: 8 d-elements/thread ----
__global__ __launch_bounds__(256) void conv_silu_kernel(
    const float* __restrict__ x, const float* __restrict__ w, u16* __restrict__ h) {
  int idx = blockIdx.x * 256 + threadIdx.x;     // ROWS*128 total
  int d8 = (idx & 127) << 3;                    // d base (8 elems)
  int row = idx >> 7;                           // token row
  int l = row & (Lseq - 1), b = row >> 12;
  const float* xb = x + ((size_t)b << 22);
  float4 wv[8];
#pragma unroll
  for (int j = 0; j < 2; ++j) {                 // w[d8*4 .. d8*4+31]
    wv[j * 4 + 0] = *(const float4*)&w[d8 * 4 + j * 16 + 0];
    wv[j * 4 + 1] = *(const float4*)&w[d8 * 4 + j * 16 + 4];
    wv[j * 4 + 2] = *(const float4*)&w[d8 * 4 + j * 16 + 8];
    wv[j * 4 + 3] = *(const float4*)&w[d8 * 4 + j * 16 + 12];
  }
  float acc[8] = {0, 0, 0, 0, 0, 0, 0, 0};
#pragma unroll
  for (int i = 0; i < 4; ++i) {
    int li = l - 3 + i;
    if (li >= 0) {
      float4 x0 = *(const float4*)&xb[((size_t)li << 10) + d8];
      float4 x1 = *(const float4*)&xb[((size_t)li << 10) + d8 + 4];
      acc[0] = fmaf(((const float*)&wv[0])[i], x0.x, acc[0]);
      acc[1] = fmaf(((const float*)&wv[1])[i], x0.y, acc[1]);
      acc[2] = fmaf(((const float*)&wv[2])[i], x0.z, acc[2]);
      acc[3] = fmaf(((const float*)&wv[3])[i], x0.w, acc[3]);
      acc[4] = fmaf(((const float*)&wv[4])[i], x1.x, acc[4]);
      acc[5] = fmaf(((const float*)&wv[5])[i], x1.y, acc[5]);
      acc[6] = fmaf(((const float*)&wv[6])[i], x1.z, acc[6]);
      acc[7] = fmaf(((const float*)&wv[7])[i], x1.w, acc[7]);
    }
  }
  us8 o;
#pragma unroll
  for (int j = 0; j < 8; ++j) o.u[j] = f2b(acc[j] * sig_(acc[j]));
  *(us8*)&h[(size_t)row * Dm + d8] = o;
}

// ---- 2. MFMA GEMM, BK=64 + T2 XOR-swizzle (round-16 proven) ----
template <int MODE>
__global__ __launch_bounds__(256) void gemm_mfma_kernel(
    const u16* __restrict__ A, const u16* __restrict__ BT, void* __restrict__ Cv,
    int M, int N, int K) {
  __shared__ u16 As[128 * 64];
  __shared__ u16 Bs[128 * 64];
  const int tid = threadIdx.x;
  const int wid = tid >> 6, lane = tid & 63;
  const int wr = wid >> 1, wc = wid & 1;
  const int fr = lane & 15, fk = lane >> 4;
  const int nbx = N >> 7;
  const int bid = blockIdx.x, nwg = gridDim.x;
  const int swz = (bid & 7) * (nwg >> 3) + (bid >> 3);   // T1: nwg % 8 == 0
  const int row0 = (swz / nbx) * 128, col0 = (swz % nbx) * 128;

  int sr[4], sk[4];
#pragma unroll
  for (int i = 0; i < 4; ++i) {
    int s = i * 4 + wid;
    int r = s * 8 + (lane >> 3);
    sr[i] = r;
    sk[i] = ((lane & 7) ^ (r & 7)) << 3;
  }

  f32x4 acc[4][4];
#pragma unroll
  for (int i = 0; i < 4; ++i)
#pragma unroll
    for (int j = 0; j < 4; ++j) acc[i][j] = {0.f, 0.f, 0.f, 0.f};

  for (int k0 = 0; k0 < K; k0 += 64) {
#pragma unroll
    for (int i = 0; i < 4; ++i) {
      const int s = i * 4 + wid;
      gld16(&A[(size_t)(row0 + sr[i]) * K + k0 + sk[i]], &As[s * 512]);
      gld16(&BT[(size_t)(col0 + sr[i]) * K + k0 + sk[i]], &Bs[s * 512]);
    }
    __syncthreads();
#pragma unroll
    for (int kt = 0; kt < 2; ++kt) {
      bf16x8 af[4], bf[4];
#pragma unroll
      for (int mi = 0; mi < 4; ++mi) {
        int row = wr * 64 + mi * 16 + fr;
        af[mi] = *(const bf16x8*)&As[row * 64 + (((kt * 4 + fk) ^ (fr & 7)) << 3)];
      }
#pragma unroll
      for (int ni = 0; ni < 4; ++ni) {
        int row = wc * 64 + ni * 16 + fr;
        bf[ni] = *(const bf16x8*)&Bs[row * 64 + (((kt * 4 + fk) ^ (fr & 7)) << 3)];
      }
#pragma unroll
      for (int mi = 0; mi < 4; ++mi)
#pragma unroll
        for (int ni = 0; ni < 4; ++ni)
          acc[mi][ni] = __builtin_amdgcn_mfma_f32_16x16x32_bf16(
              af[mi], bf[ni], acc[mi][ni], 0, 0, 0);
    }
    __syncthreads();
  }

  if (MODE == 2) {   // fused per-row l2norm (128-col tile == one head)
    __shared__ float ssh[2][128];
#pragma unroll
    for (int mi = 0; mi < 4; ++mi)
#pragma unroll
      for (int r = 0; r < 4; ++r) {
        float p = 0.f;
#pragma unroll
        for (int ni = 0; ni < 4; ++ni) p += acc[mi][ni][r] * acc[mi][ni][r];
        p += __shfl_xor(p, 1); p += __shfl_xor(p, 2);
        p += __shfl_xor(p, 4); p += __shfl_xor(p, 8);
        if (fr == 0) ssh[wc][wr * 64 + mi * 16 + fk * 4 + r] = p;
      }
    __syncthreads();
#pragma unroll
    for (int mi = 0; mi < 4; ++mi)
#pragma unroll
      for (int r = 0; r < 4; ++r) {
        int ridx = wr * 64 + mi * 16 + fk * 4 + r;
        float sc = 1.f / fmaxf(sqrtf(ssh[0][ridx] + ssh[1][ridx]), 1e-12f);
#pragma unroll
        for (int ni = 0; ni < 4; ++ni) acc[mi][ni][r] *= sc;
      }
  }

#pragma unroll
  for (int mi = 0; mi < 4; ++mi)
#pragma unroll
    for (int ni = 0; ni < 4; ++ni) {
      int col = col0 + wc * 64 + ni * 16 + fr;
#pragma unroll
      for (int r = 0; r < 4; ++r) {
        int row = row0 + wr * 64 + mi * 16 + fk * 4 + r;
        if (MODE == 1) ((float*)Cv)[(size_t)row * N + col] = acc[mi][ni][r];
        else           ((u16*)Cv)[(size_t)row * N + col] = f2b(acc[mi][ni][r]);
      }
    }
}

// ---- 3. beta ----
__global__ __launch_bounds__(256) void beta_kernel(
    const u16* __restrict__ h, const float* __restrict__ Wb, float* __restrict__ beta) {
  int row = blockIdx.x * 4 + (threadIdx.x >> 6), lane = threadIdx.x & 63;
  const u16* hrow = h + (size_t)row * Dm;
  float a0 = 0, a1 = 0, a2 = 0, a3 = 0;
  for (int k0 = 0; k0 < Dm; k0 += 64) {
    float hv = b2f(hrow[k0 + lane]);
    float4 wv = *(const float4*)&Wb[(size_t)(k0 + lane) * 4];
    a0 = fmaf(hv, wv.x, a0); a1 = fmaf(hv, wv.y, a1);
    a2 = fmaf(hv, wv.z, a2); a3 = fmaf(hv, wv.w, a3);
  }
#pragma unroll
  for (int off = 32; off; off >>= 1) {
    a0 += __shfl_down(a0, off); a1 += __shfl_down(a1, off);
    a2 += __shfl_down(a2, off); a3 += __shfl_down(a3, off);
  }
  if (lane == 0) {
    int b = row >> 12, l = row & (Lseq - 1);
    beta[((size_t)(b * H + 0)) * Lseq + l] = sig_(a0);
    beta[((size_t)(b * H + 1)) * Lseq + l] = sig_(a1);
    beta[((size_t)(b * H + 2)) * Lseq + l] = sig_(a2);
    beta[((size_t)(b * H + 3)) * Lseq + l] = sig_(a3);
  }
}

// ---- 5a. delta prep (round-12 proven config) ----
__global__ __launch_bounds__(256) void delta_prep_kernel(
    const u16* __restrict__ q, const u16* __restrict__ k,
    u16* v, const float* __restrict__ beta,
    u16* __restrict__ Wout, u16* __restrict__ QKout) {
  __shared__ alignas(16) float Am[64][68];
  __shared__ alignas(16) float R[64][68];
  __shared__ float Bc[64];
  const int tid = threadIdx.x;
  const int wid = tid >> 6, lane = tid & 63;
  const int fr = lane & 15, fq = lane >> 4;
  const int bh = blockIdx.x >> 6, ch = blockIdx.x & 63;
  const int b = bh >> 2, hh = bh & 3;
  const int c0 = ch * CH;
  const u16* qbase = q + (size_t)b * Lseq * DK + hh * DQH;
  const u16* kbase = k + (size_t)b * Lseq * DK + hh * DQH;
  u16*       vbase = v + (size_t)b * Lseq * DV + hh * DVH;
  const float* bbase = beta + (size_t)bh * Lseq;
  u16* Wrow  = Wout  + ((size_t)bh * Lseq + c0) * DQH;
  u16* QKrow = QKout + ((size_t)bh * Lseq + c0) * CH;

  if (tid < 64) Bc[tid] = bbase[c0 + tid];
  __syncthreads();

  {   // G = K K^T, QKt = Q K^T via MFMA
    const int m0 = wid * 16;
    f32x4 accG[4], accQ[4];
#pragma unroll
    for (int ni = 0; ni < 4; ++ni) {
      accG[ni] = {0.f, 0.f, 0.f, 0.f};
      accQ[ni] = {0.f, 0.f, 0.f, 0.f};
    }
#pragma unroll
    for (int kt = 0; kt < 4; ++kt) {
      bf16x8 afk = *(const bf16x8*)&kbase[(size_t)(c0 + m0 + fr) * DK + kt * 32 + fq * 8];
      bf16x8 afq = *(const bf16x8*)&qbase[(size_t)(c0 + m0 + fr) * DK + kt * 32 + fq * 8];
#pragma unroll
      for (int ni = 0; ni < 4; ++ni) {
        bf16x8 bfk = *(const bf16x8*)&kbase[(size_t)(c0 + ni * 16 + fr) * DK + kt * 32 + fq * 8];
        accG[ni] = __builtin_amdgcn_mfma_f32_16x16x32_bf16(afk, bfk, accG[ni], 0, 0, 0);
        accQ[ni] = __builtin_amdgcn_mfma_f32_16x16x32_bf16(afq, bfk, accQ[ni], 0, 0, 0);
      }
    }
#pragma unroll
    for (int ni = 0; ni < 4; ++ni)
#pragma unroll
      for (int i = 0; i < 4; ++i) {
        int row = m0 + fq * 4 + i, col = ni * 16 + fr;
        float br = Bc[row];
        Am[row][col] = (col < row) ? br * accG[ni][i] : 0.f;
        QKrow[(size_t)row * CH + col] = f2b((col <= row) ? accQ[ni][i] : 0.f);
      }
  }
  __syncthreads();

  for (int p = 0; p < 6; ++p) {
    if (p < 2) {
      const int dbase = p * 64;
      for (int idx = tid; idx < 64 * 64; idx += 256) {
        int r = idx >> 6, d = idx & 63;
        R[r][d] = Bc[r] * b2f(kbase[(size_t)(c0 + r) * DK + dbase + d]);
      }
    } else {
      const int cbase = (p - 2) * 64;
      for (int idx = tid; idx < 64 * 64; idx += 256) {
        int r = idx >> 6, j = idx & 63;
        R[r][j] = Bc[r] * b2f(vbase[(size_t)(c0 + r) * DV + cbase + j]);
      }
    }
    __syncthreads();
    for (int rb = 0; rb < 4; ++rb) {   // blocked forward substitution
      if (rb > 0) {
        const int c = tid & 63, g = tid >> 6;
        const int R0 = rb * 16, row = R0 + g * 4;
        float s0 = 0, s1 = 0, s2 = 0, s3 = 0;
        for (int m = 0; m < R0; ++m) {
          float uv = R[m][c];
          s0 = fmaf(Am[row + 0][m], uv, s0);
          s1 = fmaf(Am[row + 1][m], uv, s1);
          s2 = fmaf(Am[row + 2][m], uv, s2);
          s3 = fmaf(Am[row + 3][m], uv, s3);
        }
        R[row + 0][c] -= s0; R[row + 1][c] -= s1;
        R[row + 2][c] -= s2; R[row + 3][c] -= s3;
      }
      __syncthreads();
      if (tid < 64) {
        const int c = tid;
        for (int i = 1; i < 16; ++i) {
          const int row = rb * 16 + i;
          float s = R[row][c];
          for (int m = 0; m < i; ++m)
            s = fmaf(-Am[row][rb * 16 + m], R[rb * 16 + m][c], s);
          R[row][c] = s;
        }
      }
      __syncthreads();
    }
    if (p < 2) {
      const int dbase = p * 64;
      for (int idx = tid; idx < 64 * 64; idx += 256) {
        int r = idx >> 6, d = idx & 63;
        Wrow[(size_t)r * DQH + dbase + d] = f2b(-R[r][d]);   // NEGATED
      }
    } else {
      const int cbase = (p - 2) * 64;
      for (int idx = tid; idx < 64 * 64; idx += 256) {
        int r = idx >> 6, j = idx & 63;
        vbase[(size_t)(c0 + r) * DV + cbase + j] = f2b(R[r][j]);
      }
    }
    __syncthreads();
  }
}

// ---- 5b. delta scan (round-12 base + T5 setprio + split MFMA chains) ----
__global__ __launch_bounds__(512) void delta_scan_kernel(
    const u16* __restrict__ q, const u16* __restrict__ k,
    const u16* __restrict__ Wb, const u16* __restrict__ QKb, u16* uo) {
  __shared__ alignas(16) u16 Kt[128][72];
  __shared__ alignas(16) u16 Sbt_hi[16][136];
  __shared__ alignas(16) u16 Sbt_lo[16][136];
  __shared__ alignas(16) u16 Ubt[16][72];
  const int tid = threadIdx.x;
  const int wid = tid >> 6, lane = tid & 63;
  const int fr = lane & 15, fq = lane >> 4;
  const int m0w = 16 * (wid & 3);
  const int bh = blockIdx.x & 15, vblk = blockIdx.x >> 4;   // XCD-local bh
  const int b = bh >> 2, hh = bh & 3;
  const u16* qbase = q + (size_t)b * Lseq * DK + hh * DQH;
  const u16* kbase = k + (size_t)b * Lseq * DK + hh * DQH;
  const u16* Wbase = Wb + (size_t)bh * Lseq * DQH;
  const u16* QKbase = QKb + (size_t)bh * Lseq * CH;
  u16* uobase = uo + (size_t)b * Lseq * DV + hh * DVH + vblk * 16;

  for (int i = tid; i < 16 * 136; i += 512) {
    (&Sbt_hi[0][0])[i] = 0; (&Sbt_lo[0][0])[i] = 0;
  }
  f32x4 Sfrag = {0.f, 0.f, 0.f, 0.f};

  const int kr0 = tid & 63, kd0 = (tid >> 6) << 3;
  const int kr1 = (tid + 512) & 63, kd1 = ((tid + 512) >> 6) << 3;

  us8 kpre0 = *(const us8*)&kbase[(size_t)kr0 * DK + kd0];
  us8 kpre1 = *(const us8*)&kbase[(size_t)kr1 * DK + kd1];
  bf16x8 fpre[4];
  bf16x8 qkpre0 = {}, qkpre1 = {};
  ushort4 u0pre = {};
  if (wid < 4) {
    const u16* wp = Wbase + (size_t)(m0w + fr) * DQH + fq * 8;
#pragma unroll
    for (int kt = 0; kt < 4; ++kt) fpre[kt] = *(const bf16x8*)&wp[kt * 32];
    const u16* up = uobase + (size_t)(m0w + fq * 4) * DV + fr;
    u0pre.x = up[0]; u0pre.y = up[(size_t)DV];
    u0pre.z = up[(size_t)2 * DV]; u0pre.w = up[(size_t)3 * DV];
  } else {
    const u16* qp = qbase + (size_t)(m0w + fr) * DK + fq * 8;
#pragma unroll
    for (int kt = 0; kt < 4; ++kt) fpre[kt] = *(const bf16x8*)&qp[kt * 32];
    const u16* qkp = QKbase + (size_t)(m0w + fr) * CH + fq * 8;
    qkpre0 = *(const bf16x8*)&qkp[0];
    qkpre1 = *(const bf16x8*)&qkp[32];
  }
  __syncthreads();

  for (int c0 = 0; c0 < Lseq; c0 += CH) {
#pragma unroll
    for (int j = 0; j < 8; ++j) Kt[kd0 + j][kr0] = kpre0.u[j];
#pragma unroll
    for (int j = 0; j < 8; ++j) Kt[kd1 + j][kr1] = kpre1.u[j];

    bf16x8 fcur[4];
#pragma unroll
    for (int kt = 0; kt < 4; ++kt) fcur[kt] = fpre[kt];
    bf16x8 qkc0 = qkpre0, qkc1 = qkpre1;
    ushort4 u0c = u0pre;

    if (c0 + CH < Lseq) {
      const int cn = c0 + CH;
      kpre0 = *(const us8*)&kbase[(size_t)(cn + kr0) * DK + kd0];
      kpre1 = *(const us8*)&kbase[(size_t)(cn + kr1) * DK + kd1];
      if (wid < 4) {
        const u16* wp = Wbase + (size_t)(cn + m0w + fr) * DQH + fq * 8;
#pragma unroll
        for (int kt = 0; kt < 4; ++kt) fpre[kt] = *(const bf16x8*)&wp[kt * 32];
        const u16* up = uobase + (size_t)(cn + m0w + fq * 4) * DV + fr;
        u0pre.x = up[0]; u0pre.y = up[(size_t)DV];
        u0pre.z = up[(size_t)2 * DV]; u0pre.w = up[(size_t)3 * DV];
      } else {
        const u16* qp = qbase + (size_t)(cn + m0w + fr) * DK + fq * 8;
#pragma unroll
        for (int kt = 0; kt < 4; ++kt) fpre[kt] = *(const bf16x8*)&qp[kt * 32];
        const u16* qkp = QKbase + (size_t)(cn + m0w + fr) * CH + fq * 8;
        qkpre0 = *(const bf16x8*)&qkp[0];
        qkpre1 = *(const bf16x8*)&qkp[32];
      }
    }

    f32x4 acc, accB;
    if (wid < 4) {
      // phase1: U = U0 + Wneg·(S_hi + S_lo), two independent chains
      acc[0] = b2f(u0c.x); acc[1] = b2f(u0c.y);
      acc[2] = b2f(u0c.z); acc[3] = b2f(u0c.w);
      accB = (f32x4){0.f, 0.f, 0.f, 0.f};
      __builtin_amdgcn_s_setprio(1);
#pragma unroll
      for (int kt = 0; kt < 2; ++kt) {
        bf16x8 sh = *(const bf16x8*)&Sbt_hi[fr][kt * 32 + fq * 8];
        bf16x8 sl = *(const bf16x8*)&Sbt_lo[fr][kt * 32 + fq * 8];
        acc = __builtin_amdgcn_mfma_f32_16x16x32_bf16(fcur[kt], sh, acc, 0, 0, 0);
        acc = __builtin_amdgcn_mfma_f32_16x16x32_bf16(fcur[kt], sl, acc, 0, 0, 0);
      }
#pragma unroll
      for (int kt = 2; kt < 4; ++kt) {
        bf16x8 sh = *(const bf16x8*)&Sbt_hi[fr][kt * 32 + fq * 8];
        bf16x8 sl = *(const bf16x8*)&Sbt_lo[fr][kt * 32 + fq * 8];
        accB = __builtin_amdgcn_mfma_f32_16x16x32_bf16(fcur[kt], sh, accB, 0, 0, 0);
        accB = __builtin_amdgcn_mfma_f32_16x16x32_bf16(fcur[kt], sl, accB, 0, 0, 0);
      }
      __builtin_amdgcn_s_setprio(0);
      ushort4 ub = {f2b(acc[0] + accB[0]), f2b(acc[1] + accB[1]),
                    f2b(acc[2] + accB[2]), f2b(acc[3] + accB[3])};
      *(ushort4*)&Ubt[fr][m0w + fq * 4] = ub;
    } else {
      // phase2a: O = Q·S_hi, two independent chains
      acc = (f32x4){0.f, 0.f, 0.f, 0.f};
      accB = (f32x4){0.f, 0.f, 0.f, 0.f};
#pragma unroll
      for (int kt = 0; kt < 2; ++kt) {
        bf16x8 sh = *(const bf16x8*)&Sbt_hi[fr][kt * 32 + fq * 8];
        acc = __builtin_amdgcn_mfma_f32_16x16x32_bf16(fcur[kt], sh, acc, 0, 0, 0);
      }
#pragma unroll
      for (int kt = 2; kt < 4; ++kt) {
        bf16x8 sh = *(const bf16x8*)&Sbt_hi[fr][kt * 32 + fq * 8];
        accB = __builtin_amdgcn_mfma_f32_16x16x32_bf16(fcur[kt], sh, accB, 0, 0, 0);
      }
    }
    __syncthreads();

    if (wid >= 4) {
      bf16x8 uf0 = *(const bf16x8*)&Ubt[fr][fq * 8];
      bf16x8 uf1 = *(const bf16x8*)&Ubt[fr][32 + fq * 8];
      acc  = __builtin_amdgcn_mfma_f32_16x16x32_bf16(qkc0, uf0, acc, 0, 0, 0);
      accB = __builtin_amdgcn_mfma_f32_16x16x32_bf16(qkc1, uf1, accB, 0, 0, 0);
      u16* op = uobase + (size_t)(c0 + m0w + fq * 4) * DV + fr;
      op[0] = f2b(acc[0] + accB[0]);
      op[(size_t)DV] = f2b(acc[1] + accB[1]);
      op[(size_t)2 * DV] = f2b(acc[2] + accB[2]);
      op[(size_t)3 * DV] = f2b(acc[3] + accB[3]);
    }
    __builtin_amdgcn_s_setprio(1);
#pragma unroll
    for (int kt = 0; kt < 2; ++kt) {
      bf16x8 kf = *(const bf16x8*)&Kt[16 * wid + fr][kt * 32 + fq * 8];
      bf16x8 uf = *(const bf16x8*)&Ubt[fr][kt * 32 + fq * 8];
      Sfrag = __builtin_amdgcn_mfma_f32_16x16x32_bf16(kf, uf, Sfrag, 0, 0, 0);
    }
    __builtin_amdgcn_s_setprio(0);
    ushort4 shv, slv;
#pragma unroll
    for (int i = 0; i < 4; ++i) {
      float s = Sfrag[i];
      u16 hpart = f2b(s);
      ((u16*)&shv)[i] = hpart;
      ((u16*)&slv)[i] = f2b(s - b2f(hpart));
    }
    *(ushort4*)&Sbt_hi[fr][16 * wid + fq * 4] = shv;
    *(ushort4*)&Sbt_lo[fr][16 * wid + fq * 4] = slv;
    __syncthreads();
  }
}

// ---- 6. gate ----
__global__ __launch_bounds__(256) void gate_kernel(
    const u16* og, const u16* __restrict__ g,
    const float* __restrict__ nw, u16* out) {
  int idx = blockIdx.x * 4 + (threadIdx.x >> 6), lane = threadIdx.x & 63;
  size_t base = (size_t)(idx >> 2) * DV + (size_t)(idx & 3) * DVH + (size_t)lane * 4;
  ushort4 o4 = *(const ushort4*)&og[base];
  float ox = b2f(o4.x), oy = b2f(o4.y), oz = b2f(o4.z), ow = b2f(o4.w);
  float ss = ox * ox + oy * oy + oz * oz + ow * ow;
#pragma unroll
  for (int off = 32; off; off >>= 1) ss += __shfl_xor(ss, off);
  float r = 1.f / sqrtf(ss * (1.f / DVH) + 1e-5f);
  ushort4 g4 = *(const ushort4*)&g[base];
  float gx = b2f(g4.x), gy = b2f(g4.y), gz = b2f(g4.z), gw = b2f(g4.w);
  float4 wv = *(const float4*)&nw[lane * 4];
  ushort4 res;
  res.x = f2b(ox * r * wv.x * (gx * sig_(gx)));
  res.y = f2b(oy * r * wv.y * (gy * sig_(gy)));
  res.z = f2b(oz * r * wv.z * (gz * sig_(gz)));
  res.w = f2b(ow * r * wv.w * (gw * sig_(gw)));
  *(ushort4*)&out[base] = res;
}

// ---- host ----
extern "C" void kernel_launch(void* const* d_in, const int* in_sizes, int n_in,
                              void* d_out, int out_size, void* d_ws, size_t ws_size,
                              hipStream_t stream) {
  (void)in_sizes; (void)n_in; (void)out_size;
  const float* x  = (const float*)d_in[0];
  const float* cw = (const float*)d_in[1];
  const float* Wq = (const float*)d_in[2];
  const float* Wk = (const float*)d_in[3];
  const float* Wv = (const float*)d_in[4];
  const float* Wb = (const float*)d_in[5];
  const float* Wg = (const float*)d_in[6];
  const float* nw = (const float*)d_in[7];
  const float* Wo = (const float*)d_in[8];
  float* out = (float*)d_out;   // f32 output

  u16* hb = (u16*)d_ws;                       // ROWS*Dm  bf16
  u16* qb = hb + (size_t)ROWS * Dm;           // ROWS*DK
  u16* kb = qb + (size_t)ROWS * DK;           // ROWS*DK
  u16* vb = kb + (size_t)ROWS * DK;           // ROWS*DV  (v -> U0 -> O; gate in-place)
  float* bbuf = (float*)(vb + (size_t)ROWS * DV);   // ROWS*H f32
  u16* Wbuf  = (u16*)(bbuf + (size_t)ROWS * H);     // 16*Lseq*DQH bf16 (negated)
  u16* QKbuf = Wbuf + (size_t)16 * Lseq * DQH;      // 16*Lseq*CH  bf16
  u16* wq16 = QKbuf + (size_t)16 * Lseq * CH;       // bf16 weights, TRANSPOSED [N][K]
  u16* wk16 = wq16 + (size_t)Dm * DK;
  u16* wv16 = wk16 + (size_t)Dm * DK;
  u16* wg16 = wv16 + (size_t)Dm * DV;
  u16* wo16 = wg16 + (size_t)Dm * DV;
  u16* gb = qb;                               // g reuses q+k region after scan

  const size_t need = (size_t)ROWS * (Dm + DK + DK + DV) * 2 + (size_t)ROWS * H * 4
                    + (size_t)16 * Lseq * (DQH + CH) * 2
                    + ((size_t)Dm * (DK * 2 + DV * 3)) * 2;
  if (ws_size < need) {
    ws_sentinel_kernel<<<1, 1, 0, stream>>>(out, (float)ws_size);
    return;
  }

  // weight convert + transpose: in [K][N] f32 -> out [N][K] bf16
  cvt_t_kernel<<<dim3(DK / 64, Dm / 32), 256, 0, stream>>>(Wq, wq16, DK, Dm);
  cvt_t_kernel<<<dim3(DK / 64, Dm / 32), 256, 0, stream>>>(Wk, wk16, DK, Dm);
  cvt_t_kernel<<<dim3(DV / 64, Dm / 32), 256, 0, stream>>>(Wv, wv16, DV, Dm);
  cvt_t_kernel<<<dim3(DV / 64, Dm / 32), 256, 0, stream>>>(Wg, wg16, DV, Dm);
  cvt_t_kernel<<<dim3(Dm / 64, DV / 32), 256, 0, stream>>>(Wo, wo16, Dm, DV);

  conv_silu_kernel<<<ROWS * Dm / 8 / 256, 256, 0, stream>>>(x, cw, hb);

  // q/k with fused l2norm (128-col tile == one head)
  gemm_mfma_kernel<2><<<(DK / 128) * (ROWS / 128), 256, 0, stream>>>(hb, wq16, qb, ROWS, DK, Dm);
  gemm_mfma_kernel<2><<<(DK / 128) * (ROWS / 128), 256, 0, stream>>>(hb, wk16, kb, ROWS, DK, Dm);
  gemm_mfma_kernel<0><<<(DV / 128) * (ROWS / 128), 256, 0, stream>>>(hb, wv16, vb, ROWS, DV, Dm);
  beta_kernel<<<ROWS / 4, 256, 0, stream>>>(hb, Wb, bbuf);

  delta_prep_kernel<<<1024, 256, 0, stream>>>(qb, kb, vb, bbuf, Wbuf, QKbuf);
  delta_scan_kernel<<<256, 512, 0, stream>>>(qb, kb, Wbuf, QKbuf, vb);

  gemm_mfma_kernel<0><<<(DV / 128) * (ROWS / 128), 256, 0, stream>>>(hb, wg16, gb, ROWS, DV, Dm);
  gate_kernel<<<ROWS * H / 4, 256, 0, stream>>>(vb, gb, nw, vb);

  gemm_mfma_kernel<1><<<(Dm / 128) * (ROWS / 128), 256, 0, stream>>>(vb, wo16, out, ROWS, Dm, DV);
}

// Round 18
// 517.699 us; speedup vs baseline: 1.9358x; 1.0390x over previous
//
#include <hip/hip_runtime.h>
#include <math.h>

constexpr int Lseq = 4096, Dm = 1024, H = 4, DK = 512, DV = 1024;
constexpr int DQH = 128, DVH = 256, CH = 64, ROWS = 4 * 4096;

typedef unsigned short u16;
struct alignas(16) us8 { u16 u[8]; };
typedef __attribute__((ext_vector_type(8))) short bf16x8;   // 8 bf16 (4 VGPRs)
typedef __attribute__((ext_vector_type(4))) float f32x4;

__device__ __forceinline__ float sig_(float x) { return 1.f / (1.f + expf(-x)); }
__device__ __forceinline__ float b2f(u16 u) {
  union { float f; unsigned v; } x; x.v = (unsigned)u << 16; return x.f;
}
__device__ __forceinline__ u16 f2b(float f) {   // round-to-nearest-even
  union { float f; unsigned v; } x; x.f = f;
  unsigned r = x.v + 0x7fffu + ((x.v >> 16) & 1u);
  return (u16)(r >> 16);
}
// async global->LDS, 16B per lane; lds dest = wave-uniform base + lane*16
__device__ __forceinline__ void gld16(const u16* g, u16* l) {
  __builtin_amdgcn_global_load_lds(
      (const __attribute__((address_space(1))) void*)g,
      (__attribute__((address_space(3))) void*)l, 16, 0, 0);
}

__global__ void ws_sentinel_kernel(float* out, float v) { out[0] = v; }

// ---- 0. f32 -> bf16 convert + TRANSPOSE: in[K][N] -> out[N][K] ----
__global__ __launch_bounds__(256) void cvt_t_kernel(
    const float* __restrict__ in, u16* __restrict__ out, int N, int K) {
  __shared__ u16 T[32][66];
  const int k0 = blockIdx.y * 32, n0 = blockIdx.x * 64;
  const int t = threadIdx.x;
#pragma unroll
  for (int i = 0; i < 8; ++i) {
    int idx = t + i * 256;
    int kk = idx >> 6, nn = idx & 63;
    T[kk][nn] = f2b(in[(size_t)(k0 + kk) * N + n0 + nn]);
  }
  __syncthreads();
#pragma unroll
  for (int i = 0; i < 8; ++i) {
    int idx = t + i * 256;
    int kk = idx & 31, nn = idx >> 5;
    out[(size_t)(n0 + nn) * K + k0 + kk] = T[kk][nn];
  }
}

// ---- 1. conv + silu -> bf16, VECTORIZED: 8 d-elements/thread ----
__global__ __launch_bounds__(256) void conv_silu_kernel(
    const float* __restrict__ x, const float* __restrict__ w, u16* __restrict__ h) {
  int idx = blockIdx.x * 256 + threadIdx.x;     // ROWS*128 total
  int d8 = (idx & 127) << 3;
  int row = idx >> 7;
  int l = row & (Lseq - 1), b = row >> 12;
  const float* xb = x + ((size_t)b << 22);
  float4 wv[8];
#pragma unroll
  for (int j = 0; j < 2; ++j) {
    wv[j * 4 + 0] = *(const float4*)&w[d8 * 4 + j * 16 + 0];
    wv[j * 4 + 1] = *(const float4*)&w[d8 * 4 + j * 16 + 4];
    wv[j * 4 + 2] = *(const float4*)&w[d8 * 4 + j * 16 + 8];
    wv[j * 4 + 3] = *(const float4*)&w[d8 * 4 + j * 16 + 12];
  }
  float acc[8] = {0, 0, 0, 0, 0, 0, 0, 0};
#pragma unroll
  for (int i = 0; i < 4; ++i) {
    int li = l - 3 + i;
    if (li >= 0) {
      float4 x0 = *(const float4*)&xb[((size_t)li << 10) + d8];
      float4 x1 = *(const float4*)&xb[((size_t)li << 10) + d8 + 4];
      acc[0] = fmaf(((const float*)&wv[0])[i], x0.x, acc[0]);
      acc[1] = fmaf(((const float*)&wv[1])[i], x0.y, acc[1]);
      acc[2] = fmaf(((const float*)&wv[2])[i], x0.z, acc[2]);
      acc[3] = fmaf(((const float*)&wv[3])[i], x0.w, acc[3]);
      acc[4] = fmaf(((const float*)&wv[4])[i], x1.x, acc[4]);
      acc[5] = fmaf(((const float*)&wv[5])[i], x1.y, acc[5]);
      acc[6] = fmaf(((const float*)&wv[6])[i], x1.z, acc[6]);
      acc[7] = fmaf(((const float*)&wv[7])[i], x1.w, acc[7]);
    }
  }
  us8 o;
#pragma unroll
  for (int j = 0; j < 8; ++j) o.u[j] = f2b(acc[j] * sig_(acc[j]));
  *(us8*)&h[(size_t)row * Dm + d8] = o;
}

// ---- 2. MFMA GEMM, BK=64 + T2 XOR-swizzle (round-16 proven) ----
template <int MODE>
__global__ __launch_bounds__(256) void gemm_mfma_kernel(
    const u16* __restrict__ A, const u16* __restrict__ BT, void* __restrict__ Cv,
    int M, int N, int K) {
  __shared__ u16 As[128 * 64];
  __shared__ u16 Bs[128 * 64];
  const int tid = threadIdx.x;
  const int wid = tid >> 6, lane = tid & 63;
  const int wr = wid >> 1, wc = wid & 1;
  const int fr = lane & 15, fk = lane >> 4;
  const int nbx = N >> 7;
  const int bid = blockIdx.x, nwg = gridDim.x;
  const int swz = (bid & 7) * (nwg >> 3) + (bid >> 3);   // T1: nwg % 8 == 0
  const int row0 = (swz / nbx) * 128, col0 = (swz % nbx) * 128;

  int sr[4], sk[4];
#pragma unroll
  for (int i = 0; i < 4; ++i) {
    int s = i * 4 + wid;
    int r = s * 8 + (lane >> 3);
    sr[i] = r;
    sk[i] = ((lane & 7) ^ (r & 7)) << 3;
  }

  f32x4 acc[4][4];
#pragma unroll
  for (int i = 0; i < 4; ++i)
#pragma unroll
    for (int j = 0; j < 4; ++j) acc[i][j] = {0.f, 0.f, 0.f, 0.f};

  for (int k0 = 0; k0 < K; k0 += 64) {
#pragma unroll
    for (int i = 0; i < 4; ++i) {
      const int s = i * 4 + wid;
      gld16(&A[(size_t)(row0 + sr[i]) * K + k0 + sk[i]], &As[s * 512]);
      gld16(&BT[(size_t)(col0 + sr[i]) * K + k0 + sk[i]], &Bs[s * 512]);
    }
    __syncthreads();
#pragma unroll
    for (int kt = 0; kt < 2; ++kt) {
      bf16x8 af[4], bf[4];
#pragma unroll
      for (int mi = 0; mi < 4; ++mi) {
        int row = wr * 64 + mi * 16 + fr;
        af[mi] = *(const bf16x8*)&As[row * 64 + (((kt * 4 + fk) ^ (fr & 7)) << 3)];
      }
#pragma unroll
      for (int ni = 0; ni < 4; ++ni) {
        int row = wc * 64 + ni * 16 + fr;
        bf[ni] = *(const bf16x8*)&Bs[row * 64 + (((kt * 4 + fk) ^ (fr & 7)) << 3)];
      }
#pragma unroll
      for (int mi = 0; mi < 4; ++mi)
#pragma unroll
        for (int ni = 0; ni < 4; ++ni)
          acc[mi][ni] = __builtin_amdgcn_mfma_f32_16x16x32_bf16(
              af[mi], bf[ni], acc[mi][ni], 0, 0, 0);
    }
    __syncthreads();
  }

  if (MODE == 2) {   // fused per-row l2norm (128-col tile == one head)
    __shared__ float ssh[2][128];
#pragma unroll
    for (int mi = 0; mi < 4; ++mi)
#pragma unroll
      for (int r = 0; r < 4; ++r) {
        float p = 0.f;
#pragma unroll
        for (int ni = 0; ni < 4; ++ni) p += acc[mi][ni][r] * acc[mi][ni][r];
        p += __shfl_xor(p, 1); p += __shfl_xor(p, 2);
        p += __shfl_xor(p, 4); p += __shfl_xor(p, 8);
        if (fr == 0) ssh[wc][wr * 64 + mi * 16 + fk * 4 + r] = p;
      }
    __syncthreads();
#pragma unroll
    for (int mi = 0; mi < 4; ++mi)
#pragma unroll
      for (int r = 0; r < 4; ++r) {
        int ridx = wr * 64 + mi * 16 + fk * 4 + r;
        float sc = 1.f / fmaxf(sqrtf(ssh[0][ridx] + ssh[1][ridx]), 1e-12f);
#pragma unroll
        for (int ni = 0; ni < 4; ++ni) acc[mi][ni][r] *= sc;
      }
  }

#pragma unroll
  for (int mi = 0; mi < 4; ++mi)
#pragma unroll
    for (int ni = 0; ni < 4; ++ni) {
      int col = col0 + wc * 64 + ni * 16 + fr;
#pragma unroll
      for (int r = 0; r < 4; ++r) {
        int row = row0 + wr * 64 + mi * 16 + fk * 4 + r;
        if (MODE == 1) ((float*)Cv)[(size_t)row * N + col] = acc[mi][ni][r];
        else           ((u16*)Cv)[(size_t)row * N + col] = f2b(acc[mi][ni][r]);
      }
    }
}

// ---- 3. beta ----
__global__ __launch_bounds__(256) void beta_kernel(
    const u16* __restrict__ h, const float* __restrict__ Wb, float* __restrict__ beta) {
  int row = blockIdx.x * 4 + (threadIdx.x >> 6), lane = threadIdx.x & 63;
  const u16* hrow = h + (size_t)row * Dm;
  float a0 = 0, a1 = 0, a2 = 0, a3 = 0;
  for (int k0 = 0; k0 < Dm; k0 += 64) {
    float hv = b2f(hrow[k0 + lane]);
    float4 wv = *(const float4*)&Wb[(size_t)(k0 + lane) * 4];
    a0 = fmaf(hv, wv.x, a0); a1 = fmaf(hv, wv.y, a1);
    a2 = fmaf(hv, wv.z, a2); a3 = fmaf(hv, wv.w, a3);
  }
#pragma unroll
  for (int off = 32; off; off >>= 1) {
    a0 += __shfl_down(a0, off); a1 += __shfl_down(a1, off);
    a2 += __shfl_down(a2, off); a3 += __shfl_down(a3, off);
  }
  if (lane == 0) {
    int b = row >> 12, l = row & (Lseq - 1);
    beta[((size_t)(b * H + 0)) * Lseq + l] = sig_(a0);
    beta[((size_t)(b * H + 1)) * Lseq + l] = sig_(a1);
    beta[((size_t)(b * H + 2)) * Lseq + l] = sig_(a2);
    beta[((size_t)(b * H + 3)) * Lseq + l] = sig_(a3);
  }
}

// ---- 5a. delta prep v2: solve T=(I+A)^-1 ONCE, apply via MFMA to 6 panels.
// W = -T·(βK) (negated), U0 = T·(βV) in-place over v, QK = tril(QK^T).
__global__ __launch_bounds__(256) void delta_prep_kernel(
    const u16* __restrict__ q, const u16* __restrict__ k,
    u16* v, const float* __restrict__ beta,
    u16* __restrict__ Wout, u16* __restrict__ QKout) {
  __shared__ alignas(16) char lds0[18432];   // Am f32[64][68] -> Th/Tl u16[64][72]
  __shared__ alignas(16) char lds1[18432];   // R  f32[64][68] -> XTh/XTl u16[64][72]
  __shared__ float Bc[64];
  float (*Am)[68] = (float(*)[68])lds0;
  float (*R)[68]  = (float(*)[68])lds1;
  u16 (*Th)[72]  = (u16(*)[72])lds0;
  u16 (*Tl)[72]  = (u16(*)[72])(lds0 + 9216);
  u16 (*XTh)[72] = (u16(*)[72])lds1;
  u16 (*XTl)[72] = (u16(*)[72])(lds1 + 9216);

  const int tid = threadIdx.x;
  const int wid = tid >> 6, lane = tid & 63;
  const int fr = lane & 15, fq = lane >> 4;
  const int bh = blockIdx.x >> 6, ch = blockIdx.x & 63;
  const int b = bh >> 2, hh = bh & 3;
  const int c0 = ch * CH;
  const u16* qbase = q + (size_t)b * Lseq * DK + hh * DQH;
  const u16* kbase = k + (size_t)b * Lseq * DK + hh * DQH;
  u16*       vbase = v + (size_t)b * Lseq * DV + hh * DVH;
  const float* bbase = beta + (size_t)bh * Lseq;
  u16* Wrow  = Wout  + ((size_t)bh * Lseq + c0) * DQH;
  u16* QKrow = QKout + ((size_t)bh * Lseq + c0) * CH;

  if (tid < 64) Bc[tid] = bbase[c0 + tid];
  // R := identity (independent of Bc)
  for (int idx = tid; idx < 64 * 64; idx += 256) {
    int r = idx >> 6, c = idx & 63;
    R[r][c] = (r == c) ? 1.f : 0.f;
  }
  __syncthreads();

  {   // Am = tril(beta*K K^T, -1); QK = tril(Q K^T) -> global, via MFMA
    const int m0 = wid * 16;
    f32x4 accG[4], accQ[4];
#pragma unroll
    for (int ni = 0; ni < 4; ++ni) {
      accG[ni] = {0.f, 0.f, 0.f, 0.f};
      accQ[ni] = {0.f, 0.f, 0.f, 0.f};
    }
#pragma unroll
    for (int kt = 0; kt < 4; ++kt) {
      bf16x8 afk = *(const bf16x8*)&kbase[(size_t)(c0 + m0 + fr) * DK + kt * 32 + fq * 8];
      bf16x8 afq = *(const bf16x8*)&qbase[(size_t)(c0 + m0 + fr) * DK + kt * 32 + fq * 8];
#pragma unroll
      for (int ni = 0; ni < 4; ++ni) {
        bf16x8 bfk = *(const bf16x8*)&kbase[(size_t)(c0 + ni * 16 + fr) * DK + kt * 32 + fq * 8];
        accG[ni] = __builtin_amdgcn_mfma_f32_16x16x32_bf16(afk, bfk, accG[ni], 0, 0, 0);
        accQ[ni] = __builtin_amdgcn_mfma_f32_16x16x32_bf16(afq, bfk, accQ[ni], 0, 0, 0);
      }
    }
#pragma unroll
    for (int ni = 0; ni < 4; ++ni)
#pragma unroll
      for (int i = 0; i < 4; ++i) {
        int row = m0 + fq * 4 + i, col = ni * 16 + fr;
        float br = Bc[row];
        Am[row][col] = (col < row) ? br * accG[ni][i] : 0.f;
        QKrow[(size_t)row * CH + col] = f2b((col <= row) ? accQ[ni][i] : 0.f);
      }
  }
  __syncthreads();

  // ---- solve (I+Am) T = I  (blocked forward substitution, one panel) ----
  for (int rb = 0; rb < 4; ++rb) {
    if (rb > 0) {
      const int c = tid & 63, g = tid >> 6;
      const int R0 = rb * 16, row = R0 + g * 4;
      float s0 = 0, s1 = 0, s2 = 0, s3 = 0;
      for (int m = 0; m < R0; ++m) {
        float uv = R[m][c];
        s0 = fmaf(Am[row + 0][m], uv, s0);
        s1 = fmaf(Am[row + 1][m], uv, s1);
        s2 = fmaf(Am[row + 2][m], uv, s2);
        s3 = fmaf(Am[row + 3][m], uv, s3);
      }
      R[row + 0][c] -= s0; R[row + 1][c] -= s1;
      R[row + 2][c] -= s2; R[row + 3][c] -= s3;
    }
    __syncthreads();
    if (tid < 64) {
      const int c = tid;
      for (int i = 1; i < 16; ++i) {
        const int row = rb * 16 + i;
        float s = R[row][c];
        for (int m = 0; m < i; ++m)
          s = fmaf(-Am[row][rb * 16 + m], R[rb * 16 + m][c], s);
        R[row][c] = s;
      }
    }
    __syncthreads();
  }

  // ---- convert T (in R) -> split bf16 Th/Tl (overwrites Am region) ----
  for (int idx = tid; idx < 64 * 64; idx += 256) {
    int r = idx >> 6, c = idx & 63;
    float tv = R[r][c];
    u16 hh2 = f2b(tv);
    Th[r][c] = hh2;
    Tl[r][c] = f2b(tv - b2f(hh2));
  }
  __syncthreads();   // Th/Tl visible; R region free for XT

  // ---- 6 panels: p<2 -> W (X=βK, negate), p>=2 -> U0 (X=βV, in-place) ----
  for (int p = 0; p < 6; ++p) {
    const int off = (p < 2) ? p * 64 : (p - 2) * 64;
    // fill X^T split bf16: XT[d/j][m]
    for (int idx = tid; idx < 64 * 64; idx += 256) {
      int d = idx & 63, m = idx >> 6;
      float xv;
      if (p < 2) xv = Bc[m] * b2f(kbase[(size_t)(c0 + m) * DK + off + d]);
      else       xv = Bc[m] * b2f(vbase[(size_t)(c0 + m) * DV + off + d]);
      u16 hh2 = f2b(xv);
      XTh[d][m] = hh2;
      XTl[d][m] = f2b(xv - b2f(hh2));
    }
    __syncthreads();
    // Y = T·X via MFMA: wave owns row-tile wid; M=N=K=64
    f32x4 acc[4];
#pragma unroll
    for (int tn = 0; tn < 4; ++tn) acc[tn] = {0.f, 0.f, 0.f, 0.f};
#pragma unroll
    for (int kt = 0; kt < 2; ++kt) {
      bf16x8 ah = *(const bf16x8*)&Th[wid * 16 + fr][kt * 32 + fq * 8];
      bf16x8 al = *(const bf16x8*)&Tl[wid * 16 + fr][kt * 32 + fq * 8];
#pragma unroll
      for (int tn = 0; tn < 4; ++tn) {
        bf16x8 xh = *(const bf16x8*)&XTh[tn * 16 + fr][kt * 32 + fq * 8];
        bf16x8 xl = *(const bf16x8*)&XTl[tn * 16 + fr][kt * 32 + fq * 8];
        acc[tn] = __builtin_amdgcn_mfma_f32_16x16x32_bf16(ah, xh, acc[tn], 0, 0, 0);
        acc[tn] = __builtin_amdgcn_mfma_f32_16x16x32_bf16(ah, xl, acc[tn], 0, 0, 0);
        acc[tn] = __builtin_amdgcn_mfma_f32_16x16x32_bf16(al, xh, acc[tn], 0, 0, 0);
      }
    }
    // store: D row = wid*16 + fq*4 + i, col = tn*16 + fr
#pragma unroll
    for (int tn = 0; tn < 4; ++tn)
#pragma unroll
      for (int i = 0; i < 4; ++i) {
        int row = wid * 16 + fq * 4 + i, col = tn * 16 + fr;
        if (p < 2) Wrow[(size_t)row * DQH + off + col] = f2b(-acc[tn][i]);
        else       vbase[(size_t)(c0 + row) * DV + off + col] = f2b(acc[tn][i]);
      }
    __syncthreads();   // all reads of XT done before next fill
  }
}

// ---- 5b. delta scan (round-17 proven: setprio + split chains) ----
__global__ __launch_bounds__(512) void delta_scan_kernel(
    const u16* __restrict__ q, const u16* __restrict__ k,
    const u16* __restrict__ Wb, const u16* __restrict__ QKb, u16* uo) {
  __shared__ alignas(16) u16 Kt[128][72];
  __shared__ alignas(16) u16 Sbt_hi[16][136];
  __shared__ alignas(16) u16 Sbt_lo[16][136];
  __shared__ alignas(16) u16 Ubt[16][72];
  const int tid = threadIdx.x;
  const int wid = tid >> 6, lane = tid & 63;
  const int fr = lane & 15, fq = lane >> 4;
  const int m0w = 16 * (wid & 3);
  const int bh = blockIdx.x & 15, vblk = blockIdx.x >> 4;   // XCD-local bh
  const int b = bh >> 2, hh = bh & 3;
  const u16* qbase = q + (size_t)b * Lseq * DK + hh * DQH;
  const u16* kbase = k + (size_t)b * Lseq * DK + hh * DQH;
  const u16* Wbase = Wb + (size_t)bh * Lseq * DQH;
  const u16* QKbase = QKb + (size_t)bh * Lseq * CH;
  u16* uobase = uo + (size_t)b * Lseq * DV + hh * DVH + vblk * 16;

  for (int i = tid; i < 16 * 136; i += 512) {
    (&Sbt_hi[0][0])[i] = 0; (&Sbt_lo[0][0])[i] = 0;
  }
  f32x4 Sfrag = {0.f, 0.f, 0.f, 0.f};

  const int kr0 = tid & 63, kd0 = (tid >> 6) << 3;
  const int kr1 = (tid + 512) & 63, kd1 = ((tid + 512) >> 6) << 3;

  us8 kpre0 = *(const us8*)&kbase[(size_t)kr0 * DK + kd0];
  us8 kpre1 = *(const us8*)&kbase[(size_t)kr1 * DK + kd1];
  bf16x8 fpre[4];
  bf16x8 qkpre0 = {}, qkpre1 = {};
  ushort4 u0pre = {};
  if (wid < 4) {
    const u16* wp = Wbase + (size_t)(m0w + fr) * DQH + fq * 8;
#pragma unroll
    for (int kt = 0; kt < 4; ++kt) fpre[kt] = *(const bf16x8*)&wp[kt * 32];
    const u16* up = uobase + (size_t)(m0w + fq * 4) * DV + fr;
    u0pre.x = up[0]; u0pre.y = up[(size_t)DV];
    u0pre.z = up[(size_t)2 * DV]; u0pre.w = up[(size_t)3 * DV];
  } else {
    const u16* qp = qbase + (size_t)(m0w + fr) * DK + fq * 8;
#pragma unroll
    for (int kt = 0; kt < 4; ++kt) fpre[kt] = *(const bf16x8*)&qp[kt * 32];
    const u16* qkp = QKbase + (size_t)(m0w + fr) * CH + fq * 8;
    qkpre0 = *(const bf16x8*)&qkp[0];
    qkpre1 = *(const bf16x8*)&qkp[32];
  }
  __syncthreads();

  for (int c0 = 0; c0 < Lseq; c0 += CH) {
#pragma unroll
    for (int j = 0; j < 8; ++j) Kt[kd0 + j][kr0] = kpre0.u[j];
#pragma unroll
    for (int j = 0; j < 8; ++j) Kt[kd1 + j][kr1] = kpre1.u[j];

    bf16x8 fcur[4];
#pragma unroll
    for (int kt = 0; kt < 4; ++kt) fcur[kt] = fpre[kt];
    bf16x8 qkc0 = qkpre0, qkc1 = qkpre1;
    ushort4 u0c = u0pre;

    if (c0 + CH < Lseq) {
      const int cn = c0 + CH;
      kpre0 = *(const us8*)&kbase[(size_t)(cn + kr0) * DK + kd0];
      kpre1 = *(const us8*)&kbase[(size_t)(cn + kr1) * DK + kd1];
      if (wid < 4) {
        const u16* wp = Wbase + (size_t)(cn + m0w + fr) * DQH + fq * 8;
#pragma unroll
        for (int kt = 0; kt < 4; ++kt) fpre[kt] = *(const bf16x8*)&wp[kt * 32];
        const u16* up = uobase + (size_t)(cn + m0w + fq * 4) * DV + fr;
        u0pre.x = up[0]; u0pre.y = up[(size_t)DV];
        u0pre.z = up[(size_t)2 * DV]; u0pre.w = up[(size_t)3 * DV];
      } else {
        const u16* qp = qbase + (size_t)(cn + m0w + fr) * DK + fq * 8;
#pragma unroll
        for (int kt = 0; kt < 4; ++kt) fpre[kt] = *(const bf16x8*)&qp[kt * 32];
        const u16* qkp = QKbase + (size_t)(cn + m0w + fr) * CH + fq * 8;
        qkpre0 = *(const bf16x8*)&qkp[0];
        qkpre1 = *(const bf16x8*)&qkp[32];
      }
    }

    f32x4 acc, accB;
    if (wid < 4) {
      acc[0] = b2f(u0c.x); acc[1] = b2f(u0c.y);
      acc[2] = b2f(u0c.z); acc[3] = b2f(u0c.w);
      accB = (f32x4){0.f, 0.f, 0.f, 0.f};
      __builtin_amdgcn_s_setprio(1);
#pragma unroll
      for (int kt = 0; kt < 2; ++kt) {
        bf16x8 sh = *(const bf16x8*)&Sbt_hi[fr][kt * 32 + fq * 8];
        bf16x8 sl = *(const bf16x8*)&Sbt_lo[fr][kt * 32 + fq * 8];
        acc = __builtin_amdgcn_mfma_f32_16x16x32_bf16(fcur[kt], sh, acc, 0, 0, 0);
        acc = __builtin_amdgcn_mfma_f32_16x16x32_bf16(fcur[kt], sl, acc, 0, 0, 0);
      }
#pragma unroll
      for (int kt = 2; kt < 4; ++kt) {
        bf16x8 sh = *(const bf16x8*)&Sbt_hi[fr][kt * 32 + fq * 8];
        bf16x8 sl = *(const bf16x8*)&Sbt_lo[fr][kt * 32 + fq * 8];
        accB = __builtin_amdgcn_mfma_f32_16x16x32_bf16(fcur[kt], sh, accB, 0, 0, 0);
        accB = __builtin_amdgcn_mfma_f32_16x16x32_bf16(fcur[kt], sl, accB, 0, 0, 0);
      }
      __builtin_amdgcn_s_setprio(0);
      ushort4 ub = {f2b(acc[0] + accB[0]), f2b(acc[1] + accB[1]),
                    f2b(acc[2] + accB[2]), f2b(acc[3] + accB[3])};
      *(ushort4*)&Ubt[fr][m0w + fq * 4] = ub;
    } else {
      acc = (f32x4){0.f, 0.f, 0.f, 0.f};
      accB = (f32x4){0.f, 0.f, 0.f, 0.f};
#pragma unroll
      for (int kt = 0; kt < 2; ++kt) {
        bf16x8 sh = *(const bf16x8*)&Sbt_hi[fr][kt * 32 + fq * 8];
        acc = __builtin_amdgcn_mfma_f32_16x16x32_bf16(fcur[kt], sh, acc, 0, 0, 0);
      }
#pragma unroll
      for (int kt = 2; kt < 4; ++kt) {
        bf16x8 sh = *(const bf16x8*)&Sbt_hi[fr][kt * 32 + fq * 8];
        accB = __builtin_amdgcn_mfma_f32_16x16x32_bf16(fcur[kt], sh, accB, 0, 0, 0);
      }
    }
    __syncthreads();

    if (wid >= 4) {
      bf16x8 uf0 = *(const bf16x8*)&Ubt[fr][fq * 8];
      bf16x8 uf1 = *(const bf16x8*)&Ubt[fr][32 + fq * 8];
      acc  = __builtin_amdgcn_mfma_f32_16x16x32_bf16(qkc0, uf0, acc, 0, 0, 0);
      accB = __builtin_amdgcn_mfma_f32_16x16x32_bf16(qkc1, uf1, accB, 0, 0, 0);
      u16* op = uobase + (size_t)(c0 + m0w + fq * 4) * DV + fr;
      op[0] = f2b(acc[0] + accB[0]);
      op[(size_t)DV] = f2b(acc[1] + accB[1]);
      op[(size_t)2 * DV] = f2b(acc[2] + accB[2]);
      op[(size_t)3 * DV] = f2b(acc[3] + accB[3]);
    }
    __builtin_amdgcn_s_setprio(1);
#pragma unroll
    for (int kt = 0; kt < 2; ++kt) {
      bf16x8 kf = *(const bf16x8*)&Kt[16 * wid + fr][kt * 32 + fq * 8];
      bf16x8 uf = *(const bf16x8*)&Ubt[fr][kt * 32 + fq * 8];
      Sfrag = __builtin_amdgcn_mfma_f32_16x16x32_bf16(kf, uf, Sfrag, 0, 0, 0);
    }
    __builtin_amdgcn_s_setprio(0);
    ushort4 shv, slv;
#pragma unroll
    for (int i = 0; i < 4; ++i) {
      float s = Sfrag[i];
      u16 hpart = f2b(s);
      ((u16*)&shv)[i] = hpart;
      ((u16*)&slv)[i] = f2b(s - b2f(hpart));
    }
    *(ushort4*)&Sbt_hi[fr][16 * wid + fq * 4] = shv;
    *(ushort4*)&Sbt_lo[fr][16 * wid + fq * 4] = slv;
    __syncthreads();
  }
}

// ---- 6. gate ----
__global__ __launch_bounds__(256) void gate_kernel(
    const u16* og, const u16* __restrict__ g,
    const float* __restrict__ nw, u16* out) {
  int idx = blockIdx.x * 4 + (threadIdx.x >> 6), lane = threadIdx.x & 63;
  size_t base = (size_t)(idx >> 2) * DV + (size_t)(idx & 3) * DVH + (size_t)lane * 4;
  ushort4 o4 = *(const ushort4*)&og[base];
  float ox = b2f(o4.x), oy = b2f(o4.y), oz = b2f(o4.z), ow = b2f(o4.w);
  float ss = ox * ox + oy * oy + oz * oz + ow * ow;
#pragma unroll
  for (int off = 32; off; off >>= 1) ss += __shfl_xor(ss, off);
  float r = 1.f / sqrtf(ss * (1.f / DVH) + 1e-5f);
  ushort4 g4 = *(const ushort4*)&g[base];
  float gx = b2f(g4.x), gy = b2f(g4.y), gz = b2f(g4.z), gw = b2f(g4.w);
  float4 wv = *(const float4*)&nw[lane * 4];
  ushort4 res;
  res.x = f2b(ox * r * wv.x * (gx * sig_(gx)));
  res.y = f2b(oy * r * wv.y * (gy * sig_(gy)));
  res.z = f2b(oz * r * wv.z * (gz * sig_(gz)));
  res.w = f2b(ow * r * wv.w * (gw * sig_(gw)));
  *(ushort4*)&out[base] = res;
}

// ---- host ----
extern "C" void kernel_launch(void* const* d_in, const int* in_sizes, int n_in,
                              void* d_out, int out_size, void* d_ws, size_t ws_size,
                              hipStream_t stream) {
  (void)in_sizes; (void)n_in; (void)out_size;
  const float* x  = (const float*)d_in[0];
  const float* cw = (const float*)d_in[1];
  const float* Wq = (const float*)d_in[2];
  const float* Wk = (const float*)d_in[3];
  const float* Wv = (const float*)d_in[4];
  const float* Wb = (const float*)d_in[5];
  const float* Wg = (const float*)d_in[6];
  const float* nw = (const float*)d_in[7];
  const float* Wo = (const float*)d_in[8];
  float* out = (float*)d_out;   // f32 output

  u16* hb = (u16*)d_ws;                       // ROWS*Dm  bf16
  u16* qb = hb + (size_t)ROWS * Dm;           // ROWS*DK
  u16* kb = qb + (size_t)ROWS * DK;           // ROWS*DK
  u16* vb = kb + (size_t)ROWS * DK;           // ROWS*DV  (v -> U0 -> O; gate in-place)
  float* bbuf = (float*)(vb + (size_t)ROWS * DV);   // ROWS*H f32
  u16* Wbuf  = (u16*)(bbuf + (size_t)ROWS * H);     // 16*Lseq*DQH bf16 (negated)
  u16* QKbuf = Wbuf + (size_t)16 * Lseq * DQH;      // 16*Lseq*CH  bf16
  u16* wq16 = QKbuf + (size_t)16 * Lseq * CH;       // bf16 weights, TRANSPOSED [N][K]
  u16* wk16 = wq16 + (size_t)Dm * DK;
  u16* wv16 = wk16 + (size_t)Dm * DK;
  u16* wg16 = wv16 + (size_t)Dm * DV;
  u16* wo16 = wg16 + (size_t)Dm * DV;
  u16* gb = qb;                               // g reuses q+k region after scan

  const size_t need = (size_t)ROWS * (Dm + DK + DK + DV) * 2 + (size_t)ROWS * H * 4
                    + (size_t)16 * Lseq * (DQH + CH) * 2
                    + ((size_t)Dm * (DK * 2 + DV * 3)) * 2;
  if (ws_size < need) {
    ws_sentinel_kernel<<<1, 1, 0, stream>>>(out, (float)ws_size);
    return;
  }

  // weight convert + transpose: in [K][N] f32 -> out [N][K] bf16
  cvt_t_kernel<<<dim3(DK / 64, Dm / 32), 256, 0, stream>>>(Wq, wq16, DK, Dm);
  cvt_t_kernel<<<dim3(DK / 64, Dm / 32), 256, 0, stream>>>(Wk, wk16, DK, Dm);
  cvt_t_kernel<<<dim3(DV / 64, Dm / 32), 256, 0, stream>>>(Wv, wv16, DV, Dm);
  cvt_t_kernel<<<dim3(DV / 64, Dm / 32), 256, 0, stream>>>(Wg, wg16, DV, Dm);
  cvt_t_kernel<<<dim3(Dm / 64, DV / 32), 256, 0, stream>>>(Wo, wo16, Dm, DV);

  conv_silu_kernel<<<ROWS * Dm / 8 / 256, 256, 0, stream>>>(x, cw, hb);

  // q/k with fused l2norm (128-col tile == one head)
  gemm_mfma_kernel<2><<<(DK / 128) * (ROWS / 128), 256, 0, stream>>>(hb, wq16, qb, ROWS, DK, Dm);
  gemm_mfma_kernel<2><<<(DK / 128) * (ROWS / 128), 256, 0, stream>>>(hb, wk16, kb, ROWS, DK, Dm);
  gemm_mfma_kernel<0><<<(DV / 128) * (ROWS / 128), 256, 0, stream>>>(hb, wv16, vb, ROWS, DV, Dm);
  beta_kernel<<<ROWS / 4, 256, 0, stream>>>(hb, Wb, bbuf);

  delta_prep_kernel<<<1024, 256, 0, stream>>>(qb, kb, vb, bbuf, Wbuf, QKbuf);
  delta_scan_kernel<<<256, 512, 0, stream>>>(qb, kb, Wbuf, QKbuf, vb);

  gemm_mfma_kernel<0><<<(DV / 128) * (ROWS / 128), 256, 0, stream>>>(hb, wg16, gb, ROWS, DV, Dm);
  gate_kernel<<<ROWS * H / 4, 256, 0, stream>>>(vb, gb, nw, vb);

  gemm_mfma_kernel<1><<<(Dm / 128) * (ROWS / 128), 256, 0, stream>>>(vb, wo16, out, ROWS, Dm, DV);
}

// Round 19
// 480.027 us; speedup vs baseline: 2.0877x; 1.0785x over previous
//
#include <hip/hip_runtime.h>
#include <math.h>

constexpr int Lseq = 4096, Dm = 1024, H = 4, DK = 512, DV = 1024;
constexpr int DQH = 128, DVH = 256, CH = 64, ROWS = 4 * 4096;

typedef unsigned short u16;
struct alignas(16) us8 { u16 u[8]; };
typedef __attribute__((ext_vector_type(8))) short bf16x8;   // 8 bf16 (4 VGPRs)
typedef __attribute__((ext_vector_type(4))) float f32x4;

__device__ __forceinline__ float sig_(float x) { return 1.f / (1.f + expf(-x)); }
__device__ __forceinline__ float b2f(u16 u) {
  union { float f; unsigned v; } x; x.v = (unsigned)u << 16; return x.f;
}
__device__ __forceinline__ u16 f2b(float f) {   // round-to-nearest-even
  union { float f; unsigned v; } x; x.f = f;
  unsigned r = x.v + 0x7fffu + ((x.v >> 16) & 1u);
  return (u16)(r >> 16);
}
__device__ __forceinline__ void gld16(const u16* g, u16* l) {
  __builtin_amdgcn_global_load_lds(
      (const __attribute__((address_space(1))) void*)g,
      (__attribute__((address_space(3))) void*)l, 16, 0, 0);
}

__global__ void ws_sentinel_kernel(float* out, float v) { out[0] = v; }

// ---- 0. f32 -> bf16 convert + TRANSPOSE, ALL 5 weights in one launch ----
__global__ __launch_bounds__(256) void cvt_all_kernel(
    const float* __restrict__ Wq, const float* __restrict__ Wk,
    const float* __restrict__ Wv, const float* __restrict__ Wg,
    const float* __restrict__ Wo,
    u16* wq16, u16* wk16, u16* wv16, u16* wg16, u16* wo16) {
  __shared__ u16 T[32][66];
  int bid = blockIdx.x;
  const float* in; u16* out; int N, K, b0;
  if (bid < 256)       { in = Wq; out = wq16; N = DK; K = Dm; b0 = bid; }
  else if (bid < 512)  { in = Wk; out = wk16; N = DK; K = Dm; b0 = bid - 256; }
  else if (bid < 1024) { in = Wv; out = wv16; N = DV; K = Dm; b0 = bid - 512; }
  else if (bid < 1536) { in = Wg; out = wg16; N = DV; K = Dm; b0 = bid - 1024; }
  else                 { in = Wo; out = wo16; N = Dm; K = DV; b0 = bid - 1536; }
  const int nbx = N / 64;
  const int k0 = (b0 / nbx) * 32, n0 = (b0 % nbx) * 64;
  const int t = threadIdx.x;
#pragma unroll
  for (int i = 0; i < 8; ++i) {
    int idx = t + i * 256;
    int kk = idx >> 6, nn = idx & 63;
    T[kk][nn] = f2b(in[(size_t)(k0 + kk) * N + n0 + nn]);
  }
  __syncthreads();
#pragma unroll
  for (int i = 0; i < 8; ++i) {
    int idx = t + i * 256;
    int kk = idx & 31, nn = idx >> 5;
    out[(size_t)(n0 + nn) * K + k0 + kk] = T[kk][nn];
  }
}

// ---- 1. conv + silu -> bf16, vectorized ----
__global__ __launch_bounds__(256) void conv_silu_kernel(
    const float* __restrict__ x, const float* __restrict__ w, u16* __restrict__ h) {
  int idx = blockIdx.x * 256 + threadIdx.x;
  int d8 = (idx & 127) << 3;
  int row = idx >> 7;
  int l = row & (Lseq - 1), b = row >> 12;
  const float* xb = x + ((size_t)b << 22);
  float4 wv[8];
#pragma unroll
  for (int j = 0; j < 2; ++j) {
    wv[j * 4 + 0] = *(const float4*)&w[d8 * 4 + j * 16 + 0];
    wv[j * 4 + 1] = *(const float4*)&w[d8 * 4 + j * 16 + 4];
    wv[j * 4 + 2] = *(const float4*)&w[d8 * 4 + j * 16 + 8];
    wv[j * 4 + 3] = *(const float4*)&w[d8 * 4 + j * 16 + 12];
  }
  float acc[8] = {0, 0, 0, 0, 0, 0, 0, 0};
#pragma unroll
  for (int i = 0; i < 4; ++i) {
    int li = l - 3 + i;
    if (li >= 0) {
      float4 x0 = *(const float4*)&xb[((size_t)li << 10) + d8];
      float4 x1 = *(const float4*)&xb[((size_t)li << 10) + d8 + 4];
      acc[0] = fmaf(((const float*)&wv[0])[i], x0.x, acc[0]);
      acc[1] = fmaf(((const float*)&wv[1])[i], x0.y, acc[1]);
      acc[2] = fmaf(((const float*)&wv[2])[i], x0.z, acc[2]);
      acc[3] = fmaf(((const float*)&wv[3])[i], x0.w, acc[3]);
      acc[4] = fmaf(((const float*)&wv[4])[i], x1.x, acc[4]);
      acc[5] = fmaf(((const float*)&wv[5])[i], x1.y, acc[5]);
      acc[6] = fmaf(((const float*)&wv[6])[i], x1.z, acc[6]);
      acc[7] = fmaf(((const float*)&wv[7])[i], x1.w, acc[7]);
    }
  }
  us8 o;
#pragma unroll
  for (int j = 0; j < 8; ++j) o.u[j] = f2b(acc[j] * sig_(acc[j]));
  *(us8*)&h[(size_t)row * Dm + d8] = o;
}

// ---- 2. MFMA GEMM, BK=64 + swizzle (round-16 proven), 256 thr ----
template <int MODE>
__global__ __launch_bounds__(256) void gemm_mfma_kernel(
    const u16* __restrict__ A, const u16* __restrict__ BT, void* __restrict__ Cv,
    int M, int N, int K) {
  __shared__ u16 As[128 * 64];
  __shared__ u16 Bs[128 * 64];
  const int tid = threadIdx.x;
  const int wid = tid >> 6, lane = tid & 63;
  const int wr = wid >> 1, wc = wid & 1;
  const int fr = lane & 15, fk = lane >> 4;
  const int nbx = N >> 7;
  const int bid = blockIdx.x, nwg = gridDim.x;
  const int swz = (bid & 7) * (nwg >> 3) + (bid >> 3);
  const int row0 = (swz / nbx) * 128, col0 = (swz % nbx) * 128;

  int sr[4], sk[4];
#pragma unroll
  for (int i = 0; i < 4; ++i) {
    int s = i * 4 + wid;
    int r = s * 8 + (lane >> 3);
    sr[i] = r;
    sk[i] = ((lane & 7) ^ (r & 7)) << 3;
  }

  f32x4 acc[4][4];
#pragma unroll
  for (int i = 0; i < 4; ++i)
#pragma unroll
    for (int j = 0; j < 4; ++j) acc[i][j] = {0.f, 0.f, 0.f, 0.f};

  for (int k0 = 0; k0 < K; k0 += 64) {
#pragma unroll
    for (int i = 0; i < 4; ++i) {
      const int s = i * 4 + wid;
      gld16(&A[(size_t)(row0 + sr[i]) * K + k0 + sk[i]], &As[s * 512]);
      gld16(&BT[(size_t)(col0 + sr[i]) * K + k0 + sk[i]], &Bs[s * 512]);
    }
    __syncthreads();
#pragma unroll
    for (int kt = 0; kt < 2; ++kt) {
      bf16x8 af[4], bf[4];
#pragma unroll
      for (int mi = 0; mi < 4; ++mi) {
        int row = wr * 64 + mi * 16 + fr;
        af[mi] = *(const bf16x8*)&As[row * 64 + (((kt * 4 + fk) ^ (fr & 7)) << 3)];
      }
#pragma unroll
      for (int ni = 0; ni < 4; ++ni) {
        int row = wc * 64 + ni * 16 + fr;
        bf[ni] = *(const bf16x8*)&Bs[row * 64 + (((kt * 4 + fk) ^ (fr & 7)) << 3)];
      }
#pragma unroll
      for (int mi = 0; mi < 4; ++mi)
#pragma unroll
        for (int ni = 0; ni < 4; ++ni)
          acc[mi][ni] = __builtin_amdgcn_mfma_f32_16x16x32_bf16(
              af[mi], bf[ni], acc[mi][ni], 0, 0, 0);
    }
    __syncthreads();
  }

  if (MODE == 2) {
    __shared__ float ssh[2][128];
#pragma unroll
    for (int mi = 0; mi < 4; ++mi)
#pragma unroll
      for (int r = 0; r < 4; ++r) {
        float p = 0.f;
#pragma unroll
        for (int ni = 0; ni < 4; ++ni) p += acc[mi][ni][r] * acc[mi][ni][r];
        p += __shfl_xor(p, 1); p += __shfl_xor(p, 2);
        p += __shfl_xor(p, 4); p += __shfl_xor(p, 8);
        if (fr == 0) ssh[wc][wr * 64 + mi * 16 + fk * 4 + r] = p;
      }
    __syncthreads();
#pragma unroll
    for (int mi = 0; mi < 4; ++mi)
#pragma unroll
      for (int r = 0; r < 4; ++r) {
        int ridx = wr * 64 + mi * 16 + fk * 4 + r;
        float sc = 1.f / fmaxf(sqrtf(ssh[0][ridx] + ssh[1][ridx]), 1e-12f);
#pragma unroll
        for (int ni = 0; ni < 4; ++ni) acc[mi][ni][r] *= sc;
      }
  }

#pragma unroll
  for (int mi = 0; mi < 4; ++mi)
#pragma unroll
    for (int ni = 0; ni < 4; ++ni) {
      int col = col0 + wc * 64 + ni * 16 + fr;
#pragma unroll
      for (int r = 0; r < 4; ++r) {
        int row = row0 + wr * 64 + mi * 16 + fk * 4 + r;
        if (MODE == 1) ((float*)Cv)[(size_t)row * N + col] = acc[mi][ni][r];
        else           ((u16*)Cv)[(size_t)row * N + col] = f2b(acc[mi][ni][r]);
      }
    }
}

// ---- 3. beta ----
__global__ __launch_bounds__(256) void beta_kernel(
    const u16* __restrict__ h, const float* __restrict__ Wb, float* __restrict__ beta) {
  int row = blockIdx.x * 4 + (threadIdx.x >> 6), lane = threadIdx.x & 63;
  const u16* hrow = h + (size_t)row * Dm;
  float a0 = 0, a1 = 0, a2 = 0, a3 = 0;
  for (int k0 = 0; k0 < Dm; k0 += 64) {
    float hv = b2f(hrow[k0 + lane]);
    float4 wv = *(const float4*)&Wb[(size_t)(k0 + lane) * 4];
    a0 = fmaf(hv, wv.x, a0); a1 = fmaf(hv, wv.y, a1);
    a2 = fmaf(hv, wv.z, a2); a3 = fmaf(hv, wv.w, a3);
  }
#pragma unroll
  for (int off = 32; off; off >>= 1) {
    a0 += __shfl_down(a0, off); a1 += __shfl_down(a1, off);
    a2 += __shfl_down(a2, off); a3 += __shfl_down(a3, off);
  }
  if (lane == 0) {
    int b = row >> 12, l = row & (Lseq - 1);
    beta[((size_t)(b * H + 0)) * Lseq + l] = sig_(a0);
    beta[((size_t)(b * H + 1)) * Lseq + l] = sig_(a1);
    beta[((size_t)(b * H + 2)) * Lseq + l] = sig_(a2);
    beta[((size_t)(b * H + 3)) * Lseq + l] = sig_(a3);
  }
}

// ---- 5a. delta prep v2 (round-18 proven) ----
__global__ __launch_bounds__(256) void delta_prep_kernel(
    const u16* __restrict__ q, const u16* __restrict__ k,
    u16* v, const float* __restrict__ beta,
    u16* __restrict__ Wout, u16* __restrict__ QKout) {
  __shared__ alignas(16) char lds0[18432];
  __shared__ alignas(16) char lds1[18432];
  __shared__ float Bc[64];
  float (*Am)[68] = (float(*)[68])lds0;
  float (*R)[68]  = (float(*)[68])lds1;
  u16 (*Th)[72]  = (u16(*)[72])lds0;
  u16 (*Tl)[72]  = (u16(*)[72])(lds0 + 9216);
  u16 (*XTh)[72] = (u16(*)[72])lds1;
  u16 (*XTl)[72] = (u16(*)[72])(lds1 + 9216);

  const int tid = threadIdx.x;
  const int wid = tid >> 6, lane = tid & 63;
  const int fr = lane & 15, fq = lane >> 4;
  const int bh = blockIdx.x >> 6, ch = blockIdx.x & 63;
  const int b = bh >> 2, hh = bh & 3;
  const int c0 = ch * CH;
  const u16* qbase = q + (size_t)b * Lseq * DK + hh * DQH;
  const u16* kbase = k + (size_t)b * Lseq * DK + hh * DQH;
  u16*       vbase = v + (size_t)b * Lseq * DV + hh * DVH;
  const float* bbase = beta + (size_t)bh * Lseq;
  u16* Wrow  = Wout  + ((size_t)bh * Lseq + c0) * DQH;
  u16* QKrow = QKout + ((size_t)bh * Lseq + c0) * CH;

  if (tid < 64) Bc[tid] = bbase[c0 + tid];
  for (int idx = tid; idx < 64 * 64; idx += 256) {
    int r = idx >> 6, c = idx & 63;
    R[r][c] = (r == c) ? 1.f : 0.f;
  }
  __syncthreads();

  {
    const int m0 = wid * 16;
    f32x4 accG[4], accQ[4];
#pragma unroll
    for (int ni = 0; ni < 4; ++ni) {
      accG[ni] = {0.f, 0.f, 0.f, 0.f};
      accQ[ni] = {0.f, 0.f, 0.f, 0.f};
    }
#pragma unroll
    for (int kt = 0; kt < 4; ++kt) {
      bf16x8 afk = *(const bf16x8*)&kbase[(size_t)(c0 + m0 + fr) * DK + kt * 32 + fq * 8];
      bf16x8 afq = *(const bf16x8*)&qbase[(size_t)(c0 + m0 + fr) * DK + kt * 32 + fq * 8];
#pragma unroll
      for (int ni = 0; ni < 4; ++ni) {
        bf16x8 bfk = *(const bf16x8*)&kbase[(size_t)(c0 + ni * 16 + fr) * DK + kt * 32 + fq * 8];
        accG[ni] = __builtin_amdgcn_mfma_f32_16x16x32_bf16(afk, bfk, accG[ni], 0, 0, 0);
        accQ[ni] = __builtin_amdgcn_mfma_f32_16x16x32_bf16(afq, bfk, accQ[ni], 0, 0, 0);
      }
    }
#pragma unroll
    for (int ni = 0; ni < 4; ++ni)
#pragma unroll
      for (int i = 0; i < 4; ++i) {
        int row = m0 + fq * 4 + i, col = ni * 16 + fr;
        float br = Bc[row];
        Am[row][col] = (col < row) ? br * accG[ni][i] : 0.f;
        QKrow[(size_t)row * CH + col] = f2b((col <= row) ? accQ[ni][i] : 0.f);
      }
  }
  __syncthreads();

  for (int rb = 0; rb < 4; ++rb) {
    if (rb > 0) {
      const int c = tid & 63, g = tid >> 6;
      const int R0 = rb * 16, row = R0 + g * 4;
      float s0 = 0, s1 = 0, s2 = 0, s3 = 0;
      for (int m = 0; m < R0; ++m) {
        float uv = R[m][c];
        s0 = fmaf(Am[row + 0][m], uv, s0);
        s1 = fmaf(Am[row + 1][m], uv, s1);
        s2 = fmaf(Am[row + 2][m], uv, s2);
        s3 = fmaf(Am[row + 3][m], uv, s3);
      }
      R[row + 0][c] -= s0; R[row + 1][c] -= s1;
      R[row + 2][c] -= s2; R[row + 3][c] -= s3;
    }
    __syncthreads();
    if (tid < 64) {
      const int c = tid;
      for (int i = 1; i < 16; ++i) {
        const int row = rb * 16 + i;
        float s = R[row][c];
        for (int m = 0; m < i; ++m)
          s = fmaf(-Am[row][rb * 16 + m], R[rb * 16 + m][c], s);
        R[row][c] = s;
      }
    }
    __syncthreads();
  }

  for (int idx = tid; idx < 64 * 64; idx += 256) {
    int r = idx >> 6, c = idx & 63;
    float tv = R[r][c];
    u16 hh2 = f2b(tv);
    Th[r][c] = hh2;
    Tl[r][c] = f2b(tv - b2f(hh2));
  }
  __syncthreads();

  for (int p = 0; p < 6; ++p) {
    const int off = (p < 2) ? p * 64 : (p - 2) * 64;
    for (int idx = tid; idx < 64 * 64; idx += 256) {
      int d = idx & 63, m = idx >> 6;
      float xv;
      if (p < 2) xv = Bc[m] * b2f(kbase[(size_t)(c0 + m) * DK + off + d]);
      else       xv = Bc[m] * b2f(vbase[(size_t)(c0 + m) * DV + off + d]);
      u16 hh2 = f2b(xv);
      XTh[d][m] = hh2;
      XTl[d][m] = f2b(xv - b2f(hh2));
    }
    __syncthreads();
    f32x4 acc[4];
#pragma unroll
    for (int tn = 0; tn < 4; ++tn) acc[tn] = {0.f, 0.f, 0.f, 0.f};
#pragma unroll
    for (int kt = 0; kt < 2; ++kt) {
      bf16x8 ah = *(const bf16x8*)&Th[wid * 16 + fr][kt * 32 + fq * 8];
      bf16x8 al = *(const bf16x8*)&Tl[wid * 16 + fr][kt * 32 + fq * 8];
#pragma unroll
      for (int tn = 0; tn < 4; ++tn) {
        bf16x8 xh = *(const bf16x8*)&XTh[tn * 16 + fr][kt * 32 + fq * 8];
        bf16x8 xl = *(const bf16x8*)&XTl[tn * 16 + fr][kt * 32 + fq * 8];
        acc[tn] = __builtin_amdgcn_mfma_f32_16x16x32_bf16(ah, xh, acc[tn], 0, 0, 0);
        acc[tn] = __builtin_amdgcn_mfma_f32_16x16x32_bf16(ah, xl, acc[tn], 0, 0, 0);
        acc[tn] = __builtin_amdgcn_mfma_f32_16x16x32_bf16(al, xh, acc[tn], 0, 0, 0);
      }
    }
#pragma unroll
    for (int tn = 0; tn < 4; ++tn)
#pragma unroll
      for (int i = 0; i < 4; ++i) {
        int row = wid * 16 + fq * 4 + i, col = tn * 16 + fr;
        if (p < 2) Wrow[(size_t)row * DQH + off + col] = f2b(-acc[tn][i]);
        else       vbase[(size_t)(c0 + row) * DV + off + col] = f2b(acc[tn][i]);
      }
    __syncthreads();
  }
}

// ---- scan body (round-17/18 proven), shared by standalone + fused kernels ----
__device__ __forceinline__ void scan_body(
    int sbid, const u16* __restrict__ q, const u16* __restrict__ k,
    const u16* __restrict__ Wb, const u16* __restrict__ QKb, u16* uo,
    u16 (*Kt)[72], u16 (*Sbt_hi)[136], u16 (*Sbt_lo)[136], u16 (*Ubt)[72]) {
  const int tid = threadIdx.x;
  const int wid = tid >> 6, lane = tid & 63;
  const int fr = lane & 15, fq = lane >> 4;
  const int m0w = 16 * (wid & 3);
  const int bh = sbid & 15, vblk = sbid >> 4;   // XCD-local bh
  const int b = bh >> 2, hh = bh & 3;
  const u16* qbase = q + (size_t)b * Lseq * DK + hh * DQH;
  const u16* kbase = k + (size_t)b * Lseq * DK + hh * DQH;
  const u16* Wbase = Wb + (size_t)bh * Lseq * DQH;
  const u16* QKbase = QKb + (size_t)bh * Lseq * CH;
  u16* uobase = uo + (size_t)b * Lseq * DV + hh * DVH + vblk * 16;

  for (int i = tid; i < 16 * 136; i += 512) {
    (&Sbt_hi[0][0])[i] = 0; (&Sbt_lo[0][0])[i] = 0;
  }
  f32x4 Sfrag = {0.f, 0.f, 0.f, 0.f};

  const int kr0 = tid & 63, kd0 = (tid >> 6) << 3;
  const int kr1 = (tid + 512) & 63, kd1 = ((tid + 512) >> 6) << 3;

  us8 kpre0 = *(const us8*)&kbase[(size_t)kr0 * DK + kd0];
  us8 kpre1 = *(const us8*)&kbase[(size_t)kr1 * DK + kd1];
  bf16x8 fpre[4];
  bf16x8 qkpre0 = {}, qkpre1 = {};
  ushort4 u0pre = {};
  if (wid < 4) {
    const u16* wp = Wbase + (size_t)(m0w + fr) * DQH + fq * 8;
#pragma unroll
    for (int kt = 0; kt < 4; ++kt) fpre[kt] = *(const bf16x8*)&wp[kt * 32];
    const u16* up = uobase + (size_t)(m0w + fq * 4) * DV + fr;
    u0pre.x = up[0]; u0pre.y = up[(size_t)DV];
    u0pre.z = up[(size_t)2 * DV]; u0pre.w = up[(size_t)3 * DV];
  } else {
    const u16* qp = qbase + (size_t)(m0w + fr) * DK + fq * 8;
#pragma unroll
    for (int kt = 0; kt < 4; ++kt) fpre[kt] = *(const bf16x8*)&qp[kt * 32];
    const u16* qkp = QKbase + (size_t)(m0w + fr) * CH + fq * 8;
    qkpre0 = *(const bf16x8*)&qkp[0];
    qkpre1 = *(const bf16x8*)&qkp[32];
  }
  __syncthreads();

  for (int c0 = 0; c0 < Lseq; c0 += CH) {
#pragma unroll
    for (int j = 0; j < 8; ++j) Kt[kd0 + j][kr0] = kpre0.u[j];
#pragma unroll
    for (int j = 0; j < 8; ++j) Kt[kd1 + j][kr1] = kpre1.u[j];

    bf16x8 fcur[4];
#pragma unroll
    for (int kt = 0; kt < 4; ++kt) fcur[kt] = fpre[kt];
    bf16x8 qkc0 = qkpre0, qkc1 = qkpre1;
    ushort4 u0c = u0pre;

    if (c0 + CH < Lseq) {
      const int cn = c0 + CH;
      kpre0 = *(const us8*)&kbase[(size_t)(cn + kr0) * DK + kd0];
      kpre1 = *(const us8*)&kbase[(size_t)(cn + kr1) * DK + kd1];
      if (wid < 4) {
        const u16* wp = Wbase + (size_t)(cn + m0w + fr) * DQH + fq * 8;
#pragma unroll
        for (int kt = 0; kt < 4; ++kt) fpre[kt] = *(const bf16x8*)&wp[kt * 32];
        const u16* up = uobase + (size_t)(cn + m0w + fq * 4) * DV + fr;
        u0pre.x = up[0]; u0pre.y = up[(size_t)DV];
        u0pre.z = up[(size_t)2 * DV]; u0pre.w = up[(size_t)3 * DV];
      } else {
        const u16* qp = qbase + (size_t)(cn + m0w + fr) * DK + fq * 8;
#pragma unroll
        for (int kt = 0; kt < 4; ++kt) fpre[kt] = *(const bf16x8*)&qp[kt * 32];
        const u16* qkp = QKbase + (size_t)(cn + m0w + fr) * CH + fq * 8;
        qkpre0 = *(const bf16x8*)&qkp[0];
        qkpre1 = *(const bf16x8*)&qkp[32];
      }
    }

    f32x4 acc, accB;
    if (wid < 4) {
      acc[0] = b2f(u0c.x); acc[1] = b2f(u0c.y);
      acc[2] = b2f(u0c.z); acc[3] = b2f(u0c.w);
      accB = (f32x4){0.f, 0.f, 0.f, 0.f};
      __builtin_amdgcn_s_setprio(1);
#pragma unroll
      for (int kt = 0; kt < 2; ++kt) {
        bf16x8 sh = *(const bf16x8*)&Sbt_hi[fr][kt * 32 + fq * 8];
        bf16x8 sl = *(const bf16x8*)&Sbt_lo[fr][kt * 32 + fq * 8];
        acc = __builtin_amdgcn_mfma_f32_16x16x32_bf16(fcur[kt], sh, acc, 0, 0, 0);
        acc = __builtin_amdgcn_mfma_f32_16x16x32_bf16(fcur[kt], sl, acc, 0, 0, 0);
      }
#pragma unroll
      for (int kt = 2; kt < 4; ++kt) {
        bf16x8 sh = *(const bf16x8*)&Sbt_hi[fr][kt * 32 + fq * 8];
        bf16x8 sl = *(const bf16x8*)&Sbt_lo[fr][kt * 32 + fq * 8];
        accB = __builtin_amdgcn_mfma_f32_16x16x32_bf16(fcur[kt], sh, accB, 0, 0, 0);
        accB = __builtin_amdgcn_mfma_f32_16x16x32_bf16(fcur[kt], sl, accB, 0, 0, 0);
      }
      __builtin_amdgcn_s_setprio(0);
      ushort4 ub = {f2b(acc[0] + accB[0]), f2b(acc[1] + accB[1]),
                    f2b(acc[2] + accB[2]), f2b(acc[3] + accB[3])};
      *(ushort4*)&Ubt[fr][m0w + fq * 4] = ub;
    } else {
      acc = (f32x4){0.f, 0.f, 0.f, 0.f};
      accB = (f32x4){0.f, 0.f, 0.f, 0.f};
#pragma unroll
      for (int kt = 0; kt < 2; ++kt) {
        bf16x8 sh = *(const bf16x8*)&Sbt_hi[fr][kt * 32 + fq * 8];
        acc = __builtin_amdgcn_mfma_f32_16x16x32_bf16(fcur[kt], sh, acc, 0, 0, 0);
      }
#pragma unroll
      for (int kt = 2; kt < 4; ++kt) {
        bf16x8 sh = *(const bf16x8*)&Sbt_hi[fr][kt * 32 + fq * 8];
        accB = __builtin_amdgcn_mfma_f32_16x16x32_bf16(fcur[kt], sh, accB, 0, 0, 0);
      }
    }
    __syncthreads();

    if (wid >= 4) {
      bf16x8 uf0 = *(const bf16x8*)&Ubt[fr][fq * 8];
      bf16x8 uf1 = *(const bf16x8*)&Ubt[fr][32 + fq * 8];
      acc  = __builtin_amdgcn_mfma_f32_16x16x32_bf16(qkc0, uf0, acc, 0, 0, 0);
      accB = __builtin_amdgcn_mfma_f32_16x16x32_bf16(qkc1, uf1, accB, 0, 0, 0);
      u16* op = uobase + (size_t)(c0 + m0w + fq * 4) * DV + fr;
      op[0] = f2b(acc[0] + accB[0]);
      op[(size_t)DV] = f2b(acc[1] + accB[1]);
      op[(size_t)2 * DV] = f2b(acc[2] + accB[2]);
      op[(size_t)3 * DV] = f2b(acc[3] + accB[3]);
    }
    __builtin_amdgcn_s_setprio(1);
#pragma unroll
    for (int kt = 0; kt < 2; ++kt) {
      bf16x8 kf = *(const bf16x8*)&Kt[16 * wid + fr][kt * 32 + fq * 8];
      bf16x8 uf = *(const bf16x8*)&Ubt[fr][kt * 32 + fq * 8];
      Sfrag = __builtin_amdgcn_mfma_f32_16x16x32_bf16(kf, uf, Sfrag, 0, 0, 0);
    }
    __builtin_amdgcn_s_setprio(0);
    ushort4 shv, slv;
#pragma unroll
    for (int i = 0; i < 4; ++i) {
      float s = Sfrag[i];
      u16 hpart = f2b(s);
      ((u16*)&shv)[i] = hpart;
      ((u16*)&slv)[i] = f2b(s - b2f(hpart));
    }
    *(ushort4*)&Sbt_hi[fr][16 * wid + fq * 4] = shv;
    *(ushort4*)&Sbt_lo[fr][16 * wid + fq * 4] = slv;
    __syncthreads();
  }
}

// ---- 5b standalone scan (fallback path) ----
__global__ __launch_bounds__(512) void delta_scan_kernel(
    const u16* __restrict__ q, const u16* __restrict__ k,
    const u16* __restrict__ Wb, const u16* __restrict__ QKb, u16* uo) {
  __shared__ alignas(16) u16 Kt[128][72];
  __shared__ alignas(16) u16 Sbt_hi[16][136];
  __shared__ alignas(16) u16 Sbt_lo[16][136];
  __shared__ alignas(16) u16 Ubt[16][72];
  scan_body(blockIdx.x, q, k, Wb, QKb, uo, Kt, Sbt_hi, Sbt_lo, Ubt);
}

// ---- 5c FUSED: blocks 0-255 scan; blocks 256-1279 Wg GEMM (512 thr, 8 waves) ----
__global__ __launch_bounds__(512) void scan_wg_kernel(
    const u16* __restrict__ q, const u16* __restrict__ k,
    const u16* __restrict__ Wb, const u16* __restrict__ QKb, u16* uo,
    const u16* __restrict__ A, const u16* __restrict__ BT, u16* __restrict__ C) {
  __shared__ alignas(16) u16 Kt[128][72];
  __shared__ alignas(16) u16 Sbt_hi[16][136];
  __shared__ alignas(16) u16 Sbt_lo[16][136];
  __shared__ alignas(16) u16 Ubt[16][72];
  __shared__ u16 As[128 * 64];
  __shared__ u16 Bs[128 * 64];

  if (blockIdx.x < 256) {
    scan_body(blockIdx.x, q, k, Wb, QKb, uo, Kt, Sbt_hi, Sbt_lo, Ubt);
    return;
  }
  // ---- Wg GEMM: C[ROWS][DV] = A[ROWS][Dm] @ BT[DV][Dm]^T, bf16 out ----
  const int tid = threadIdx.x;
  const int wid = tid >> 6, lane = tid & 63;
  const int wr = wid >> 2, wc = wid & 3;       // 2x4 wave grid, 64x32 tiles
  const int fr = lane & 15, fk = lane >> 4;
  const int nbx = DV >> 7;                     // 8
  const int gbid = blockIdx.x - 256, nwg = 1024;
  const int swz = (gbid & 7) * (nwg >> 3) + (gbid >> 3);
  const int row0 = (swz / nbx) * 128, col0 = (swz % nbx) * 128;

  int sr[2], sk[2];
#pragma unroll
  for (int i = 0; i < 2; ++i) {
    int s = i * 8 + wid;
    int r = s * 8 + (lane >> 3);
    sr[i] = r;
    sk[i] = ((lane & 7) ^ (r & 7)) << 3;
  }

  f32x4 acc[4][2];
#pragma unroll
  for (int i = 0; i < 4; ++i)
#pragma unroll
    for (int j = 0; j < 2; ++j) acc[i][j] = {0.f, 0.f, 0.f, 0.f};

  for (int k0 = 0; k0 < Dm; k0 += 64) {
#pragma unroll
    for (int i = 0; i < 2; ++i) {
      const int s = i * 8 + wid;
      gld16(&A[(size_t)(row0 + sr[i]) * Dm + k0 + sk[i]], &As[s * 512]);
      gld16(&BT[(size_t)(col0 + sr[i]) * Dm + k0 + sk[i]], &Bs[s * 512]);
    }
    __syncthreads();
#pragma unroll
    for (int kt = 0; kt < 2; ++kt) {
      bf16x8 af[4], bf[2];
#pragma unroll
      for (int mi = 0; mi < 4; ++mi) {
        int row = wr * 64 + mi * 16 + fr;
        af[mi] = *(const bf16x8*)&As[row * 64 + (((kt * 4 + fk) ^ (fr & 7)) << 3)];
      }
#pragma unroll
      for (int ni = 0; ni < 2; ++ni) {
        int row = wc * 32 + ni * 16 + fr;
        bf[ni] = *(const bf16x8*)&Bs[row * 64 + (((kt * 4 + fk) ^ (fr & 7)) << 3)];
      }
#pragma unroll
      for (int mi = 0; mi < 4; ++mi)
#pragma unroll
        for (int ni = 0; ni < 2; ++ni)
          acc[mi][ni] = __builtin_amdgcn_mfma_f32_16x16x32_bf16(
              af[mi], bf[ni], acc[mi][ni], 0, 0, 0);
    }
    __syncthreads();
  }
#pragma unroll
  for (int mi = 0; mi < 4; ++mi)
#pragma unroll
    for (int ni = 0; ni < 2; ++ni) {
      int col = col0 + wc * 32 + ni * 16 + fr;
#pragma unroll
      for (int r = 0; r < 4; ++r) {
        int row = row0 + wr * 64 + mi * 16 + fk * 4 + r;
        C[(size_t)row * DV + col] = f2b(acc[mi][ni][r]);
      }
    }
}

// ---- 6. gate ----
__global__ __launch_bounds__(256) void gate_kernel(
    const u16* og, const u16* __restrict__ g,
    const float* __restrict__ nw, u16* out) {
  int idx = blockIdx.x * 4 + (threadIdx.x >> 6), lane = threadIdx.x & 63;
  size_t base = (size_t)(idx >> 2) * DV + (size_t)(idx & 3) * DVH + (size_t)lane * 4;
  ushort4 o4 = *(const ushort4*)&og[base];
  float ox = b2f(o4.x), oy = b2f(o4.y), oz = b2f(o4.z), ow = b2f(o4.w);
  float ss = ox * ox + oy * oy + oz * oz + ow * ow;
#pragma unroll
  for (int off = 32; off; off >>= 1) ss += __shfl_xor(ss, off);
  float r = 1.f / sqrtf(ss * (1.f / DVH) + 1e-5f);
  ushort4 g4 = *(const ushort4*)&g[base];
  float gx = b2f(g4.x), gy = b2f(g4.y), gz = b2f(g4.z), gw = b2f(g4.w);
  float4 wv = *(const float4*)&nw[lane * 4];
  ushort4 res;
  res.x = f2b(ox * r * wv.x * (gx * sig_(gx)));
  res.y = f2b(oy * r * wv.y * (gy * sig_(gy)));
  res.z = f2b(oz * r * wv.z * (gz * sig_(gz)));
  res.w = f2b(ow * r * wv.w * (gw * sig_(gw)));
  *(ushort4*)&out[base] = res;
}

// ---- host ----
extern "C" void kernel_launch(void* const* d_in, const int* in_sizes, int n_in,
                              void* d_out, int out_size, void* d_ws, size_t ws_size,
                              hipStream_t stream) {
  (void)in_sizes; (void)n_in; (void)out_size;
  const float* x  = (const float*)d_in[0];
  const float* cw = (const float*)d_in[1];
  const float* Wq = (const float*)d_in[2];
  const float* Wk = (const float*)d_in[3];
  const float* Wv = (const float*)d_in[4];
  const float* Wb = (const float*)d_in[5];
  const float* Wg = (const float*)d_in[6];
  const float* nw = (const float*)d_in[7];
  const float* Wo = (const float*)d_in[8];
  float* out = (float*)d_out;   // f32 output

  u16* hb = (u16*)d_ws;                       // ROWS*Dm  bf16
  u16* qb = hb + (size_t)ROWS * Dm;           // ROWS*DK
  u16* kb = qb + (size_t)ROWS * DK;           // ROWS*DK
  u16* vb = kb + (size_t)ROWS * DK;           // ROWS*DV  (v -> U0 -> O; gate in-place)
  float* bbuf = (float*)(vb + (size_t)ROWS * DV);   // ROWS*H f32
  u16* Wbuf  = (u16*)(bbuf + (size_t)ROWS * H);     // 16*Lseq*DQH bf16 (negated)
  u16* QKbuf = Wbuf + (size_t)16 * Lseq * DQH;      // 16*Lseq*CH  bf16
  u16* wq16 = QKbuf + (size_t)16 * Lseq * CH;       // bf16 weights, TRANSPOSED [N][K]
  u16* wk16 = wq16 + (size_t)Dm * DK;
  u16* wv16 = wk16 + (size_t)Dm * DK;
  u16* wg16 = wv16 + (size_t)Dm * DV;
  u16* wo16 = wg16 + (size_t)Dm * DV;
  u16* gb2  = wo16 + (size_t)DV * Dm;               // separate g buffer (fused path)
  u16* gb   = qb;                                   // aliased g buffer (fallback)

  const size_t need = (size_t)ROWS * (Dm + DK + DK + DV) * 2 + (size_t)ROWS * H * 4
                    + (size_t)16 * Lseq * (DQH + CH) * 2
                    + ((size_t)Dm * (DK * 2 + DV * 3)) * 2;
  const size_t need2 = need + (size_t)ROWS * DV * 2;
  if (ws_size < need) {
    ws_sentinel_kernel<<<1, 1, 0, stream>>>(out, (float)ws_size);
    return;
  }
  const bool fused = (ws_size >= need2);

  cvt_all_kernel<<<2048, 256, 0, stream>>>(Wq, Wk, Wv, Wg, Wo,
                                           wq16, wk16, wv16, wg16, wo16);
  conv_silu_kernel<<<ROWS * Dm / 8 / 256, 256, 0, stream>>>(x, cw, hb);

  gemm_mfma_kernel<2><<<(DK / 128) * (ROWS / 128), 256, 0, stream>>>(hb, wq16, qb, ROWS, DK, Dm);
  gemm_mfma_kernel<2><<<(DK / 128) * (ROWS / 128), 256, 0, stream>>>(hb, wk16, kb, ROWS, DK, Dm);
  gemm_mfma_kernel<0><<<(DV / 128) * (ROWS / 128), 256, 0, stream>>>(hb, wv16, vb, ROWS, DV, Dm);
  beta_kernel<<<ROWS / 4, 256, 0, stream>>>(hb, Wb, bbuf);

  delta_prep_kernel<<<1024, 256, 0, stream>>>(qb, kb, vb, bbuf, Wbuf, QKbuf);

  if (fused) {
    // scan (blocks 0-255) runs concurrently with the independent Wg GEMM
    scan_wg_kernel<<<1280, 512, 0, stream>>>(qb, kb, Wbuf, QKbuf, vb, hb, wg16, gb2);
    gate_kernel<<<ROWS * H / 4, 256, 0, stream>>>(vb, gb2, nw, vb);
  } else {
    delta_scan_kernel<<<256, 512, 0, stream>>>(qb, kb, Wbuf, QKbuf, vb);
    gemm_mfma_kernel<0><<<(DV / 128) * (ROWS / 128), 256, 0, stream>>>(hb, wg16, gb, ROWS, DV, Dm);
    gate_kernel<<<ROWS * H / 4, 256, 0, stream>>>(vb, gb, nw, vb);
  }

  gemm_mfma_kernel<1><<<(Dm / 128) * (ROWS / 128), 256, 0, stream>>>(vb, wo16, out, ROWS, Dm, DV);
}

// Round 20
// 468.725 us; speedup vs baseline: 2.1380x; 1.0241x over previous
//
#include <hip/hip_runtime.h>
#include <math.h>

constexpr int Lseq = 4096, Dm = 1024, H = 4, DK = 512, DV = 1024;
constexpr int DQH = 128, DVH = 256, CH = 64, ROWS = 4 * 4096;
constexpr int QKS = 1024;   // combined q|k row stride

typedef unsigned short u16;
struct alignas(16) us8 { u16 u[8]; };
typedef __attribute__((ext_vector_type(8))) short bf16x8;
typedef __attribute__((ext_vector_type(4))) float f32x4;

__device__ __forceinline__ float sig_(float x) { return 1.f / (1.f + expf(-x)); }
__device__ __forceinline__ float b2f(u16 u) {
  union { float f; unsigned v; } x; x.v = (unsigned)u << 16; return x.f;
}
__device__ __forceinline__ u16 f2b(float f) {   // round-to-nearest-even
  union { float f; unsigned v; } x; x.f = f;
  unsigned r = x.v + 0x7fffu + ((x.v >> 16) & 1u);
  return (u16)(r >> 16);
}
__device__ __forceinline__ void gld16(const u16* g, u16* l) {
  __builtin_amdgcn_global_load_lds(
      (const __attribute__((address_space(1))) void*)g,
      (__attribute__((address_space(3))) void*)l, 16, 0, 0);
}

__global__ void ws_sentinel_kernel(float* out, float v) { out[0] = v; }

// ---- 1. PROLOGUE: conv+silu (blocks 0..8191) + weight cvt/T (blocks 8192..10239) ----
__global__ __launch_bounds__(256) void prologue_kernel(
    const float* __restrict__ x, const float* __restrict__ w, u16* __restrict__ h,
    const float* __restrict__ Wq, const float* __restrict__ Wk,
    const float* __restrict__ Wv, const float* __restrict__ Wg,
    const float* __restrict__ Wo,
    u16* wq16, u16* wk16, u16* wv16, u16* wg16, u16* wo16) {
  __shared__ u16 T[32][66];
  const int t = threadIdx.x;
  if (blockIdx.x < 8192) {   // conv + silu, 8 d-elems/thread
    int idx = blockIdx.x * 256 + t;
    int d8 = (idx & 127) << 3;
    int row = idx >> 7;
    int l = row & (Lseq - 1), b = row >> 12;
    const float* xb = x + ((size_t)b << 22);
    float4 wv_[8];
#pragma unroll
    for (int j = 0; j < 2; ++j) {
      wv_[j * 4 + 0] = *(const float4*)&w[d8 * 4 + j * 16 + 0];
      wv_[j * 4 + 1] = *(const float4*)&w[d8 * 4 + j * 16 + 4];
      wv_[j * 4 + 2] = *(const float4*)&w[d8 * 4 + j * 16 + 8];
      wv_[j * 4 + 3] = *(const float4*)&w[d8 * 4 + j * 16 + 12];
    }
    float acc[8] = {0, 0, 0, 0, 0, 0, 0, 0};
#pragma unroll
    for (int i = 0; i < 4; ++i) {
      int li = l - 3 + i;
      if (li >= 0) {
        float4 x0 = *(const float4*)&xb[((size_t)li << 10) + d8];
        float4 x1 = *(const float4*)&xb[((size_t)li << 10) + d8 + 4];
        acc[0] = fmaf(((const float*)&wv_[0])[i], x0.x, acc[0]);
        acc[1] = fmaf(((const float*)&wv_[1])[i], x0.y, acc[1]);
        acc[2] = fmaf(((const float*)&wv_[2])[i], x0.z, acc[2]);
        acc[3] = fmaf(((const float*)&wv_[3])[i], x0.w, acc[3]);
        acc[4] = fmaf(((const float*)&wv_[4])[i], x1.x, acc[4]);
        acc[5] = fmaf(((const float*)&wv_[5])[i], x1.y, acc[5]);
        acc[6] = fmaf(((const float*)&wv_[6])[i], x1.z, acc[6]);
        acc[7] = fmaf(((const float*)&wv_[7])[i], x1.w, acc[7]);
      }
    }
    us8 o;
#pragma unroll
    for (int j = 0; j < 8; ++j) o.u[j] = f2b(acc[j] * sig_(acc[j]));
    *(us8*)&h[(size_t)row * Dm + d8] = o;
    return;
  }
  // weight convert + transpose
  int bid = blockIdx.x - 8192;
  const float* in; u16* out; int N, K, b0;
  if (bid < 256)       { in = Wq; out = wq16; N = DK; K = Dm; b0 = bid; }
  else if (bid < 512)  { in = Wk; out = wk16; N = DK; K = Dm; b0 = bid - 256; }
  else if (bid < 1024) { in = Wv; out = wv16; N = DV; K = Dm; b0 = bid - 512; }
  else if (bid < 1536) { in = Wg; out = wg16; N = DV; K = Dm; b0 = bid - 1024; }
  else                 { in = Wo; out = wo16; N = Dm; K = DV; b0 = bid - 1536; }
  const int nbx = N / 64;
  const int k0 = (b0 / nbx) * 32, n0 = (b0 % nbx) * 64;
#pragma unroll
  for (int i = 0; i < 8; ++i) {
    int idx = t + i * 256;
    int kk = idx >> 6, nn = idx & 63;
    T[kk][nn] = f2b(in[(size_t)(k0 + kk) * N + n0 + nn]);
  }
  __syncthreads();
#pragma unroll
  for (int i = 0; i < 8; ++i) {
    int idx = t + i * 256;
    int kk = idx & 31, nn = idx >> 5;
    out[(size_t)(n0 + nn) * K + k0 + kk] = T[kk][nn];
  }
}

// ---- GEMM body (BK=64 + swizzle, round-16 proven), 256 thr ----
template <int MODE>
__device__ __forceinline__ void gemm_body(
    const u16* __restrict__ A, const u16* __restrict__ BT, void* __restrict__ Cv,
    int M, int N, int K, int bid, int nwg, u16* As, u16* Bs) {
  const int tid = threadIdx.x;
  const int wid = tid >> 6, lane = tid & 63;
  const int wr = wid >> 1, wc = wid & 1;
  const int fr = lane & 15, fk = lane >> 4;
  const int nbx = N >> 7;
  const int swz = (bid & 7) * (nwg >> 3) + (bid >> 3);   // T1: nwg % 8 == 0
  const int row0 = (swz / nbx) * 128, col0 = (swz % nbx) * 128;

  int sr[4], sk[4];
#pragma unroll
  for (int i = 0; i < 4; ++i) {
    int s = i * 4 + wid;
    int r = s * 8 + (lane >> 3);
    sr[i] = r;
    sk[i] = ((lane & 7) ^ (r & 7)) << 3;
  }

  f32x4 acc[4][4];
#pragma unroll
  for (int i = 0; i < 4; ++i)
#pragma unroll
    for (int j = 0; j < 4; ++j) acc[i][j] = {0.f, 0.f, 0.f, 0.f};

  for (int k0 = 0; k0 < K; k0 += 64) {
#pragma unroll
    for (int i = 0; i < 4; ++i) {
      const int s = i * 4 + wid;
      gld16(&A[(size_t)(row0 + sr[i]) * K + k0 + sk[i]], &As[s * 512]);
      gld16(&BT[(size_t)(col0 + sr[i]) * K + k0 + sk[i]], &Bs[s * 512]);
    }
    __syncthreads();
#pragma unroll
    for (int kt = 0; kt < 2; ++kt) {
      bf16x8 af[4], bf[4];
#pragma unroll
      for (int mi = 0; mi < 4; ++mi) {
        int row = wr * 64 + mi * 16 + fr;
        af[mi] = *(const bf16x8*)&As[row * 64 + (((kt * 4 + fk) ^ (fr & 7)) << 3)];
      }
#pragma unroll
      for (int ni = 0; ni < 4; ++ni) {
        int row = wc * 64 + ni * 16 + fr;
        bf[ni] = *(const bf16x8*)&Bs[row * 64 + (((kt * 4 + fk) ^ (fr & 7)) << 3)];
      }
#pragma unroll
      for (int mi = 0; mi < 4; ++mi)
#pragma unroll
        for (int ni = 0; ni < 4; ++ni)
          acc[mi][ni] = __builtin_amdgcn_mfma_f32_16x16x32_bf16(
              af[mi], bf[ni], acc[mi][ni], 0, 0, 0);
    }
    __syncthreads();
  }

  if (MODE == 2) {   // fused per-row l2norm (128-col tile == one head)
    __shared__ float ssh[2][128];
#pragma unroll
    for (int mi = 0; mi < 4; ++mi)
#pragma unroll
      for (int r = 0; r < 4; ++r) {
        float p = 0.f;
#pragma unroll
        for (int ni = 0; ni < 4; ++ni) p += acc[mi][ni][r] * acc[mi][ni][r];
        p += __shfl_xor(p, 1); p += __shfl_xor(p, 2);
        p += __shfl_xor(p, 4); p += __shfl_xor(p, 8);
        if (fr == 0) ssh[wc][wr * 64 + mi * 16 + fk * 4 + r] = p;
      }
    __syncthreads();
#pragma unroll
    for (int mi = 0; mi < 4; ++mi)
#pragma unroll
      for (int r = 0; r < 4; ++r) {
        int ridx = wr * 64 + mi * 16 + fk * 4 + r;
        float sc = 1.f / fmaxf(sqrtf(ssh[0][ridx] + ssh[1][ridx]), 1e-12f);
#pragma unroll
        for (int ni = 0; ni < 4; ++ni) acc[mi][ni][r] *= sc;
      }
  }

#pragma unroll
  for (int mi = 0; mi < 4; ++mi)
#pragma unroll
    for (int ni = 0; ni < 4; ++ni) {
      int col = col0 + wc * 64 + ni * 16 + fr;
#pragma unroll
      for (int r = 0; r < 4; ++r) {
        int row = row0 + wr * 64 + mi * 16 + fk * 4 + r;
        if (MODE == 1) ((float*)Cv)[(size_t)row * N + col] = acc[mi][ni][r];
        else           ((u16*)Cv)[(size_t)row * N + col] = f2b(acc[mi][ni][r]);
      }
    }
}

// ---- standalone Wo GEMM (f32 out) ----
__global__ __launch_bounds__(256) void gemm_mfma_kernel(
    const u16* __restrict__ A, const u16* __restrict__ BT, void* __restrict__ Cv,
    int M, int N, int K) {
  __shared__ u16 As[128 * 64];
  __shared__ u16 Bs[128 * 64];
  gemm_body<1>(A, BT, Cv, M, N, K, blockIdx.x, gridDim.x, As, Bs);
}

// ---- 2. PROJECTIONS mega-kernel: qk GEMM (0..1023, l2norm) + v GEMM
//      (1024..2047) + beta (2048..6143) ----
__global__ __launch_bounds__(256) void proj_kernel(
    const u16* __restrict__ hb, const u16* __restrict__ wqk16,
    const u16* __restrict__ wv16, const float* __restrict__ Wb,
    u16* __restrict__ qk, u16* __restrict__ vb, float* __restrict__ beta) {
  __shared__ u16 As[128 * 64];
  __shared__ u16 Bs[128 * 64];
  const int bid = blockIdx.x;
  if (bid < 1024) {
    gemm_body<2>(hb, wqk16, qk, ROWS, QKS, Dm, bid, 1024, As, Bs);
    return;
  }
  if (bid < 2048) {
    gemm_body<0>(hb, wv16, vb, ROWS, DV, Dm, bid - 1024, 1024, As, Bs);
    return;
  }
  // beta = sigmoid(h @ Wb)
  int row = (bid - 2048) * 4 + (threadIdx.x >> 6), lane = threadIdx.x & 63;
  const u16* hrow = hb + (size_t)row * Dm;
  float a0 = 0, a1 = 0, a2 = 0, a3 = 0;
  for (int k0 = 0; k0 < Dm; k0 += 64) {
    float hv = b2f(hrow[k0 + lane]);
    float4 wv = *(const float4*)&Wb[(size_t)(k0 + lane) * 4];
    a0 = fmaf(hv, wv.x, a0); a1 = fmaf(hv, wv.y, a1);
    a2 = fmaf(hv, wv.z, a2); a3 = fmaf(hv, wv.w, a3);
  }
#pragma unroll
  for (int off = 32; off; off >>= 1) {
    a0 += __shfl_down(a0, off); a1 += __shfl_down(a1, off);
    a2 += __shfl_down(a2, off); a3 += __shfl_down(a3, off);
  }
  if (lane == 0) {
    int b = row >> 12, l = row & (Lseq - 1);
    beta[((size_t)(b * H + 0)) * Lseq + l] = sig_(a0);
    beta[((size_t)(b * H + 1)) * Lseq + l] = sig_(a1);
    beta[((size_t)(b * H + 2)) * Lseq + l] = sig_(a2);
    beta[((size_t)(b * H + 3)) * Lseq + l] = sig_(a3);
  }
}

// ---- 5a. delta prep v2 (round-18 proven; q/k from combined qk, stride QKS) ----
__global__ __launch_bounds__(256) void delta_prep_kernel(
    const u16* __restrict__ qk, u16* v, const float* __restrict__ beta,
    u16* __restrict__ Wout, u16* __restrict__ QKout) {
  __shared__ alignas(16) char lds0[18432];
  __shared__ alignas(16) char lds1[18432];
  __shared__ float Bc[64];
  float (*Am)[68] = (float(*)[68])lds0;
  float (*R)[68]  = (float(*)[68])lds1;
  u16 (*Th)[72]  = (u16(*)[72])lds0;
  u16 (*Tl)[72]  = (u16(*)[72])(lds0 + 9216);
  u16 (*XTh)[72] = (u16(*)[72])lds1;
  u16 (*XTl)[72] = (u16(*)[72])(lds1 + 9216);

  const int tid = threadIdx.x;
  const int wid = tid >> 6, lane = tid & 63;
  const int fr = lane & 15, fq = lane >> 4;
  const int bh = blockIdx.x >> 6, ch = blockIdx.x & 63;
  const int b = bh >> 2, hh = bh & 3;
  const int c0 = ch * CH;
  const u16* qbase = qk + (size_t)b * Lseq * QKS + hh * DQH;
  const u16* kbase = qk + (size_t)b * Lseq * QKS + 512 + hh * DQH;
  u16*       vbase = v + (size_t)b * Lseq * DV + hh * DVH;
  const float* bbase = beta + (size_t)bh * Lseq;
  u16* Wrow  = Wout  + ((size_t)bh * Lseq + c0) * DQH;
  u16* QKrow = QKout + ((size_t)bh * Lseq + c0) * CH;

  if (tid < 64) Bc[tid] = bbase[c0 + tid];
  for (int idx = tid; idx < 64 * 64; idx += 256) {
    int r = idx >> 6, c = idx & 63;
    R[r][c] = (r == c) ? 1.f : 0.f;
  }
  __syncthreads();

  {
    const int m0 = wid * 16;
    f32x4 accG[4], accQ[4];
#pragma unroll
    for (int ni = 0; ni < 4; ++ni) {
      accG[ni] = {0.f, 0.f, 0.f, 0.f};
      accQ[ni] = {0.f, 0.f, 0.f, 0.f};
    }
#pragma unroll
    for (int kt = 0; kt < 4; ++kt) {
      bf16x8 afk = *(const bf16x8*)&kbase[(size_t)(c0 + m0 + fr) * QKS + kt * 32 + fq * 8];
      bf16x8 afq = *(const bf16x8*)&qbase[(size_t)(c0 + m0 + fr) * QKS + kt * 32 + fq * 8];
#pragma unroll
      for (int ni = 0; ni < 4; ++ni) {
        bf16x8 bfk = *(const bf16x8*)&kbase[(size_t)(c0 + ni * 16 + fr) * QKS + kt * 32 + fq * 8];
        accG[ni] = __builtin_amdgcn_mfma_f32_16x16x32_bf16(afk, bfk, accG[ni], 0, 0, 0);
        accQ[ni] = __builtin_amdgcn_mfma_f32_16x16x32_bf16(afq, bfk, accQ[ni], 0, 0, 0);
      }
    }
#pragma unroll
    for (int ni = 0; ni < 4; ++ni)
#pragma unroll
      for (int i = 0; i < 4; ++i) {
        int row = m0 + fq * 4 + i, col = ni * 16 + fr;
        float br = Bc[row];
        Am[row][col] = (col < row) ? br * accG[ni][i] : 0.f;
        QKrow[(size_t)row * CH + col] = f2b((col <= row) ? accQ[ni][i] : 0.f);
      }
  }
  __syncthreads();

  for (int rb = 0; rb < 4; ++rb) {
    if (rb > 0) {
      const int c = tid & 63, g = tid >> 6;
      const int R0 = rb * 16, row = R0 + g * 4;
      float s0 = 0, s1 = 0, s2 = 0, s3 = 0;
      for (int m = 0; m < R0; ++m) {
        float uv = R[m][c];
        s0 = fmaf(Am[row + 0][m], uv, s0);
        s1 = fmaf(Am[row + 1][m], uv, s1);
        s2 = fmaf(Am[row + 2][m], uv, s2);
        s3 = fmaf(Am[row + 3][m], uv, s3);
      }
      R[row + 0][c] -= s0; R[row + 1][c] -= s1;
      R[row + 2][c] -= s2; R[row + 3][c] -= s3;
    }
    __syncthreads();
    if (tid < 64) {
      const int c = tid;
      for (int i = 1; i < 16; ++i) {
        const int row = rb * 16 + i;
        float s = R[row][c];
        for (int m = 0; m < i; ++m)
          s = fmaf(-Am[row][rb * 16 + m], R[rb * 16 + m][c], s);
        R[row][c] = s;
      }
    }
    __syncthreads();
  }

  for (int idx = tid; idx < 64 * 64; idx += 256) {
    int r = idx >> 6, c = idx & 63;
    float tv = R[r][c];
    u16 hh2 = f2b(tv);
    Th[r][c] = hh2;
    Tl[r][c] = f2b(tv - b2f(hh2));
  }
  __syncthreads();

  for (int p = 0; p < 6; ++p) {
    const int off = (p < 2) ? p * 64 : (p - 2) * 64;
    for (int idx = tid; idx < 64 * 64; idx += 256) {
      int d = idx & 63, m = idx >> 6;
      float xv;
      if (p < 2) xv = Bc[m] * b2f(kbase[(size_t)(c0 + m) * QKS + off + d]);
      else       xv = Bc[m] * b2f(vbase[(size_t)(c0 + m) * DV + off + d]);
      u16 hh2 = f2b(xv);
      XTh[d][m] = hh2;
      XTl[d][m] = f2b(xv - b2f(hh2));
    }
    __syncthreads();
    f32x4 acc[4];
#pragma unroll
    for (int tn = 0; tn < 4; ++tn) acc[tn] = {0.f, 0.f, 0.f, 0.f};
#pragma unroll
    for (int kt = 0; kt < 2; ++kt) {
      bf16x8 ah = *(const bf16x8*)&Th[wid * 16 + fr][kt * 32 + fq * 8];
      bf16x8 al = *(const bf16x8*)&Tl[wid * 16 + fr][kt * 32 + fq * 8];
#pragma unroll
      for (int tn = 0; tn < 4; ++tn) {
        bf16x8 xh = *(const bf16x8*)&XTh[tn * 16 + fr][kt * 32 + fq * 8];
        bf16x8 xl = *(const bf16x8*)&XTl[tn * 16 + fr][kt * 32 + fq * 8];
        acc[tn] = __builtin_amdgcn_mfma_f32_16x16x32_bf16(ah, xh, acc[tn], 0, 0, 0);
        acc[tn] = __builtin_amdgcn_mfma_f32_16x16x32_bf16(ah, xl, acc[tn], 0, 0, 0);
        acc[tn] = __builtin_amdgcn_mfma_f32_16x16x32_bf16(al, xh, acc[tn], 0, 0, 0);
      }
    }
#pragma unroll
    for (int tn = 0; tn < 4; ++tn)
#pragma unroll
      for (int i = 0; i < 4; ++i) {
        int row = wid * 16 + fq * 4 + i, col = tn * 16 + fr;
        if (p < 2) Wrow[(size_t)row * DQH + off + col] = f2b(-acc[tn][i]);
        else       vbase[(size_t)(c0 + row) * DV + off + col] = f2b(acc[tn][i]);
      }
    __syncthreads();
  }
}

// ---- scan body (round-17/18 proven; q/k from combined qk, stride QKS) ----
__device__ __forceinline__ void scan_body(
    int sbid, const u16* __restrict__ qkp,
    const u16* __restrict__ Wb, const u16* __restrict__ QKb, u16* uo,
    u16 (*Kt)[72], u16 (*Sbt_hi)[136], u16 (*Sbt_lo)[136], u16 (*Ubt)[72]) {
  const int tid = threadIdx.x;
  const int wid = tid >> 6, lane = tid & 63;
  const int fr = lane & 15, fq = lane >> 4;
  const int m0w = 16 * (wid & 3);
  const int bh = sbid & 15, vblk = sbid >> 4;   // XCD-local bh
  const int b = bh >> 2, hh = bh & 3;
  const u16* qbase = qkp + (size_t)b * Lseq * QKS + hh * DQH;
  const u16* kbase = qkp + (size_t)b * Lseq * QKS + 512 + hh * DQH;
  const u16* Wbase = Wb + (size_t)bh * Lseq * DQH;
  const u16* QKbase = QKb + (size_t)bh * Lseq * CH;
  u16* uobase = uo + (size_t)b * Lseq * DV + hh * DVH + vblk * 16;

  for (int i = tid; i < 16 * 136; i += 512) {
    (&Sbt_hi[0][0])[i] = 0; (&Sbt_lo[0][0])[i] = 0;
  }
  f32x4 Sfrag = {0.f, 0.f, 0.f, 0.f};

  const int kr0 = tid & 63, kd0 = (tid >> 6) << 3;
  const int kr1 = (tid + 512) & 63, kd1 = ((tid + 512) >> 6) << 3;

  us8 kpre0 = *(const us8*)&kbase[(size_t)kr0 * QKS + kd0];
  us8 kpre1 = *(const us8*)&kbase[(size_t)kr1 * QKS + kd1];
  bf16x8 fpre[4];
  bf16x8 qkpre0 = {}, qkpre1 = {};
  ushort4 u0pre = {};
  if (wid < 4) {
    const u16* wp = Wbase + (size_t)(m0w + fr) * DQH + fq * 8;
#pragma unroll
    for (int kt = 0; kt < 4; ++kt) fpre[kt] = *(const bf16x8*)&wp[kt * 32];
    const u16* up = uobase + (size_t)(m0w + fq * 4) * DV + fr;
    u0pre.x = up[0]; u0pre.y = up[(size_t)DV];
    u0pre.z = up[(size_t)2 * DV]; u0pre.w = up[(size_t)3 * DV];
  } else {
    const u16* qp = qbase + (size_t)(m0w + fr) * QKS + fq * 8;
#pragma unroll
    for (int kt = 0; kt < 4; ++kt) fpre[kt] = *(const bf16x8*)&qp[kt * 32];
    const u16* qkp2 = QKbase + (size_t)(m0w + fr) * CH + fq * 8;
    qkpre0 = *(const bf16x8*)&qkp2[0];
    qkpre1 = *(const bf16x8*)&qkp2[32];
  }
  __syncthreads();

  for (int c0 = 0; c0 < Lseq; c0 += CH) {
#pragma unroll
    for (int j = 0; j < 8; ++j) Kt[kd0 + j][kr0] = kpre0.u[j];
#pragma unroll
    for (int j = 0; j < 8; ++j) Kt[kd1 + j][kr1] = kpre1.u[j];

    bf16x8 fcur[4];
#pragma unroll
    for (int kt = 0; kt < 4; ++kt) fcur[kt] = fpre[kt];
    bf16x8 qkc0 = qkpre0, qkc1 = qkpre1;
    ushort4 u0c = u0pre;

    if (c0 + CH < Lseq) {
      const int cn = c0 + CH;
      kpre0 = *(const us8*)&kbase[(size_t)(cn + kr0) * QKS + kd0];
      kpre1 = *(const us8*)&kbase[(size_t)(cn + kr1) * QKS + kd1];
      if (wid < 4) {
        const u16* wp = Wbase + (size_t)(cn + m0w + fr) * DQH + fq * 8;
#pragma unroll
        for (int kt = 0; kt < 4; ++kt) fpre[kt] = *(const bf16x8*)&wp[kt * 32];
        const u16* up = uobase + (size_t)(cn + m0w + fq * 4) * DV + fr;
        u0pre.x = up[0]; u0pre.y = up[(size_t)DV];
        u0pre.z = up[(size_t)2 * DV]; u0pre.w = up[(size_t)3 * DV];
      } else {
        const u16* qp = qbase + (size_t)(cn + m0w + fr) * QKS + fq * 8;
#pragma unroll
        for (int kt = 0; kt < 4; ++kt) fpre[kt] = *(const bf16x8*)&qp[kt * 32];
        const u16* qkp2 = QKbase + (size_t)(cn + m0w + fr) * CH + fq * 8;
        qkpre0 = *(const bf16x8*)&qkp2[0];
        qkpre1 = *(const bf16x8*)&qkp2[32];
      }
    }

    f32x4 acc, accB;
    if (wid < 4) {
      acc[0] = b2f(u0c.x); acc[1] = b2f(u0c.y);
      acc[2] = b2f(u0c.z); acc[3] = b2f(u0c.w);
      accB = (f32x4){0.f, 0.f, 0.f, 0.f};
      __builtin_amdgcn_s_setprio(1);
#pragma unroll
      for (int kt = 0; kt < 2; ++kt) {
        bf16x8 sh = *(const bf16x8*)&Sbt_hi[fr][kt * 32 + fq * 8];
        bf16x8 sl = *(const bf16x8*)&Sbt_lo[fr][kt * 32 + fq * 8];
        acc = __builtin_amdgcn_mfma_f32_16x16x32_bf16(fcur[kt], sh, acc, 0, 0, 0);
        acc = __builtin_amdgcn_mfma_f32_16x16x32_bf16(fcur[kt], sl, acc, 0, 0, 0);
      }
#pragma unroll
      for (int kt = 2; kt < 4; ++kt) {
        bf16x8 sh = *(const bf16x8*)&Sbt_hi[fr][kt * 32 + fq * 8];
        bf16x8 sl = *(const bf16x8*)&Sbt_lo[fr][kt * 32 + fq * 8];
        accB = __builtin_amdgcn_mfma_f32_16x16x32_bf16(fcur[kt], sh, accB, 0, 0, 0);
        accB = __builtin_amdgcn_mfma_f32_16x16x32_bf16(fcur[kt], sl, accB, 0, 0, 0);
      }
      __builtin_amdgcn_s_setprio(0);
      ushort4 ub = {f2b(acc[0] + accB[0]), f2b(acc[1] + accB[1]),
                    f2b(acc[2] + accB[2]), f2b(acc[3] + accB[3])};
      *(ushort4*)&Ubt[fr][m0w + fq * 4] = ub;
    } else {
      acc = (f32x4){0.f, 0.f, 0.f, 0.f};
      accB = (f32x4){0.f, 0.f, 0.f, 0.f};
#pragma unroll
      for (int kt = 0; kt < 2; ++kt) {
        bf16x8 sh = *(const bf16x8*)&Sbt_hi[fr][kt * 32 + fq * 8];
        acc = __builtin_amdgcn_mfma_f32_16x16x32_bf16(fcur[kt], sh, acc, 0, 0, 0);
      }
#pragma unroll
      for (int kt = 2; kt < 4; ++kt) {
        bf16x8 sh = *(const bf16x8*)&Sbt_hi[fr][kt * 32 + fq * 8];
        accB = __builtin_amdgcn_mfma_f32_16x16x32_bf16(fcur[kt], sh, accB, 0, 0, 0);
      }
    }
    __syncthreads();

    if (wid >= 4) {
      bf16x8 uf0 = *(const bf16x8*)&Ubt[fr][fq * 8];
      bf16x8 uf1 = *(const bf16x8*)&Ubt[fr][32 + fq * 8];
      acc  = __builtin_amdgcn_mfma_f32_16x16x32_bf16(qkc0, uf0, acc, 0, 0, 0);
      accB = __builtin_amdgcn_mfma_f32_16x16x32_bf16(qkc1, uf1, accB, 0, 0, 0);
      u16* op = uobase + (size_t)(c0 + m0w + fq * 4) * DV + fr;
      op[0] = f2b(acc[0] + accB[0]);
      op[(size_t)DV] = f2b(acc[1] + accB[1]);
      op[(size_t)2 * DV] = f2b(acc[2] + accB[2]);
      op[(size_t)3 * DV] = f2b(acc[3] + accB[3]);
    }
    __builtin_amdgcn_s_setprio(1);
#pragma unroll
    for (int kt = 0; kt < 2; ++kt) {
      bf16x8 kf = *(const bf16x8*)&Kt[16 * wid + fr][kt * 32 + fq * 8];
      bf16x8 uf = *(const bf16x8*)&Ubt[fr][kt * 32 + fq * 8];
      Sfrag = __builtin_amdgcn_mfma_f32_16x16x32_bf16(kf, uf, Sfrag, 0, 0, 0);
    }
    __builtin_amdgcn_s_setprio(0);
    ushort4 shv, slv;
#pragma unroll
    for (int i = 0; i < 4; ++i) {
      float s = Sfrag[i];
      u16 hpart = f2b(s);
      ((u16*)&shv)[i] = hpart;
      ((u16*)&slv)[i] = f2b(s - b2f(hpart));
    }
    *(ushort4*)&Sbt_hi[fr][16 * wid + fq * 4] = shv;
    *(ushort4*)&Sbt_lo[fr][16 * wid + fq * 4] = slv;
    __syncthreads();
  }
}

// ---- 5b standalone scan (fallback) ----
__global__ __launch_bounds__(512) void delta_scan_kernel(
    const u16* __restrict__ qk, const u16* __restrict__ Wb,
    const u16* __restrict__ QKb, u16* uo) {
  __shared__ alignas(16) u16 Kt[128][72];
  __shared__ alignas(16) u16 Sbt_hi[16][136];
  __shared__ alignas(16) u16 Sbt_lo[16][136];
  __shared__ alignas(16) u16 Ubt[16][72];
  scan_body(blockIdx.x, qk, Wb, QKb, uo, Kt, Sbt_hi, Sbt_lo, Ubt);
}

// ---- 5c FUSED: blocks 0-255 scan; 256-1279 Wg GEMM (512 thr, 8 waves) ----
__global__ __launch_bounds__(512) void scan_wg_kernel(
    const u16* __restrict__ qk, const u16* __restrict__ Wb,
    const u16* __restrict__ QKb, u16* uo,
    const u16* __restrict__ A, const u16* __restrict__ BT, u16* __restrict__ C) {
  __shared__ alignas(16) u16 Kt[128][72];
  __shared__ alignas(16) u16 Sbt_hi[16][136];
  __shared__ alignas(16) u16 Sbt_lo[16][136];
  __shared__ alignas(16) u16 Ubt[16][72];
  __shared__ u16 As[128 * 64];
  __shared__ u16 Bs[128 * 64];

  if (blockIdx.x < 256) {
    scan_body(blockIdx.x, qk, Wb, QKb, uo, Kt, Sbt_hi, Sbt_lo, Ubt);
    return;
  }
  const int tid = threadIdx.x;
  const int wid = tid >> 6, lane = tid & 63;
  const int wr = wid >> 2, wc = wid & 3;
  const int fr = lane & 15, fk = lane >> 4;
  const int nbx = DV >> 7;
  const int gbid = blockIdx.x - 256, nwg = 1024;
  const int swz = (gbid & 7) * (nwg >> 3) + (gbid >> 3);
  const int row0 = (swz / nbx) * 128, col0 = (swz % nbx) * 128;

  int sr[2], sk[2];
#pragma unroll
  for (int i = 0; i < 2; ++i) {
    int s = i * 8 + wid;
    int r = s * 8 + (lane >> 3);
    sr[i] = r;
    sk[i] = ((lane & 7) ^ (r & 7)) << 3;
  }

  f32x4 acc[4][2];
#pragma unroll
  for (int i = 0; i < 4; ++i)
#pragma unroll
    for (int j = 0; j < 2; ++j) acc[i][j] = {0.f, 0.f, 0.f, 0.f};

  for (int k0 = 0; k0 < Dm; k0 += 64) {
#pragma unroll
    for (int i = 0; i < 2; ++i) {
      const int s = i * 8 + wid;
      gld16(&A[(size_t)(row0 + sr[i]) * Dm + k0 + sk[i]], &As[s * 512]);
      gld16(&BT[(size_t)(col0 + sr[i]) * Dm + k0 + sk[i]], &Bs[s * 512]);
    }
    __syncthreads();
#pragma unroll
    for (int kt = 0; kt < 2; ++kt) {
      bf16x8 af[4], bf[2];
#pragma unroll
      for (int mi = 0; mi < 4; ++mi) {
        int row = wr * 64 + mi * 16 + fr;
        af[mi] = *(const bf16x8*)&As[row * 64 + (((kt * 4 + fk) ^ (fr & 7)) << 3)];
      }
#pragma unroll
      for (int ni = 0; ni < 2; ++ni) {
        int row = wc * 32 + ni * 16 + fr;
        bf[ni] = *(const bf16x8*)&Bs[row * 64 + (((kt * 4 + fk) ^ (fr & 7)) << 3)];
      }
#pragma unroll
      for (int mi = 0; mi < 4; ++mi)
#pragma unroll
        for (int ni = 0; ni < 2; ++ni)
          acc[mi][ni] = __builtin_amdgcn_mfma_f32_16x16x32_bf16(
              af[mi], bf[ni], acc[mi][ni], 0, 0, 0);
    }
    __syncthreads();
  }
#pragma unroll
  for (int mi = 0; mi < 4; ++mi)
#pragma unroll
    for (int ni = 0; ni < 2; ++ni) {
      int col = col0 + wc * 32 + ni * 16 + fr;
#pragma unroll
      for (int r = 0; r < 4; ++r) {
        int row = row0 + wr * 64 + mi * 16 + fk * 4 + r;
        C[(size_t)row * DV + col] = f2b(acc[mi][ni][r]);
      }
    }
}

// ---- 6. gate ----
__global__ __launch_bounds__(256) void gate_kernel(
    const u16* og, const u16* __restrict__ g,
    const float* __restrict__ nw, u16* out) {
  int idx = blockIdx.x * 4 + (threadIdx.x >> 6), lane = threadIdx.x & 63;
  size_t base = (size_t)(idx >> 2) * DV + (size_t)(idx & 3) * DVH + (size_t)lane * 4;
  ushort4 o4 = *(const ushort4*)&og[base];
  float ox = b2f(o4.x), oy = b2f(o4.y), oz = b2f(o4.z), ow = b2f(o4.w);
  float ss = ox * ox + oy * oy + oz * oz + ow * ow;
#pragma unroll
  for (int off = 32; off; off >>= 1) ss += __shfl_xor(ss, off);
  float r = 1.f / sqrtf(ss * (1.f / DVH) + 1e-5f);
  ushort4 g4 = *(const ushort4*)&g[base];
  float gx = b2f(g4.x), gy = b2f(g4.y), gz = b2f(g4.z), gw = b2f(g4.w);
  float4 wv = *(const float4*)&nw[lane * 4];
  ushort4 res;
  res.x = f2b(ox * r * wv.x * (gx * sig_(gx)));
  res.y = f2b(oy * r * wv.y * (gy * sig_(gy)));
  res.z = f2b(oz * r * wv.z * (gz * sig_(gz)));
  res.w = f2b(ow * r * wv.w * (gw * sig_(gw)));
  *(ushort4*)&out[base] = res;
}

// ---- fallback Wg GEMM (bf16 out) ----
__global__ __launch_bounds__(256) void gemm_bf16_kernel(
    const u16* __restrict__ A, const u16* __restrict__ BT, void* __restrict__ Cv,
    int M, int N, int K) {
  __shared__ u16 As[128 * 64];
  __shared__ u16 Bs[128 * 64];
  gemm_body<0>(A, BT, Cv, M, N, K, blockIdx.x, gridDim.x, As, Bs);
}

// ---- host ----
extern "C" void kernel_launch(void* const* d_in, const int* in_sizes, int n_in,
                              void* d_out, int out_size, void* d_ws, size_t ws_size,
                              hipStream_t stream) {
  (void)in_sizes; (void)n_in; (void)out_size;
  const float* x  = (const float*)d_in[0];
  const float* cw = (const float*)d_in[1];
  const float* Wq = (const float*)d_in[2];
  const float* Wk = (const float*)d_in[3];
  const float* Wv = (const float*)d_in[4];
  const float* Wb = (const float*)d_in[5];
  const float* Wg = (const float*)d_in[6];
  const float* nw = (const float*)d_in[7];
  const float* Wo = (const float*)d_in[8];
  float* out = (float*)d_out;   // f32 output

  u16* hb  = (u16*)d_ws;                       // ROWS*Dm  bf16
  u16* qkb = hb + (size_t)ROWS * Dm;           // ROWS*QKS (q cols 0-511, k 512-1023)
  u16* vb  = qkb + (size_t)ROWS * QKS;         // ROWS*DV  (v -> U0 -> O; gate in-place)
  float* bbuf = (float*)(vb + (size_t)ROWS * DV);   // ROWS*H f32
  u16* Wbuf  = (u16*)(bbuf + (size_t)ROWS * H);     // 16*Lseq*DQH bf16 (negated)
  u16* QKbuf = Wbuf + (size_t)16 * Lseq * DQH;      // 16*Lseq*CH  bf16
  u16* wq16 = QKbuf + (size_t)16 * Lseq * CH;       // [N][K] bf16; wq16||wk16 = combined
  u16* wk16 = wq16 + (size_t)Dm * DK;
  u16* wv16 = wk16 + (size_t)Dm * DK;
  u16* wg16 = wv16 + (size_t)Dm * DV;
  u16* wo16 = wg16 + (size_t)Dm * DV;
  u16* gb2  = wo16 + (size_t)DV * Dm;               // separate g buffer (fused path)
  u16* gb   = qkb;                                  // aliased g buffer (fallback)

  const size_t need = (size_t)ROWS * (Dm + QKS + DV) * 2 + (size_t)ROWS * H * 4
                    + (size_t)16 * Lseq * (DQH + CH) * 2
                    + ((size_t)Dm * (DK * 2 + DV * 3)) * 2;
  const size_t need2 = need + (size_t)ROWS * DV * 2;
  if (ws_size < need) {
    ws_sentinel_kernel<<<1, 1, 0, stream>>>(out, (float)ws_size);
    return;
  }
  const bool fused = (ws_size >= need2);

  prologue_kernel<<<10240, 256, 0, stream>>>(x, cw, hb, Wq, Wk, Wv, Wg, Wo,
                                             wq16, wk16, wv16, wg16, wo16);
  proj_kernel<<<6144, 256, 0, stream>>>(hb, wq16, wv16, Wb, qkb, vb, bbuf);

  delta_prep_kernel<<<1024, 256, 0, stream>>>(qkb, vb, bbuf, Wbuf, QKbuf);

  if (fused) {
    scan_wg_kernel<<<1280, 512, 0, stream>>>(qkb, Wbuf, QKbuf, vb, hb, wg16, gb2);
    gate_kernel<<<ROWS * H / 4, 256, 0, stream>>>(vb, gb2, nw, vb);
  } else {
    delta_scan_kernel<<<256, 512, 0, stream>>>(qkb, Wbuf, QKbuf, vb);
    gemm_bf16_kernel<<<(DV / 128) * (ROWS / 128), 256, 0, stream>>>(hb, wg16, gb, ROWS, DV, Dm);
    gate_kernel<<<ROWS * H / 4, 256, 0, stream>>>(vb, gb, nw, vb);
  }

  gemm_mfma_kernel<<<(Dm / 128) * (ROWS / 128), 256, 0, stream>>>(vb, wo16, out, ROWS, Dm, DV);
}